// Round 3
// baseline (3987.678 us; speedup 1.0000x reference)
//
#include <hip/hip_runtime.h>
#include <math.h>

#define BB 32
#define NN 1024
#define KK 20
#define NCH 4
typedef unsigned long long u64;
typedef unsigned int u32;
static constexpr float EPSF = 1e-5f;

// ---------------- transpose (B,N,3) -> (B,3,N) ----------------
__global__ void transpose3_kernel(const float* __restrict__ x, float* __restrict__ xT) {
  int t = blockIdx.x * blockDim.x + threadIdx.x;
  if (t >= BB * NN) return;
  int b = t >> 10, i = t & (NN - 1);
  #pragma unroll
  for (int c = 0; c < 3; ++c)
    xT[((size_t)b * 3 + c) * NN + i] = x[(size_t)t * 3 + c];
}

// ---------------- xx = sum(x*x) per point ----------------
template<int C>
__global__ void xx_kernel(const float* __restrict__ x, float* __restrict__ xx) {
  int t = blockIdx.x * blockDim.x + threadIdx.x;
  if (t >= BB * NN) return;
  const float* p = x + (size_t)t * C;
  float s = 0.f;
  #pragma unroll
  for (int c = 0; c < C; ++c) s += p[c] * p[c];
  xx[t] = s;
}

// ---------------- sorted top-20 insert on packed u64 keys ----------------
__device__ __forceinline__ void ins20(u64 (&key)[KK], u64 k) {
  if (k > key[KK - 1]) {
    #pragma unroll
    for (int s = KK - 1; s >= 1; --s)
      key[s] = (k > key[s - 1]) ? key[s - 1] : ((k > key[s]) ? k : key[s]);
    key[0] = (k > key[0]) ? k : key[0];
  }
}

__device__ __forceinline__ u64 mkkey(float d, int j) {
  u32 bits = __float_as_uint(d);
  u32 m = (bits & 0x80000000u) ? ~bits : (bits | 0x80000000u);
  return ((u64)m << 32) | (u32)(~(u32)j);
}

// ---------------- dist GEMM: D[bg][i][j] = 2*dot(x_i,x_j) - xx_j ----------------
// (row-constant -xx_i dropped: row-wise top-k invariant)
#define TI 128
#define CC 64
__global__ __launch_bounds__(256) void dist_kernel(
    const float* __restrict__ x,   // (B,N,64)
    const float* __restrict__ xx,  // (B,N)
    float* __restrict__ D,         // (g,N,N)
    int b0) {
  int b = b0 + blockIdx.z;
  int i0 = blockIdx.y * TI;
  int j0 = blockIdx.x * TI;

  __shared__ float4 At[TI * (CC / 4)];
  __shared__ float4 Bt[TI * (CC / 4)];

  const float4* xa = (const float4*)(x + ((size_t)b * NN + i0) * CC);
  const float4* xb = (const float4*)(x + ((size_t)b * NN + j0) * CC);
  #pragma unroll
  for (int t = threadIdx.x; t < TI * (CC / 4); t += 256) {
    int row = t >> 4, c4 = t & 15;
    int c4s = c4 ^ ((row >> 3) & 7);
    At[row * 16 + c4s] = xa[t];
    Bt[row * 16 + c4s] = xb[t];
  }
  __syncthreads();

  int tx = threadIdx.x & 15, ty = threadIdx.x >> 4;
  int ar[8], br[8], asw[8], bsw[8];
  #pragma unroll
  for (int r = 0; r < 8; ++r) {
    int row = ty * 8 + r, col = tx * 8 + r;
    ar[r] = row * 16; asw[r] = (row >> 3) & 7;
    br[r] = col * 16; bsw[r] = (col >> 3) & 7;
  }

  float acc[8][8];
  #pragma unroll
  for (int r = 0; r < 8; ++r)
    #pragma unroll
    for (int s = 0; s < 8; ++s) acc[r][s] = 0.f;

  #pragma unroll
  for (int c4 = 0; c4 < 16; ++c4) {
    float4 av[8], bv[8];
    #pragma unroll
    for (int r = 0; r < 8; ++r) av[r] = At[ar[r] + (c4 ^ asw[r])];
    #pragma unroll
    for (int s = 0; s < 8; ++s) bv[s] = Bt[br[s] + (c4 ^ bsw[s])];
    #pragma unroll
    for (int r = 0; r < 8; ++r)
      #pragma unroll
      for (int s = 0; s < 8; ++s) {
        acc[r][s] += av[r].x * bv[s].x;
        acc[r][s] += av[r].y * bv[s].y;
        acc[r][s] += av[r].z * bv[s].z;
        acc[r][s] += av[r].w * bv[s].w;
      }
  }

  const float* xxb = xx + (size_t)b * NN;
  float xxj[8];
  #pragma unroll
  for (int s = 0; s < 8; ++s) xxj[s] = xxb[j0 + tx * 8 + s];

  float* Dg = D + (size_t)blockIdx.z * NN * NN;
  #pragma unroll
  for (int r = 0; r < 8; ++r) {
    float4 o0, o1;
    o0.x = 2.f * acc[r][0] - xxj[0];
    o0.y = 2.f * acc[r][1] - xxj[1];
    o0.z = 2.f * acc[r][2] - xxj[2];
    o0.w = 2.f * acc[r][3] - xxj[3];
    o1.x = 2.f * acc[r][4] - xxj[4];
    o1.y = 2.f * acc[r][5] - xxj[5];
    o1.z = 2.f * acc[r][6] - xxj[6];
    o1.w = 2.f * acc[r][7] - xxj[7];
    float4* dst = (float4*)(Dg + (size_t)(i0 + ty * 8 + r) * NN + j0 + tx * 8);
    dst[0] = o0; dst[1] = o1;
  }
}

// ---------------- select: per (bg,row,chunk) thread -> sorted top-20 of 256 cands ----------------
__global__ __launch_bounds__(256) void select_kernel(
    const float* __restrict__ D,  // (g,N,N)
    u64* __restrict__ P,          // (B,N,NCH,KK)
    int b0) {
  int t = blockIdx.x * 256 + threadIdx.x;   // g*NCH*N threads
  int row = t & (NN - 1);
  int ch  = (t >> 10) & (NCH - 1);
  int bg  = t >> 12;

  const float4* dp = (const float4*)(D + ((size_t)bg * NN + row) * NN + ch * (NN / NCH));
  int jbase = ch * (NN / NCH);

  u64 key[KK];
  #pragma unroll
  for (int e = 0; e < KK; ++e) key[e] = 0ull;

  #pragma unroll 4
  for (int q = 0; q < NN / NCH / 4; ++q) {
    float4 v = dp[q];
    int j = jbase + q * 4;
    ins20(key, mkkey(v.x, j + 0));
    ins20(key, mkkey(v.y, j + 1));
    ins20(key, mkkey(v.z, j + 2));
    ins20(key, mkkey(v.w, j + 3));
  }

  u64* out = P + (((size_t)(b0 + bg) * NN + row) * NCH + ch) * KK;
  #pragma unroll
  for (int e = 0; e < KK; ++e) out[e] = key[e];
}

// ---------------- select3: layer-1 fused distance (C=3), d = 2*dot - xx_j ----------------
__global__ __launch_bounds__(256) void select3_kernel(
    const float* __restrict__ x,   // (B,N,3)
    const float* __restrict__ xT,  // (B,3,N)
    const float* __restrict__ xx,  // (B,N)
    u64* __restrict__ P) {         // (B,N,NCH,KK)
  int t = blockIdx.x * 256 + threadIdx.x;   // B*NCH*N threads
  int row = t & (NN - 1);
  int ch  = (t >> 10) & (NCH - 1);
  int b   = t >> 12;

  const float* xr = x + ((size_t)b * NN + row) * 3;
  float x0 = xr[0], x1 = xr[1], x2 = xr[2];
  const float* xxb = xx + (size_t)b * NN;
  const float* xTb = xT + (size_t)b * 3 * NN;
  int jbase = ch * (NN / NCH);

  u64 key[KK];
  #pragma unroll
  for (int e = 0; e < KK; ++e) key[e] = 0ull;

  for (int q = 0; q < NN / NCH / 4; ++q) {
    int j = jbase + q * 4;
    float4 a = *(const float4*)(xTb + 0 * NN + j);
    float4 bv = *(const float4*)(xTb + 1 * NN + j);
    float4 c = *(const float4*)(xTb + 2 * NN + j);
    float4 xj = *(const float4*)(xxb + j);
    float d0 = 0.f, d1 = 0.f, d2 = 0.f, d3 = 0.f;
    d0 += x0 * a.x; d0 += x1 * bv.x; d0 += x2 * c.x;
    d1 += x0 * a.y; d1 += x1 * bv.y; d1 += x2 * c.y;
    d2 += x0 * a.z; d2 += x1 * bv.z; d2 += x2 * c.z;
    d3 += x0 * a.w; d3 += x1 * bv.w; d3 += x2 * c.w;
    ins20(key, mkkey(2.f * d0 - xj.x, j + 0));
    ins20(key, mkkey(2.f * d1 - xj.y, j + 1));
    ins20(key, mkkey(2.f * d2 - xj.z, j + 2));
    ins20(key, mkkey(2.f * d3 - xj.w, j + 3));
  }

  u64* out = P + (((size_t)b * NN + row) * NCH + ch) * KK;
  #pragma unroll
  for (int e = 0; e < KK; ++e) out[e] = key[e];
}

// ---------------- merge NCH sorted lists -> final idx ----------------
__global__ __launch_bounds__(256) void merge_kernel(
    const u64* __restrict__ P, int* __restrict__ oidx) {
  int t = blockIdx.x * 256 + threadIdx.x;   // B*N threads
  if (t >= BB * NN) return;
  const u64* p = P + (size_t)t * NCH * KK;

  u64 best[KK];
  #pragma unroll
  for (int e = 0; e < KK; ++e) best[e] = 0ull;

  for (int l = 0; l < NCH; ++l) {
    const u64* pl = p + l * KK;
    for (int e = 0; e < KK; ++e) {
      u64 k = pl[e];
      if (k <= best[KK - 1]) break;   // sorted desc -> rest smaller
      #pragma unroll
      for (int s = KK - 1; s >= 1; --s)
        best[s] = (k > best[s - 1]) ? best[s - 1] : ((k > best[s]) ? k : best[s]);
      best[0] = (k > best[0]) ? k : best[0];
    }
  }
  int* orow = oidx + (size_t)t * KK;
  #pragma unroll
  for (int e = 0; e < KK; ++e) orow[e] = (int)(~(u32)best[e]);
}

// ---------------- uc GEMM: uc[b,i,col] ; col<O: Wa.x_i ; col>=O: (Wb-Wa).x_i ----------------
template<int O>
__global__ __launch_bounds__(256) void uc_gemm_kernel(
    const float* __restrict__ x,   // (B,N,64)
    const float* __restrict__ w,   // (O,128)
    float* __restrict__ uc) {      // (B,N,2O)
  int b = blockIdx.z;
  int i0 = blockIdx.y * TI;
  int j0 = blockIdx.x * TI;

  __shared__ float4 At[TI * 16];
  __shared__ float4 Bt[TI * 16];

  const float4* xa = (const float4*)(x + ((size_t)b * NN + i0) * CC);
  const float4* w4 = (const float4*)w;   // row stride 32 float4
  #pragma unroll
  for (int t = threadIdx.x; t < TI * 16; t += 256) {
    int row = t >> 4, c4 = t & 15;
    int c4s = c4 ^ ((row >> 3) & 7);
    At[row * 16 + c4s] = xa[t];
    int wrow = j0 + row;
    float4 bvv;
    if (wrow < O) {
      bvv = w4[(size_t)wrow * 32 + c4];
    } else {
      float4 lo = w4[(size_t)(wrow - O) * 32 + c4];
      float4 hi = w4[(size_t)(wrow - O) * 32 + 16 + c4];
      bvv.x = hi.x - lo.x; bvv.y = hi.y - lo.y; bvv.z = hi.z - lo.z; bvv.w = hi.w - lo.w;
    }
    Bt[row * 16 + c4s] = bvv;
  }
  __syncthreads();

  int tx = threadIdx.x & 15, ty = threadIdx.x >> 4;
  int ar[8], br[8], asw[8], bsw[8];
  #pragma unroll
  for (int r = 0; r < 8; ++r) {
    int row = ty * 8 + r, col = tx * 8 + r;
    ar[r] = row * 16; asw[r] = (row >> 3) & 7;
    br[r] = col * 16; bsw[r] = (col >> 3) & 7;
  }

  float acc[8][8];
  #pragma unroll
  for (int r = 0; r < 8; ++r)
    #pragma unroll
    for (int s = 0; s < 8; ++s) acc[r][s] = 0.f;

  #pragma unroll
  for (int c4 = 0; c4 < 16; ++c4) {
    float4 av[8], bv[8];
    #pragma unroll
    for (int r = 0; r < 8; ++r) av[r] = At[ar[r] + (c4 ^ asw[r])];
    #pragma unroll
    for (int s = 0; s < 8; ++s) bv[s] = Bt[br[s] + (c4 ^ bsw[s])];
    #pragma unroll
    for (int r = 0; r < 8; ++r)
      #pragma unroll
      for (int s = 0; s < 8; ++s) {
        acc[r][s] += av[r].x * bv[s].x;
        acc[r][s] += av[r].y * bv[s].y;
        acc[r][s] += av[r].z * bv[s].z;
        acc[r][s] += av[r].w * bv[s].w;
      }
  }

  #pragma unroll
  for (int r = 0; r < 8; ++r) {
    float4 o0, o1;
    o0.x = acc[r][0]; o0.y = acc[r][1]; o0.z = acc[r][2]; o0.w = acc[r][3];
    o1.x = acc[r][4]; o1.y = acc[r][5]; o1.z = acc[r][6]; o1.w = acc[r][7];
    float4* dst = (float4*)(uc + ((size_t)b * NN + i0 + ty * 8 + r) * (2 * O) + j0 + tx * 8);
    dst[0] = o0; dst[1] = o1;
  }
}

// ---------------- layer-1 uc (C=3) ----------------
__global__ __launch_bounds__(256) void uc3_kernel(
    const float* __restrict__ x, const float* __restrict__ w, float* __restrict__ uc) {
  int t = blockIdx.x * 256 + threadIdx.x;   // B*N*128
  int col = t & 127;
  int i = (t >> 7) & (NN - 1);
  int b = t >> 17;
  const float* xr = x + ((size_t)b * NN + i) * 3;
  float x0 = xr[0], x1 = xr[1], x2 = xr[2];
  float r;
  if (col < 64) {
    const float* wr = w + col * 6;
    r = wr[0] * x0 + wr[1] * x1 + wr[2] * x2;
  } else {
    const float* wr = w + (col - 64) * 6;
    r = (wr[3] - wr[0]) * x0 + (wr[4] - wr[1]) * x1 + (wr[5] - wr[2]) * x2;
  }
  uc[(size_t)t] = r;
}

// ---------------- gather-max + BN/ReLU: y[i,o] = relu(s*(max_k u[j_k,o] + c0[i,o]) + b) ----------------
template<int O>
__global__ __launch_bounds__(256) void gathermax_kernel(
    const float* __restrict__ uc,   // (B,N,2O)
    const int*   __restrict__ idx,  // (B,N,K)
    const float* __restrict__ g,
    const float* __restrict__ bb,
    float* __restrict__ y) {        // (B,N,O)
  constexpr int O4 = O / 4;
  int t = blockIdx.x * 256 + threadIdx.x;   // B*N*O4
  int o4 = t & (O4 - 1);
  int rest = t / O4;
  int i = rest & (NN - 1);
  int b = rest >> 10;

  const int* irow = idx + ((size_t)b * NN + i) * KK;
  int jj[KK];
  #pragma unroll
  for (int k = 0; k < KK; ++k) jj[k] = irow[k];

  const float* ucb = uc + (size_t)b * NN * (2 * O);
  float4 vm = make_float4(-INFINITY, -INFINITY, -INFINITY, -INFINITY);
  #pragma unroll
  for (int k = 0; k < KK; ++k) {
    float4 v = *(const float4*)(ucb + (size_t)jj[k] * (2 * O) + o4 * 4);
    vm.x = fmaxf(vm.x, v.x); vm.y = fmaxf(vm.y, v.y);
    vm.z = fmaxf(vm.z, v.z); vm.w = fmaxf(vm.w, v.w);
  }
  float4 c0 = *(const float4*)(ucb + (size_t)i * (2 * O) + O + o4 * 4);
  float4 gv = ((const float4*)g)[o4];
  float4 bv = ((const float4*)bb)[o4];
  const float inv = 1.0f / sqrtf(1.0f + EPSF);
  float4 o;
  o.x = fmaxf((gv.x * inv) * (vm.x + c0.x) + bv.x, 0.f);
  o.y = fmaxf((gv.y * inv) * (vm.y + c0.y) + bv.y, 0.f);
  o.z = fmaxf((gv.z * inv) * (vm.z + c0.z) + bv.z, 0.f);
  o.w = fmaxf((gv.w * inv) * (vm.w + c0.w) + bv.w, 0.f);
  *(float4*)(y + ((size_t)b * NN + i) * O + o4 * 4) = o;
}

// ---------------- global max pool over N ----------------
template<int O>
__global__ __launch_bounds__(256) void pool_kernel(
    const float* __restrict__ y, float* __restrict__ pooled, int ooff) {
  int b = blockIdx.x;
  int ob = blockIdx.y * 64;
  int lane = threadIdx.x & 63, wv = threadIdx.x >> 6;
  int o = ob + lane;
  const float* yb = y + (size_t)b * NN * O;
  float m = -INFINITY;
  for (int i = wv; i < NN; i += 4)
    m = fmaxf(m, yb[(size_t)i * O + o]);
  __shared__ float red[4][64];
  red[wv][lane] = m;
  __syncthreads();
  if (wv == 0) {
    m = fmaxf(fmaxf(red[0][lane], red[1][lane]), fmaxf(red[2][lane], red[3][lane]));
    pooled[b * 320 + ooff + o] = m;
  }
}

// ---------------- fc ----------------
template<int IN, int OUT, bool BNRELU>
__global__ void fc_kernel(const float* __restrict__ in, const float* __restrict__ W,
                          const float* __restrict__ lb, const float* __restrict__ g,
                          const float* __restrict__ bbias, float* __restrict__ out) {
  int t = blockIdx.x * blockDim.x + threadIdx.x;
  if (t >= BB * OUT) return;
  int b = t / OUT, o = t % OUT;
  const float4* iv = (const float4*)(in + (size_t)b * IN);
  const float4* wv = (const float4*)(W + (size_t)o * IN);
  float acc = 0.f;
  for (int c4 = 0; c4 < IN / 4; ++c4) {
    float4 a = iv[c4], ww = wv[c4];
    acc += a.x * ww.x + a.y * ww.y + a.z * ww.z + a.w * ww.w;
  }
  acc += lb[o];
  if (BNRELU) {
    float s = g[o] / sqrtf(1.0f + EPSF);
    acc = fmaxf(acc * s + bbias[o], 0.0f);
  }
  out[t] = acc;
}

extern "C" void kernel_launch(void* const* d_in, const int* in_sizes, int n_in,
                              void* d_out, int out_size, void* d_ws, size_t ws_size,
                              hipStream_t stream) {
  const float* x   = (const float*)d_in[0];
  const float* w1  = (const float*)d_in[1];
  const float* g1  = (const float*)d_in[2];
  const float* b1  = (const float*)d_in[3];
  const float* w2  = (const float*)d_in[4];
  const float* g2  = (const float*)d_in[5];
  const float* b2  = (const float*)d_in[6];
  const float* w3  = (const float*)d_in[7];
  const float* g3  = (const float*)d_in[8];
  const float* b3  = (const float*)d_in[9];
  const float* w4  = (const float*)d_in[10];
  const float* g4  = (const float*)d_in[11];
  const float* b4  = (const float*)d_in[12];
  const float* lw1 = (const float*)d_in[13];
  const float* lb1 = (const float*)d_in[14];
  const float* g5  = (const float*)d_in[15];
  const float* b5  = (const float*)d_in[16];
  const float* lw2 = (const float*)d_in[17];
  const float* lb2 = (const float*)d_in[18];
  const float* g6  = (const float*)d_in[19];
  const float* b6  = (const float*)d_in[20];
  const float* lw3 = (const float*)d_in[21];
  const float* lb3 = (const float*)d_in[22];
  float* out = (float*)d_out;

  char* ws = (char*)d_ws;
  size_t off = 0;
  auto alloc = [&](size_t bytes) -> char* {
    char* p = ws + off;
    off += (bytes + 255) & ~255ULL;
    return p;
  };
  int*   idx    = (int*)  alloc((size_t)BB * NN * KK * 4);
  float* xx     = (float*)alloc((size_t)BB * NN * 4);
  float* xT0    = (float*)alloc((size_t)BB * 3 * NN * 4);
  float* bufA   = (float*)alloc((size_t)BB * NN * 64 * 4);
  float* bufB   = (float*)alloc((size_t)BB * NN * 64 * 4);
  float* bufC   = (float*)alloc((size_t)BB * NN * 128 * 4);
  float* pooled = (float*)alloc((size_t)BB * 320 * 4);
  float* h1     = (float*)alloc((size_t)BB * 1024 * 4);
  float* h2     = (float*)alloc((size_t)BB * 512 * 4);
  u64*   P      = (u64*)  alloc((size_t)BB * NN * NCH * KK * 8);
  float* uc     = (float*)alloc((size_t)BB * NN * 256 * 4);

  size_t dbytes_per_b = (size_t)NN * NN * 4;
  size_t rem = (ws_size > off) ? (ws_size - off) : 0;
  int gmax = (int)(rem / dbytes_per_b);
  if (gmax > 8) gmax = 8;
  if (gmax < 1) gmax = 1;
  float* D = (float*)alloc((size_t)gmax * dbytes_per_b);

  dim3 blk(256);
  int bn_blocks = (BB * NN + 255) / 256;

  auto knn64 = [&](const float* feat) {
    xx_kernel<64><<<bn_blocks, blk, 0, stream>>>(feat, xx);
    for (int b0 = 0; b0 < BB; b0 += gmax) {
      int gg = (BB - b0 < gmax) ? (BB - b0) : gmax;
      dist_kernel<<<dim3(NN / TI, NN / TI, gg), blk, 0, stream>>>(feat, xx, D, b0);
      select_kernel<<<(gg * NCH * NN) / 256, blk, 0, stream>>>(D, P, b0);
    }
    merge_kernel<<<(BB * NN) / 256, blk, 0, stream>>>(P, idx);
  };

  // ---- layer 1 (C=3 -> 64) ----
  transpose3_kernel<<<bn_blocks, blk, 0, stream>>>(x, xT0);
  xx_kernel<3><<<bn_blocks, blk, 0, stream>>>(x, xx);
  select3_kernel<<<(BB * NCH * NN) / 256, blk, 0, stream>>>(x, xT0, xx, P);
  merge_kernel<<<(BB * NN) / 256, blk, 0, stream>>>(P, idx);
  uc3_kernel<<<(BB * NN * 128) / 256, blk, 0, stream>>>(x, w1, uc);
  gathermax_kernel<64><<<(BB * NN * 16) / 256, blk, 0, stream>>>(uc, idx, g1, b1, bufA);
  pool_kernel<64><<<dim3(BB, 1), blk, 0, stream>>>(bufA, pooled, 0);

  // ---- layer 2 (64 -> 64) ----
  knn64(bufA);
  uc_gemm_kernel<64><<<dim3(1, NN / TI, BB), blk, 0, stream>>>(bufA, w2, uc);
  gathermax_kernel<64><<<(BB * NN * 16) / 256, blk, 0, stream>>>(uc, idx, g2, b2, bufB);
  pool_kernel<64><<<dim3(BB, 1), blk, 0, stream>>>(bufB, pooled, 64);

  // ---- layer 3 (64 -> 64) ----
  knn64(bufB);
  uc_gemm_kernel<64><<<dim3(1, NN / TI, BB), blk, 0, stream>>>(bufB, w3, uc);
  gathermax_kernel<64><<<(BB * NN * 16) / 256, blk, 0, stream>>>(uc, idx, g3, b3, bufA);
  pool_kernel<64><<<dim3(BB, 1), blk, 0, stream>>>(bufA, pooled, 128);

  // ---- layer 4 (64 -> 128) ----
  knn64(bufA);
  uc_gemm_kernel<128><<<dim3(2, NN / TI, BB), blk, 0, stream>>>(bufA, w4, uc);
  gathermax_kernel<128><<<(BB * NN * 32) / 256, blk, 0, stream>>>(uc, idx, g4, b4, bufC);
  pool_kernel<128><<<dim3(BB, 2), blk, 0, stream>>>(bufC, pooled, 192);

  // ---- classifier ----
  fc_kernel<320, 1024, true><<<(BB * 1024 + 255) / 256, blk, 0, stream>>>(pooled, lw1, lb1, g5, b5, h1);
  fc_kernel<1024, 512, true><<<(BB * 512 + 255) / 256, blk, 0, stream>>>(h1, lw2, lb2, g6, b6, h2);
  fc_kernel<512, 40, false><<<(BB * 40 + 255) / 256, blk, 0, stream>>>(h2, lw3, lb3, nullptr, nullptr, out);
}

// Round 4
// 1857.460 us; speedup vs baseline: 2.1468x; 2.1468x over previous
//
#include <hip/hip_runtime.h>
#include <math.h>

#define BB 32
#define NN 1024
#define KK 20
typedef unsigned long long u64;
typedef unsigned int u32;
static constexpr float EPSF = 1e-5f;

// ---------------- transpose (B,N,3) -> (B,3,N) ----------------
__global__ void transpose3_kernel(const float* __restrict__ x, float* __restrict__ xT) {
  int t = blockIdx.x * blockDim.x + threadIdx.x;
  if (t >= BB * NN) return;
  int b = t >> 10, i = t & (NN - 1);
  #pragma unroll
  for (int c = 0; c < 3; ++c)
    xT[((size_t)b * 3 + c) * NN + i] = x[(size_t)t * 3 + c];
}

// ---------------- xx = sum(x*x) per point ----------------
template<int C>
__global__ void xx_kernel(const float* __restrict__ x, float* __restrict__ xx) {
  int t = blockIdx.x * blockDim.x + threadIdx.x;
  if (t >= BB * NN) return;
  const float* p = x + (size_t)t * C;
  float s = 0.f;
  #pragma unroll
  for (int c = 0; c < C; ++c) s += p[c] * p[c];
  xx[t] = s;
}

// ---------------- packed key: monotone f32 map in high bits, ~j in low ----------------
__device__ __forceinline__ u64 mkkey(float d, int j) {
  u32 bits = __float_as_uint(d);
  u32 m = (bits & 0x80000000u) ? ~bits : (bits | 0x80000000u);
  return ((u64)m << 32) | (u32)(~(u32)j);
}

__device__ __forceinline__ u64 shflx64(u64 v, int m) {
  u32 lo = __shfl_xor((u32)v, m);
  u32 hi = __shfl_xor((u32)(v >> 32), m);
  return ((u64)hi << 32) | lo;
}

// ---------------- dist GEMM: D[bg][i][j] = 2*dot(x_i,x_j) - xx_j ----------------
#define TI 128
#define CC 64
__global__ __launch_bounds__(256) void dist_kernel(
    const float* __restrict__ x,   // (B,N,64)
    const float* __restrict__ xx,  // (B,N)
    float* __restrict__ D,         // (g,N,N)
    int b0) {
  int b = b0 + blockIdx.z;
  int i0 = blockIdx.y * TI;
  int j0 = blockIdx.x * TI;

  __shared__ float4 At[TI * (CC / 4)];
  __shared__ float4 Bt[TI * (CC / 4)];

  const float4* xa = (const float4*)(x + ((size_t)b * NN + i0) * CC);
  const float4* xb = (const float4*)(x + ((size_t)b * NN + j0) * CC);
  for (int t = threadIdx.x; t < TI * (CC / 4); t += 256) {
    int row = t >> 4, c4 = t & 15;
    int c4s = c4 ^ ((row >> 3) & 7);
    At[row * 16 + c4s] = xa[t];
    Bt[row * 16 + c4s] = xb[t];
  }
  __syncthreads();

  int tx = threadIdx.x & 15, ty = threadIdx.x >> 4;
  int ar[8], br[8], asw[8], bsw[8];
  #pragma unroll
  for (int r = 0; r < 8; ++r) {
    int row = ty * 8 + r, col = tx * 8 + r;
    ar[r] = row * 16; asw[r] = (row >> 3) & 7;
    br[r] = col * 16; bsw[r] = (col >> 3) & 7;
  }

  float acc[8][8];
  #pragma unroll
  for (int r = 0; r < 8; ++r)
    #pragma unroll
    for (int s = 0; s < 8; ++s) acc[r][s] = 0.f;

  #pragma unroll
  for (int c4 = 0; c4 < 16; ++c4) {
    float4 av[8], bv[8];
    #pragma unroll
    for (int r = 0; r < 8; ++r) av[r] = At[ar[r] + (c4 ^ asw[r])];
    #pragma unroll
    for (int s = 0; s < 8; ++s) bv[s] = Bt[br[s] + (c4 ^ bsw[s])];
    #pragma unroll
    for (int r = 0; r < 8; ++r)
      #pragma unroll
      for (int s = 0; s < 8; ++s) {
        acc[r][s] += av[r].x * bv[s].x;
        acc[r][s] += av[r].y * bv[s].y;
        acc[r][s] += av[r].z * bv[s].z;
        acc[r][s] += av[r].w * bv[s].w;
      }
  }

  const float* xxb = xx + (size_t)b * NN;
  float xxj[8];
  #pragma unroll
  for (int s = 0; s < 8; ++s) xxj[s] = xxb[j0 + tx * 8 + s];

  float* Dg = D + (size_t)blockIdx.z * NN * NN;
  #pragma unroll
  for (int r = 0; r < 8; ++r) {
    float4 o0, o1;
    o0.x = 2.f * acc[r][0] - xxj[0];
    o0.y = 2.f * acc[r][1] - xxj[1];
    o0.z = 2.f * acc[r][2] - xxj[2];
    o0.w = 2.f * acc[r][3] - xxj[3];
    o1.x = 2.f * acc[r][4] - xxj[4];
    o1.y = 2.f * acc[r][5] - xxj[5];
    o1.z = 2.f * acc[r][6] - xxj[6];
    o1.w = 2.f * acc[r][7] - xxj[7];
    float4* dst = (float4*)(Dg + (size_t)(i0 + ty * 8 + r) * NN + j0 + tx * 8);
    dst[0] = o0; dst[1] = o1;
  }
}

// ---------------- wave-per-row top-20: butterfly argmax, 20 rounds ----------------
__global__ __launch_bounds__(256) void topk_kernel(
    const float* __restrict__ D, int* __restrict__ oidx, int b0) {
  int wid = (blockIdx.x << 2) + (threadIdx.x >> 6);
  int lane = threadIdx.x & 63;
  int row = wid & (NN - 1);
  int bg = wid >> 10;

  const float4* dp = (const float4*)(D + ((size_t)bg * NN + row) * NN);
  u64 k[16];
  #pragma unroll
  for (int q = 0; q < 4; ++q) {
    int f4i = q * 64 + lane;           // coalesced
    float4 v = dp[f4i];
    int j = f4i * 4;
    k[q * 4 + 0] = mkkey(v.x, j + 0);
    k[q * 4 + 1] = mkkey(v.y, j + 1);
    k[q * 4 + 2] = mkkey(v.z, j + 2);
    k[q * 4 + 3] = mkkey(v.w, j + 3);
  }
  u64 lm = k[0];
  #pragma unroll
  for (int e = 1; e < 16; ++e) lm = k[e] > lm ? k[e] : lm;

  u64 res = 0;
  for (int t = 0; t < KK; ++t) {
    u64 w = lm;
    #pragma unroll
    for (int m = 1; m < 64; m <<= 1) {
      u64 o = shflx64(w, m);
      w = o > w ? o : w;
    }
    if (lane == t) res = w;
    bool win = (lm == w);
    #pragma unroll
    for (int e = 0; e < 16; ++e) k[e] = (k[e] == w) ? 0ull : k[e];
    if (win) {
      u64 m2 = k[0];
      #pragma unroll
      for (int e = 1; e < 16; ++e) m2 = k[e] > m2 ? k[e] : m2;
      lm = m2;
    }
  }
  if (lane < KK)
    oidx[((size_t)(b0 + bg) * NN + row) * KK + lane] = (int)(~(u32)res);
}

// ---------------- layer-1: fused C=3 distance + wave-per-row top-20 ----------------
__global__ __launch_bounds__(256) void topk3_kernel(
    const float* __restrict__ x,   // (B,N,3)
    const float* __restrict__ xT,  // (B,3,N)
    const float* __restrict__ xx,  // (B,N)
    int* __restrict__ oidx) {
  int wid = (blockIdx.x << 2) + (threadIdx.x >> 6);
  int lane = threadIdx.x & 63;
  int row = wid & (NN - 1);
  int b = wid >> 10;

  const float* xr = x + ((size_t)b * NN + row) * 3;
  float x0 = xr[0], x1 = xr[1], x2 = xr[2];
  const float* xTb = xT + (size_t)b * 3 * NN;
  const float* xxb = xx + (size_t)b * NN;

  u64 k[16];
  #pragma unroll
  for (int q = 0; q < 4; ++q) {
    int f4i = q * 64 + lane;
    int j = f4i * 4;
    float4 a  = ((const float4*)xTb)[f4i];
    float4 bv = ((const float4*)(xTb + NN))[f4i];
    float4 c  = ((const float4*)(xTb + 2 * NN))[f4i];
    float4 xj = ((const float4*)xxb)[f4i];
    float d0 = 0.f; d0 += x0 * a.x; d0 += x1 * bv.x; d0 += x2 * c.x;
    float d1 = 0.f; d1 += x0 * a.y; d1 += x1 * bv.y; d1 += x2 * c.y;
    float d2 = 0.f; d2 += x0 * a.z; d2 += x1 * bv.z; d2 += x2 * c.z;
    float d3 = 0.f; d3 += x0 * a.w; d3 += x1 * bv.w; d3 += x2 * c.w;
    k[q * 4 + 0] = mkkey(2.f * d0 - xj.x, j + 0);
    k[q * 4 + 1] = mkkey(2.f * d1 - xj.y, j + 1);
    k[q * 4 + 2] = mkkey(2.f * d2 - xj.z, j + 2);
    k[q * 4 + 3] = mkkey(2.f * d3 - xj.w, j + 3);
  }
  u64 lm = k[0];
  #pragma unroll
  for (int e = 1; e < 16; ++e) lm = k[e] > lm ? k[e] : lm;

  u64 res = 0;
  for (int t = 0; t < KK; ++t) {
    u64 w = lm;
    #pragma unroll
    for (int m = 1; m < 64; m <<= 1) {
      u64 o = shflx64(w, m);
      w = o > w ? o : w;
    }
    if (lane == t) res = w;
    bool win = (lm == w);
    #pragma unroll
    for (int e = 0; e < 16; ++e) k[e] = (k[e] == w) ? 0ull : k[e];
    if (win) {
      u64 m2 = k[0];
      #pragma unroll
      for (int e = 1; e < 16; ++e) m2 = k[e] > m2 ? k[e] : m2;
      lm = m2;
    }
  }
  if (lane < KK)
    oidx[((size_t)b * NN + row) * KK + lane] = (int)(~(u32)res);
}

// ---------------- uc part GEMM: uc[b,i,PART*O+col] ----------------
// PART 0: Wa . x_i ; PART 1: (Wb - Wa) . x_i.  W half staged in swizzled LDS.
template<int O, int PART>
__global__ __launch_bounds__(256) void ucpart_kernel(
    const float* __restrict__ x,   // (B,N,64)
    const float* __restrict__ w,   // (O,128)
    float* __restrict__ uc) {      // (B,N,2O)
  constexpr int PPT = 32 * O / 256;   // points per thread: O=64 -> 8, O=128 -> 16
  __shared__ float4 Ws[O * 16];
  __shared__ float4 As[32 * 16];

  int tile = blockIdx.x;             // B*N/32 tiles
  int b = tile >> 5;
  int i0 = (tile & 31) * 32;

  const float4* w4 = (const float4*)w;
  for (int r = threadIdx.x; r < O * 16; r += 256) {
    int rowc = r >> 4, c4 = r & 15;
    float4 v;
    if (PART == 0) {
      v = w4[(size_t)rowc * 32 + c4];
    } else {
      float4 lo = w4[(size_t)rowc * 32 + c4];
      float4 hi = w4[(size_t)rowc * 32 + 16 + c4];
      v = make_float4(hi.x - lo.x, hi.y - lo.y, hi.z - lo.z, hi.w - lo.w);
    }
    Ws[(rowc << 4) + (c4 ^ (rowc & 7))] = v;
  }
  const float4* xa = (const float4*)(x + ((size_t)b * NN + i0) * CC);
  for (int r = threadIdx.x; r < 32 * 16; r += 256) As[r] = xa[r];
  __syncthreads();

  int col = threadIdx.x % O;
  int pg = threadIdx.x / O;
  float4 wc[16];
  #pragma unroll
  for (int c4 = 0; c4 < 16; ++c4) wc[c4] = Ws[(col << 4) + (c4 ^ (col & 7))];

  #pragma unroll
  for (int pp = 0; pp < PPT; ++pp) {
    int p = pg * PPT + pp;
    float acc = 0.f;
    #pragma unroll
    for (int c4 = 0; c4 < 16; ++c4) {
      float4 a = As[(p << 4) + c4];
      acc += a.x * wc[c4].x; acc += a.y * wc[c4].y;
      acc += a.z * wc[c4].z; acc += a.w * wc[c4].w;
    }
    uc[((size_t)b * NN + i0 + p) * (2 * O) + PART * O + col] = acc;
  }
}

// ---------------- layer-1 uc (C=3) ----------------
__global__ __launch_bounds__(256) void uc3_kernel(
    const float* __restrict__ x, const float* __restrict__ w, float* __restrict__ uc) {
  int t = blockIdx.x * 256 + threadIdx.x;   // B*N*128
  int col = t & 127;
  int i = (t >> 7) & (NN - 1);
  int b = t >> 17;
  const float* xr = x + ((size_t)b * NN + i) * 3;
  float x0 = xr[0], x1 = xr[1], x2 = xr[2];
  float r;
  if (col < 64) {
    const float* wr = w + col * 6;
    r = wr[0] * x0 + wr[1] * x1 + wr[2] * x2;
  } else {
    const float* wr = w + (col - 64) * 6;
    r = (wr[3] - wr[0]) * x0 + (wr[4] - wr[1]) * x1 + (wr[5] - wr[2]) * x2;
  }
  uc[(size_t)t] = r;
}

// ---------------- gather-max + BN/ReLU ----------------
template<int O>
__global__ __launch_bounds__(256) void gathermax_kernel(
    const float* __restrict__ uc,   // (B,N,2O)
    const int*   __restrict__ idx,  // (B,N,K)
    const float* __restrict__ g,
    const float* __restrict__ bb,
    float* __restrict__ y) {        // (B,N,O)
  constexpr int O4 = O / 4;
  int t = blockIdx.x * 256 + threadIdx.x;   // B*N*O4
  int o4 = t & (O4 - 1);
  int rest = t / O4;
  int i = rest & (NN - 1);
  int b = rest >> 10;

  const int* irow = idx + ((size_t)b * NN + i) * KK;
  int jj[KK];
  #pragma unroll
  for (int k = 0; k < KK; ++k) jj[k] = irow[k];

  const float* ucb = uc + (size_t)b * NN * (2 * O);
  float4 vm = make_float4(-INFINITY, -INFINITY, -INFINITY, -INFINITY);
  #pragma unroll
  for (int k = 0; k < KK; ++k) {
    float4 v = *(const float4*)(ucb + (size_t)jj[k] * (2 * O) + o4 * 4);
    vm.x = fmaxf(vm.x, v.x); vm.y = fmaxf(vm.y, v.y);
    vm.z = fmaxf(vm.z, v.z); vm.w = fmaxf(vm.w, v.w);
  }
  float4 c0 = *(const float4*)(ucb + (size_t)i * (2 * O) + O + o4 * 4);
  float4 gv = ((const float4*)g)[o4];
  float4 bv = ((const float4*)bb)[o4];
  const float inv = 1.0f / sqrtf(1.0f + EPSF);
  float4 o;
  o.x = fmaxf((gv.x * inv) * (vm.x + c0.x) + bv.x, 0.f);
  o.y = fmaxf((gv.y * inv) * (vm.y + c0.y) + bv.y, 0.f);
  o.z = fmaxf((gv.z * inv) * (vm.z + c0.z) + bv.z, 0.f);
  o.w = fmaxf((gv.w * inv) * (vm.w + c0.w) + bv.w, 0.f);
  *(float4*)(y + ((size_t)b * NN + i) * O + o4 * 4) = o;
}

// ---------------- global max pool over N ----------------
template<int O>
__global__ __launch_bounds__(256) void pool_kernel(
    const float* __restrict__ y, float* __restrict__ pooled, int ooff) {
  int b = blockIdx.x;
  int ob = blockIdx.y * 64;
  int lane = threadIdx.x & 63, wv = threadIdx.x >> 6;
  int o = ob + lane;
  const float* yb = y + (size_t)b * NN * O;
  float m = -INFINITY;
  for (int i = wv; i < NN; i += 4)
    m = fmaxf(m, yb[(size_t)i * O + o]);
  __shared__ float red[4][64];
  red[wv][lane] = m;
  __syncthreads();
  if (wv == 0) {
    m = fmaxf(fmaxf(red[0][lane], red[1][lane]), fmaxf(red[2][lane], red[3][lane]));
    pooled[b * 320 + ooff + o] = m;
  }
}

// ---------------- fc ----------------
template<int IN, int OUT, bool BNRELU>
__global__ void fc_kernel(const float* __restrict__ in, const float* __restrict__ W,
                          const float* __restrict__ lb, const float* __restrict__ g,
                          const float* __restrict__ bbias, float* __restrict__ out) {
  int t = blockIdx.x * blockDim.x + threadIdx.x;
  if (t >= BB * OUT) return;
  int b = t / OUT, o = t % OUT;
  const float4* iv = (const float4*)(in + (size_t)b * IN);
  const float4* wv = (const float4*)(W + (size_t)o * IN);
  float acc = 0.f;
  for (int c4 = 0; c4 < IN / 4; ++c4) {
    float4 a = iv[c4], ww = wv[c4];
    acc += a.x * ww.x + a.y * ww.y + a.z * ww.z + a.w * ww.w;
  }
  acc += lb[o];
  if (BNRELU) {
    float s = g[o] / sqrtf(1.0f + EPSF);
    acc = fmaxf(acc * s + bbias[o], 0.0f);
  }
  out[t] = acc;
}

extern "C" void kernel_launch(void* const* d_in, const int* in_sizes, int n_in,
                              void* d_out, int out_size, void* d_ws, size_t ws_size,
                              hipStream_t stream) {
  const float* x   = (const float*)d_in[0];
  const float* w1  = (const float*)d_in[1];
  const float* g1  = (const float*)d_in[2];
  const float* b1  = (const float*)d_in[3];
  const float* w2  = (const float*)d_in[4];
  const float* g2  = (const float*)d_in[5];
  const float* b2  = (const float*)d_in[6];
  const float* w3  = (const float*)d_in[7];
  const float* g3  = (const float*)d_in[8];
  const float* b3  = (const float*)d_in[9];
  const float* w4  = (const float*)d_in[10];
  const float* g4  = (const float*)d_in[11];
  const float* b4  = (const float*)d_in[12];
  const float* lw1 = (const float*)d_in[13];
  const float* lb1 = (const float*)d_in[14];
  const float* g5  = (const float*)d_in[15];
  const float* b5  = (const float*)d_in[16];
  const float* lw2 = (const float*)d_in[17];
  const float* lb2 = (const float*)d_in[18];
  const float* g6  = (const float*)d_in[19];
  const float* b6  = (const float*)d_in[20];
  const float* lw3 = (const float*)d_in[21];
  const float* lb3 = (const float*)d_in[22];
  float* out = (float*)d_out;

  char* ws = (char*)d_ws;
  size_t off = 0;
  auto alloc = [&](size_t bytes) -> char* {
    char* p = ws + off;
    off += (bytes + 255) & ~255ULL;
    return p;
  };
  int*   idx    = (int*)  alloc((size_t)BB * NN * KK * 4);
  float* xx     = (float*)alloc((size_t)BB * NN * 4);
  float* xT0    = (float*)alloc((size_t)BB * 3 * NN * 4);
  float* bufA   = (float*)alloc((size_t)BB * NN * 64 * 4);
  float* bufB   = (float*)alloc((size_t)BB * NN * 64 * 4);
  float* bufC   = (float*)alloc((size_t)BB * NN * 128 * 4);
  float* pooled = (float*)alloc((size_t)BB * 320 * 4);
  float* h1     = (float*)alloc((size_t)BB * 1024 * 4);
  float* h2     = (float*)alloc((size_t)BB * 512 * 4);
  float* uc     = (float*)alloc((size_t)BB * NN * 256 * 4);

  size_t dbytes_per_b = (size_t)NN * NN * 4;
  size_t rem = (ws_size > off) ? (ws_size - off) : 0;
  int gmax = (int)(rem / dbytes_per_b);
  if (gmax > 8) gmax = 8;
  if (gmax < 1) gmax = 1;
  float* D = (float*)alloc((size_t)gmax * dbytes_per_b);

  dim3 blk(256);
  int bn_blocks = (BB * NN + 255) / 256;

  auto knn64 = [&](const float* feat) {
    xx_kernel<64><<<bn_blocks, blk, 0, stream>>>(feat, xx);
    for (int b0 = 0; b0 < BB; b0 += gmax) {
      int gg = (BB - b0 < gmax) ? (BB - b0) : gmax;
      dist_kernel<<<dim3(NN / TI, NN / TI, gg), blk, 0, stream>>>(feat, xx, D, b0);
      topk_kernel<<<(gg * NN) / 4, blk, 0, stream>>>(D, idx, b0);
    }
  };

  // ---- layer 1 (C=3 -> 64) ----
  transpose3_kernel<<<bn_blocks, blk, 0, stream>>>(x, xT0);
  xx_kernel<3><<<bn_blocks, blk, 0, stream>>>(x, xx);
  topk3_kernel<<<(BB * NN) / 4, blk, 0, stream>>>(x, xT0, xx, idx);
  uc3_kernel<<<(BB * NN * 128) / 256, blk, 0, stream>>>(x, w1, uc);
  gathermax_kernel<64><<<(BB * NN * 16) / 256, blk, 0, stream>>>(uc, idx, g1, b1, bufA);
  pool_kernel<64><<<dim3(BB, 1), blk, 0, stream>>>(bufA, pooled, 0);

  // ---- layer 2 (64 -> 64) ----
  knn64(bufA);
  ucpart_kernel<64, 0><<<(BB * NN) / 32, blk, 0, stream>>>(bufA, w2, uc);
  ucpart_kernel<64, 1><<<(BB * NN) / 32, blk, 0, stream>>>(bufA, w2, uc);
  gathermax_kernel<64><<<(BB * NN * 16) / 256, blk, 0, stream>>>(uc, idx, g2, b2, bufB);
  pool_kernel<64><<<dim3(BB, 1), blk, 0, stream>>>(bufB, pooled, 64);

  // ---- layer 3 (64 -> 64) ----
  knn64(bufB);
  ucpart_kernel<64, 0><<<(BB * NN) / 32, blk, 0, stream>>>(bufB, w3, uc);
  ucpart_kernel<64, 1><<<(BB * NN) / 32, blk, 0, stream>>>(bufB, w3, uc);
  gathermax_kernel<64><<<(BB * NN * 16) / 256, blk, 0, stream>>>(uc, idx, g3, b3, bufA);
  pool_kernel<64><<<dim3(BB, 1), blk, 0, stream>>>(bufA, pooled, 128);

  // ---- layer 4 (64 -> 128) ----
  knn64(bufA);
  ucpart_kernel<128, 0><<<(BB * NN) / 32, blk, 0, stream>>>(bufA, w4, uc);
  ucpart_kernel<128, 1><<<(BB * NN) / 32, blk, 0, stream>>>(bufA, w4, uc);
  gathermax_kernel<128><<<(BB * NN * 32) / 256, blk, 0, stream>>>(uc, idx, g4, b4, bufC);
  pool_kernel<128><<<dim3(BB, 2), blk, 0, stream>>>(bufC, pooled, 192);

  // ---- classifier ----
  fc_kernel<320, 1024, true><<<(BB * 1024 + 255) / 256, blk, 0, stream>>>(pooled, lw1, lb1, g5, b5, h1);
  fc_kernel<1024, 512, true><<<(BB * 512 + 255) / 256, blk, 0, stream>>>(h1, lw2, lb2, g6, b6, h2);
  fc_kernel<512, 40, false><<<(BB * 40 + 255) / 256, blk, 0, stream>>>(h2, lw3, lb3, nullptr, nullptr, out);
}

// Round 5
// 1021.687 us; speedup vs baseline: 3.9030x; 1.8180x over previous
//
#include <hip/hip_runtime.h>
#include <math.h>

#define BB 32
#define NN 1024
#define KK 20
typedef unsigned long long u64;
typedef unsigned int u32;
static constexpr float EPSF = 1e-5f;

// ---------------- fused transpose (B,N,3)->(B,3,N) + xx ----------------
__global__ void t3xx_kernel(const float* __restrict__ x, float* __restrict__ xT,
                            float* __restrict__ xx) {
  int t = blockIdx.x * blockDim.x + threadIdx.x;
  if (t >= BB * NN) return;
  int b = t >> 10, i = t & (NN - 1);
  float v0 = x[(size_t)t * 3 + 0], v1 = x[(size_t)t * 3 + 1], v2 = x[(size_t)t * 3 + 2];
  xT[((size_t)b * 3 + 0) * NN + i] = v0;
  xT[((size_t)b * 3 + 1) * NN + i] = v1;
  xT[((size_t)b * 3 + 2) * NN + i] = v2;
  float s = 0.f;
  s += v0 * v0; s += v1 * v1; s += v2 * v2;
  xx[t] = s;
}

// ---------------- xx = sum(x*x), C=64 ----------------
__global__ void xx64_kernel(const float* __restrict__ x, float* __restrict__ xx) {
  int t = blockIdx.x * blockDim.x + threadIdx.x;
  if (t >= BB * NN) return;
  const float* p = x + (size_t)t * 64;
  float s = 0.f;
  #pragma unroll
  for (int c = 0; c < 64; ++c) s += p[c] * p[c];
  xx[t] = s;
}

// ---------------- zero pooled ----------------
__global__ void zero_kernel(float* __restrict__ p, int n) {
  int t = blockIdx.x * blockDim.x + threadIdx.x;
  if (t < n) p[t] = 0.0f;
}

// ---------------- exact-integer f64 key: m(d)*1024 + (1023-j) ----------------
__device__ __forceinline__ double mkkeyd(float d, double idxd) {
  u32 bits = __float_as_uint(d);
  u32 m = (bits & 0x80000000u) ? ~bits : (bits | 0x80000000u);
  return fma((double)m, 1024.0, idxd);
}

// Batcher odd-even merge sort, 16 doubles descending (compile-time network)
__device__ __forceinline__ void sort16(double (&k)[16]) {
  #pragma unroll
  for (int p = 1; p < 16; p <<= 1)
    #pragma unroll
    for (int kq = p; kq >= 1; kq >>= 1)
      #pragma unroll
      for (int j = kq & (p - 1); j + kq < 16; j += 2 * kq)
        #pragma unroll
        for (int i = 0; i < kq; ++i)
          if (i + j + kq < 16)
            if (((i + j) / (2 * p)) == ((i + j + kq) / (2 * p))) {
              double a = k[i + j], c = k[i + j + kq];
              k[i + j] = fmax(a, c);
              k[i + j + kq] = fmin(a, c);
            }
}

// shared tournament: 20 rounds of wave-max + sorted pop; writes KK indices
__device__ __forceinline__ void tourney_out(double (&k)[16], int lane, int* __restrict__ orow) {
  sort16(k);
  double lm = k[0];
  double res = 0.0;
  #pragma unroll
  for (int t = 0; t < KK; ++t) {
    double w = lm;
    #pragma unroll
    for (int m = 1; m < 64; m <<= 1)
      w = fmax(w, __shfl_xor(w, m));
    if (lane == t) res = w;
    bool win = (lm == w);
    #pragma unroll
    for (int e = 0; e < 15; ++e) k[e] = win ? k[e + 1] : k[e];
    k[15] = win ? 0.0 : k[15];
    lm = win ? k[0] : lm;
  }
  if (lane < KK) {
    double md = trunc(res * (1.0 / 1024.0));       // exact
    double rd = fma(md, -1024.0, res);             // exact remainder
    int r = (int)rd;
    orow[lane] = 1023 - r;
  }
}

// ---------------- dist GEMM: D[bg][i][j] = 2*dot(x_i,x_j) - xx_j ----------------
#define TI 128
#define CC 64
__global__ __launch_bounds__(256) void dist_kernel(
    const float* __restrict__ x,   // (B,N,64)
    const float* __restrict__ xx,  // (B,N)
    float* __restrict__ D,         // (g,N,N)
    int b0) {
  int b = b0 + blockIdx.z;
  int i0 = blockIdx.y * TI;
  int j0 = blockIdx.x * TI;

  __shared__ float4 At[TI * (CC / 4)];
  __shared__ float4 Bt[TI * (CC / 4)];

  const float4* xa = (const float4*)(x + ((size_t)b * NN + i0) * CC);
  const float4* xb = (const float4*)(x + ((size_t)b * NN + j0) * CC);
  for (int t = threadIdx.x; t < TI * (CC / 4); t += 256) {
    int row = t >> 4, c4 = t & 15;
    int c4s = c4 ^ ((row >> 3) & 7);
    At[row * 16 + c4s] = xa[t];
    Bt[row * 16 + c4s] = xb[t];
  }
  __syncthreads();

  int tx = threadIdx.x & 15, ty = threadIdx.x >> 4;
  int ar[8], br[8], asw[8], bsw[8];
  #pragma unroll
  for (int r = 0; r < 8; ++r) {
    int row = ty * 8 + r, col = tx * 8 + r;
    ar[r] = row * 16; asw[r] = (row >> 3) & 7;
    br[r] = col * 16; bsw[r] = (col >> 3) & 7;
  }

  float acc[8][8];
  #pragma unroll
  for (int r = 0; r < 8; ++r)
    #pragma unroll
    for (int s = 0; s < 8; ++s) acc[r][s] = 0.f;

  #pragma unroll
  for (int c4 = 0; c4 < 16; ++c4) {
    float4 av[8], bv[8];
    #pragma unroll
    for (int r = 0; r < 8; ++r) av[r] = At[ar[r] + (c4 ^ asw[r])];
    #pragma unroll
    for (int s = 0; s < 8; ++s) bv[s] = Bt[br[s] + (c4 ^ bsw[s])];
    #pragma unroll
    for (int r = 0; r < 8; ++r)
      #pragma unroll
      for (int s = 0; s < 8; ++s) {
        acc[r][s] += av[r].x * bv[s].x;
        acc[r][s] += av[r].y * bv[s].y;
        acc[r][s] += av[r].z * bv[s].z;
        acc[r][s] += av[r].w * bv[s].w;
      }
  }

  const float* xxb = xx + (size_t)b * NN;
  float xxj[8];
  #pragma unroll
  for (int s = 0; s < 8; ++s) xxj[s] = xxb[j0 + tx * 8 + s];

  float* Dg = D + (size_t)blockIdx.z * NN * NN;
  #pragma unroll
  for (int r = 0; r < 8; ++r) {
    float4 o0, o1;
    o0.x = 2.f * acc[r][0] - xxj[0];
    o0.y = 2.f * acc[r][1] - xxj[1];
    o0.z = 2.f * acc[r][2] - xxj[2];
    o0.w = 2.f * acc[r][3] - xxj[3];
    o1.x = 2.f * acc[r][4] - xxj[4];
    o1.y = 2.f * acc[r][5] - xxj[5];
    o1.z = 2.f * acc[r][6] - xxj[6];
    o1.w = 2.f * acc[r][7] - xxj[7];
    float4* dst = (float4*)(Dg + (size_t)(i0 + ty * 8 + r) * NN + j0 + tx * 8);
    dst[0] = o0; dst[1] = o1;
  }
}

// ---------------- wave-per-row top-20 (f64 keys, sorted pop) ----------------
__global__ __launch_bounds__(256) void topk_kernel(
    const float* __restrict__ D, int* __restrict__ oidx, int b0) {
  int wid = (blockIdx.x << 2) + (threadIdx.x >> 6);
  int lane = threadIdx.x & 63;
  int row = wid & (NN - 1);
  int bg = wid >> 10;

  const float4* dp = (const float4*)(D + ((size_t)bg * NN + row) * NN);
  double k[16];
  double based = (double)(1023 - lane * 4);
  #pragma unroll
  for (int q = 0; q < 4; ++q) {
    float4 v = dp[q * 64 + lane];
    double qb = based - (double)(q * 256);
    k[q * 4 + 0] = mkkeyd(v.x, qb - 0.0);
    k[q * 4 + 1] = mkkeyd(v.y, qb - 1.0);
    k[q * 4 + 2] = mkkeyd(v.z, qb - 2.0);
    k[q * 4 + 3] = mkkeyd(v.w, qb - 3.0);
  }
  tourney_out(k, lane, oidx + ((size_t)(b0 + bg) * NN + row) * KK);
}

// ---------------- layer-1: fused C=3 distance + top-20 ----------------
__global__ __launch_bounds__(256) void topk3_kernel(
    const float* __restrict__ x,   // (B,N,3)
    const float* __restrict__ xT,  // (B,3,N)
    const float* __restrict__ xx,  // (B,N)
    int* __restrict__ oidx) {
  int wid = (blockIdx.x << 2) + (threadIdx.x >> 6);
  int lane = threadIdx.x & 63;
  int row = wid & (NN - 1);
  int b = wid >> 10;

  const float* xr = x + ((size_t)b * NN + row) * 3;
  float x0 = xr[0], x1 = xr[1], x2 = xr[2];
  const float* xTb = xT + (size_t)b * 3 * NN;
  const float* xxb = xx + (size_t)b * NN;

  double k[16];
  double based = (double)(1023 - lane * 4);
  #pragma unroll
  for (int q = 0; q < 4; ++q) {
    int f4i = q * 64 + lane;
    float4 a  = ((const float4*)xTb)[f4i];
    float4 bv = ((const float4*)(xTb + NN))[f4i];
    float4 c  = ((const float4*)(xTb + 2 * NN))[f4i];
    float4 xj = ((const float4*)xxb)[f4i];
    float d0 = 0.f; d0 += x0 * a.x; d0 += x1 * bv.x; d0 += x2 * c.x;
    float d1 = 0.f; d1 += x0 * a.y; d1 += x1 * bv.y; d1 += x2 * c.y;
    float d2 = 0.f; d2 += x0 * a.z; d2 += x1 * bv.z; d2 += x2 * c.z;
    float d3 = 0.f; d3 += x0 * a.w; d3 += x1 * bv.w; d3 += x2 * c.w;
    double qb = based - (double)(q * 256);
    k[q * 4 + 0] = mkkeyd(2.f * d0 - xj.x, qb - 0.0);
    k[q * 4 + 1] = mkkeyd(2.f * d1 - xj.y, qb - 1.0);
    k[q * 4 + 2] = mkkeyd(2.f * d2 - xj.z, qb - 2.0);
    k[q * 4 + 3] = mkkeyd(2.f * d3 - xj.w, qb - 3.0);
  }
  tourney_out(k, lane, oidx + ((size_t)b * NN + row) * KK);
}

// ---------------- uc part GEMM (both parts via blockIdx.y) ----------------
// part 0: Wa . x_i ; part 1: (Wb - Wa) . x_i.  W half staged in swizzled LDS.
template<int O>
__global__ __launch_bounds__(256) void ucpart_kernel(
    const float* __restrict__ x,   // (B,N,64)
    const float* __restrict__ w,   // (O,128)
    float* __restrict__ uc) {      // (B,N,2O)
  constexpr int PPT = 32 * O / 256;
  __shared__ float4 Ws[O * 16];
  __shared__ float4 As[32 * 16];

  int part = blockIdx.y;
  int tile = blockIdx.x;             // B*N/32 tiles
  int b = tile >> 5;
  int i0 = (tile & 31) * 32;

  const float4* w4 = (const float4*)w;
  for (int r = threadIdx.x; r < O * 16; r += 256) {
    int rowc = r >> 4, c4 = r & 15;
    float4 v;
    if (part == 0) {
      v = w4[(size_t)rowc * 32 + c4];
    } else {
      float4 lo = w4[(size_t)rowc * 32 + c4];
      float4 hi = w4[(size_t)rowc * 32 + 16 + c4];
      v = make_float4(hi.x - lo.x, hi.y - lo.y, hi.z - lo.z, hi.w - lo.w);
    }
    Ws[(rowc << 4) + (c4 ^ (rowc & 7))] = v;
  }
  const float4* xa = (const float4*)(x + ((size_t)b * NN + i0) * CC);
  for (int r = threadIdx.x; r < 32 * 16; r += 256) As[r] = xa[r];
  __syncthreads();

  int col = threadIdx.x % O;
  int pg = threadIdx.x / O;
  float4 wc[16];
  #pragma unroll
  for (int c4 = 0; c4 < 16; ++c4) wc[c4] = Ws[(col << 4) + (c4 ^ (col & 7))];

  #pragma unroll
  for (int pp = 0; pp < PPT; ++pp) {
    int p = pg * PPT + pp;
    float acc = 0.f;
    #pragma unroll
    for (int c4 = 0; c4 < 16; ++c4) {
      float4 a = As[(p << 4) + c4];
      acc += a.x * wc[c4].x; acc += a.y * wc[c4].y;
      acc += a.z * wc[c4].z; acc += a.w * wc[c4].w;
    }
    uc[((size_t)b * NN + i0 + p) * (2 * O) + part * O + col] = acc;
  }
}

// ---------------- layer-1 uc (C=3) ----------------
__global__ __launch_bounds__(256) void uc3_kernel(
    const float* __restrict__ x, const float* __restrict__ w, float* __restrict__ uc) {
  int t = blockIdx.x * 256 + threadIdx.x;   // B*N*128
  int col = t & 127;
  int i = (t >> 7) & (NN - 1);
  int b = t >> 17;
  const float* xr = x + ((size_t)b * NN + i) * 3;
  float x0 = xr[0], x1 = xr[1], x2 = xr[2];
  float r;
  if (col < 64) {
    const float* wr = w + col * 6;
    r = wr[0] * x0 + wr[1] * x1 + wr[2] * x2;
  } else {
    const float* wr = w + (col - 64) * 6;
    r = (wr[3] - wr[0]) * x0 + (wr[4] - wr[1]) * x1 + (wr[5] - wr[2]) * x2;
  }
  uc[(size_t)t] = r;
}

// ---------------- gather-max + BN/ReLU + fused global-pool (atomicMax) ----------------
template<int O>
__global__ __launch_bounds__(256) void gmp_kernel(
    const float* __restrict__ uc,   // (B,N,2O)
    const int*   __restrict__ idx,  // (B,N,K)
    const float* __restrict__ g,
    const float* __restrict__ bb,
    float* __restrict__ y,          // (B,N,O)
    u32* __restrict__ pooled,       // (B,320) as u32 bit patterns (all >= 0)
    int ooff) {
  constexpr int O4 = O / 4;
  constexpr int IPB = 256 / O4;
  int t = blockIdx.x * 256 + threadIdx.x;   // B*N*O4, o4 fastest
  int o4 = t & (O4 - 1);
  int rest = t / O4;
  int i = rest & (NN - 1);
  int b = rest >> 10;

  const int* irow = idx + ((size_t)b * NN + i) * KK;
  int jj[KK];
  #pragma unroll
  for (int k = 0; k < KK; ++k) jj[k] = irow[k];

  const float* ucb = uc + (size_t)b * NN * (2 * O);
  float4 vm = make_float4(-INFINITY, -INFINITY, -INFINITY, -INFINITY);
  #pragma unroll
  for (int k = 0; k < KK; ++k) {
    float4 v = *(const float4*)(ucb + (size_t)jj[k] * (2 * O) + o4 * 4);
    vm.x = fmaxf(vm.x, v.x); vm.y = fmaxf(vm.y, v.y);
    vm.z = fmaxf(vm.z, v.z); vm.w = fmaxf(vm.w, v.w);
  }
  float4 c0 = *(const float4*)(ucb + (size_t)i * (2 * O) + O + o4 * 4);
  float4 gv = ((const float4*)g)[o4];
  float4 bv = ((const float4*)bb)[o4];
  const float inv = 1.0f / sqrtf(1.0f + EPSF);
  float4 o;
  o.x = fmaxf((gv.x * inv) * (vm.x + c0.x) + bv.x, 0.f);
  o.y = fmaxf((gv.y * inv) * (vm.y + c0.y) + bv.y, 0.f);
  o.z = fmaxf((gv.z * inv) * (vm.z + c0.z) + bv.z, 0.f);
  o.w = fmaxf((gv.w * inv) * (vm.w + c0.w) + bv.w, 0.f);
  *(float4*)(y + ((size_t)b * NN + i) * O + o4 * 4) = o;

  // block-partial max over the IPB points, then one atomic per component
  __shared__ float4 sm[256];
  sm[threadIdx.x] = o;
  __syncthreads();
  if (threadIdx.x < O4) {
    float4 m = sm[threadIdx.x];
    #pragma unroll
    for (int r = 1; r < IPB; ++r) {
      float4 v = sm[threadIdx.x + r * O4];
      m.x = fmaxf(m.x, v.x); m.y = fmaxf(m.y, v.y);
      m.z = fmaxf(m.z, v.z); m.w = fmaxf(m.w, v.w);
    }
    u32* dst = pooled + (size_t)b * 320 + ooff + threadIdx.x * 4;
    atomicMax(dst + 0, __float_as_uint(m.x));
    atomicMax(dst + 1, __float_as_uint(m.y));
    atomicMax(dst + 2, __float_as_uint(m.z));
    atomicMax(dst + 3, __float_as_uint(m.w));
  }
}

// ---------------- fc ----------------
template<int IN, int OUT, bool BNRELU>
__global__ void fc_kernel(const float* __restrict__ in, const float* __restrict__ W,
                          const float* __restrict__ lb, const float* __restrict__ g,
                          const float* __restrict__ bbias, float* __restrict__ out) {
  int t = blockIdx.x * blockDim.x + threadIdx.x;
  if (t >= BB * OUT) return;
  int b = t / OUT, o = t % OUT;
  const float4* iv = (const float4*)(in + (size_t)b * IN);
  const float4* wv = (const float4*)(W + (size_t)o * IN);
  float acc = 0.f;
  for (int c4 = 0; c4 < IN / 4; ++c4) {
    float4 a = iv[c4], ww = wv[c4];
    acc += a.x * ww.x + a.y * ww.y + a.z * ww.z + a.w * ww.w;
  }
  acc += lb[o];
  if (BNRELU) {
    float s = g[o] / sqrtf(1.0f + EPSF);
    acc = fmaxf(acc * s + bbias[o], 0.0f);
  }
  out[t] = acc;
}

extern "C" void kernel_launch(void* const* d_in, const int* in_sizes, int n_in,
                              void* d_out, int out_size, void* d_ws, size_t ws_size,
                              hipStream_t stream) {
  const float* x   = (const float*)d_in[0];
  const float* w1  = (const float*)d_in[1];
  const float* g1  = (const float*)d_in[2];
  const float* b1  = (const float*)d_in[3];
  const float* w2  = (const float*)d_in[4];
  const float* g2  = (const float*)d_in[5];
  const float* b2  = (const float*)d_in[6];
  const float* w3  = (const float*)d_in[7];
  const float* g3  = (const float*)d_in[8];
  const float* b3  = (const float*)d_in[9];
  const float* w4  = (const float*)d_in[10];
  const float* g4  = (const float*)d_in[11];
  const float* b4  = (const float*)d_in[12];
  const float* lw1 = (const float*)d_in[13];
  const float* lb1 = (const float*)d_in[14];
  const float* g5  = (const float*)d_in[15];
  const float* b5  = (const float*)d_in[16];
  const float* lw2 = (const float*)d_in[17];
  const float* lb2 = (const float*)d_in[18];
  const float* g6  = (const float*)d_in[19];
  const float* b6  = (const float*)d_in[20];
  const float* lw3 = (const float*)d_in[21];
  const float* lb3 = (const float*)d_in[22];
  float* out = (float*)d_out;

  char* ws = (char*)d_ws;
  size_t off = 0;
  auto alloc = [&](size_t bytes) -> char* {
    char* p = ws + off;
    off += (bytes + 255) & ~255ULL;
    return p;
  };
  int*   idx    = (int*)  alloc((size_t)BB * NN * KK * 4);
  float* xx     = (float*)alloc((size_t)BB * NN * 4);
  float* xT0    = (float*)alloc((size_t)BB * 3 * NN * 4);
  float* bufA   = (float*)alloc((size_t)BB * NN * 64 * 4);
  float* bufB   = (float*)alloc((size_t)BB * NN * 64 * 4);
  float* bufC   = (float*)alloc((size_t)BB * NN * 128 * 4);
  float* pooled = (float*)alloc((size_t)BB * 320 * 4);
  float* h1     = (float*)alloc((size_t)BB * 1024 * 4);
  float* h2     = (float*)alloc((size_t)BB * 512 * 4);
  float* uc     = (float*)alloc((size_t)BB * NN * 256 * 4);

  size_t dbytes_per_b = (size_t)NN * NN * 4;
  size_t rem = (ws_size > off) ? (ws_size - off) : 0;
  int gmax = (int)(rem / dbytes_per_b);
  if (gmax > 32) gmax = 32;
  if (gmax < 1) gmax = 1;
  float* D = (float*)alloc((size_t)gmax * dbytes_per_b);

  dim3 blk(256);
  int bn_blocks = (BB * NN + 255) / 256;

  auto knn64 = [&](const float* feat) {
    xx64_kernel<<<bn_blocks, blk, 0, stream>>>(feat, xx);
    for (int b0 = 0; b0 < BB; b0 += gmax) {
      int gg = (BB - b0 < gmax) ? (BB - b0) : gmax;
      dist_kernel<<<dim3(NN / TI, NN / TI, gg), blk, 0, stream>>>(feat, xx, D, b0);
      topk_kernel<<<(gg * NN) / 4, blk, 0, stream>>>(D, idx, b0);
    }
  };

  zero_kernel<<<(BB * 320 + 255) / 256, blk, 0, stream>>>(pooled, BB * 320);

  // ---- layer 1 (C=3 -> 64) ----
  t3xx_kernel<<<bn_blocks, blk, 0, stream>>>(x, xT0, xx);
  topk3_kernel<<<(BB * NN) / 4, blk, 0, stream>>>(x, xT0, xx, idx);
  uc3_kernel<<<(BB * NN * 128) / 256, blk, 0, stream>>>(x, w1, uc);
  gmp_kernel<64><<<(BB * NN * 16) / 256, blk, 0, stream>>>(uc, idx, g1, b1, bufA, (u32*)pooled, 0);

  // ---- layer 2 (64 -> 64) ----
  knn64(bufA);
  ucpart_kernel<64><<<dim3((BB * NN) / 32, 2), blk, 0, stream>>>(bufA, w2, uc);
  gmp_kernel<64><<<(BB * NN * 16) / 256, blk, 0, stream>>>(uc, idx, g2, b2, bufB, (u32*)pooled, 64);

  // ---- layer 3 (64 -> 64) ----
  knn64(bufB);
  ucpart_kernel<64><<<dim3((BB * NN) / 32, 2), blk, 0, stream>>>(bufB, w3, uc);
  gmp_kernel<64><<<(BB * NN * 16) / 256, blk, 0, stream>>>(uc, idx, g3, b3, bufA, (u32*)pooled, 128);

  // ---- layer 4 (64 -> 128) ----
  knn64(bufA);
  ucpart_kernel<128><<<dim3((BB * NN) / 32, 2), blk, 0, stream>>>(bufA, w4, uc);
  gmp_kernel<128><<<(BB * NN * 32) / 256, blk, 0, stream>>>(uc, idx, g4, b4, bufC, (u32*)pooled, 192);

  // ---- classifier ----
  fc_kernel<320, 1024, true><<<(BB * 1024 + 255) / 256, blk, 0, stream>>>(pooled, lw1, lb1, g5, b5, h1);
  fc_kernel<1024, 512, true><<<(BB * 512 + 255) / 256, blk, 0, stream>>>(h1, lw2, lb2, g6, b6, h2);
  fc_kernel<512, 40, false><<<(BB * 40 + 255) / 256, blk, 0, stream>>>(h2, lw3, lb3, nullptr, nullptr, out);
}

// Round 6
// 803.655 us; speedup vs baseline: 4.9619x; 1.2713x over previous
//
#include <hip/hip_runtime.h>
#include <math.h>

#define BB 32
#define NN 1024
#define KK 20
typedef unsigned long long u64;
typedef unsigned int u32;
typedef unsigned short ushort;
static constexpr float EPSF = 1e-5f;

typedef __attribute__((ext_vector_type(8))) short bf16x8;
typedef __attribute__((ext_vector_type(4))) float f32x4;

// ---------------- fused transpose (B,N,3)->(B,3,N) + xx ----------------
__global__ void t3xx_kernel(const float* __restrict__ x, float* __restrict__ xT,
                            float* __restrict__ xx) {
  int t = blockIdx.x * blockDim.x + threadIdx.x;
  if (t >= BB * NN) return;
  int b = t >> 10, i = t & (NN - 1);
  float v0 = x[(size_t)t * 3 + 0], v1 = x[(size_t)t * 3 + 1], v2 = x[(size_t)t * 3 + 2];
  xT[((size_t)b * 3 + 0) * NN + i] = v0;
  xT[((size_t)b * 3 + 1) * NN + i] = v1;
  xT[((size_t)b * 3 + 2) * NN + i] = v2;
  float s = 0.f;
  s += v0 * v0; s += v1 * v1; s += v2 * v2;
  xx[t] = s;
}

// ---------------- xx = sum(x*x), C=64 ----------------
__global__ void xx64_kernel(const float* __restrict__ x, float* __restrict__ xx) {
  int t = blockIdx.x * blockDim.x + threadIdx.x;
  if (t >= BB * NN) return;
  const float* p = x + (size_t)t * 64;
  float s = 0.f;
  #pragma unroll
  for (int c = 0; c < 64; ++c) s += p[c] * p[c];
  xx[t] = s;
}

// ---------------- split fp32 -> [hi(64) | lo(64)] bf16 rows ----------------
__global__ void cvt_kernel(const float* __restrict__ x, ushort* __restrict__ xhl) {
  int t = blockIdx.x * 256 + threadIdx.x;    // B*N*16 threads, 4 ch each
  int c4 = t & 15;
  int p = t >> 4;
  float4 v = *(const float4*)(x + (size_t)p * 64 + c4 * 4);
  ushort4 hi, lo;
  u32 b0 = __float_as_uint(v.x); hi.x = b0 >> 16;
  u32 b1 = __float_as_uint(v.y); hi.y = b1 >> 16;
  u32 b2 = __float_as_uint(v.z); hi.z = b2 >> 16;
  u32 b3 = __float_as_uint(v.w); hi.w = b3 >> 16;
  lo.x = __float_as_uint(v.x - __uint_as_float(b0 & 0xFFFF0000u)) >> 16;
  lo.y = __float_as_uint(v.y - __uint_as_float(b1 & 0xFFFF0000u)) >> 16;
  lo.z = __float_as_uint(v.z - __uint_as_float(b2 & 0xFFFF0000u)) >> 16;
  lo.w = __float_as_uint(v.w - __uint_as_float(b3 & 0xFFFF0000u)) >> 16;
  *(ushort4*)(xhl + (size_t)p * 128 + c4 * 4) = hi;
  *(ushort4*)(xhl + (size_t)p * 128 + 64 + c4 * 4) = lo;
}

// ---------------- zero pooled ----------------
__global__ void zero_kernel(float* __restrict__ p, int n) {
  int t = blockIdx.x * blockDim.x + threadIdx.x;
  if (t < n) p[t] = 0.0f;
}

// ---------------- exact-integer f64 key: m(d)*1024 + (1023-j) ----------------
__device__ __forceinline__ double mkkeyd(float d, double idxd) {
  u32 bits = __float_as_uint(d);
  u32 m = (bits & 0x80000000u) ? ~bits : (bits | 0x80000000u);
  return fma((double)m, 1024.0, idxd);
}

// Batcher odd-even merge sort, 16 doubles descending
__device__ __forceinline__ void sort16(double (&k)[16]) {
  #pragma unroll
  for (int p = 1; p < 16; p <<= 1)
    #pragma unroll
    for (int kq = p; kq >= 1; kq >>= 1)
      #pragma unroll
      for (int j = kq & (p - 1); j + kq < 16; j += 2 * kq)
        #pragma unroll
        for (int i = 0; i < kq; ++i)
          if (i + j + kq < 16)
            if (((i + j) / (2 * p)) == ((i + j + kq) / (2 * p))) {
              double a = k[i + j], c = k[i + j + kq];
              k[i + j] = fmax(a, c);
              k[i + j + kq] = fmin(a, c);
            }
}

__device__ __forceinline__ void tourney_out(double (&k)[16], int lane, int* __restrict__ orow) {
  sort16(k);
  double lm = k[0];
  double res = 0.0;
  #pragma unroll
  for (int t = 0; t < KK; ++t) {
    double w = lm;
    #pragma unroll
    for (int m = 1; m < 64; m <<= 1)
      w = fmax(w, __shfl_xor(w, m));
    if (lane == t) res = w;
    bool win = (lm == w);
    #pragma unroll
    for (int e = 0; e < 15; ++e) k[e] = win ? k[e + 1] : k[e];
    k[15] = win ? 0.0 : k[15];
    lm = win ? k[0] : lm;
  }
  if (lane < KK) {
    double md = trunc(res * (1.0 / 1024.0));
    double rd = fma(md, -1024.0, res);
    int r = (int)rd;
    orow[lane] = 1023 - r;
  }
}

// ---------------- MFMA split-bf16 dist: D[bg][i][j] = 2*dot(x_i,x_j) - xx_j ----------------
__global__ __launch_bounds__(256) void distm_kernel(
    const ushort* __restrict__ xhl,  // (B,N,128) [hi|lo]
    const float* __restrict__ xx,    // (B,N)
    float* __restrict__ D,           // (g,N,N)
    int b0) {
  int b = b0 + blockIdx.z;
  int w = threadIdx.x >> 6;
  int lane = threadIdx.x & 63;
  int wm = w >> 1, wn = w & 1;
  int i0 = blockIdx.y * 128 + wm * 64;
  int j0 = blockIdx.x * 128 + wn * 64;
  int r16 = lane & 15;
  int kg = lane >> 4;

  const ushort* base = xhl + (size_t)b * NN * 128;
  f32x4 acc[4][4];
  #pragma unroll
  for (int mi = 0; mi < 4; ++mi)
    #pragma unroll
    for (int ni = 0; ni < 4; ++ni) acc[mi][ni] = (f32x4){0.f, 0.f, 0.f, 0.f};

  #pragma unroll
  for (int ks = 0; ks < 2; ++ks) {
    int k0 = ks * 32 + kg * 8;
    bf16x8 ah[4], al[4], bh[4], bl[4];
    #pragma unroll
    for (int mi = 0; mi < 4; ++mi) {
      const ushort* pr = base + (size_t)(i0 + mi * 16 + r16) * 128 + k0;
      ah[mi] = *(const bf16x8*)pr;
      al[mi] = *(const bf16x8*)(pr + 64);
    }
    #pragma unroll
    for (int ni = 0; ni < 4; ++ni) {
      const ushort* pr = base + (size_t)(j0 + ni * 16 + r16) * 128 + k0;
      bh[ni] = *(const bf16x8*)pr;
      bl[ni] = *(const bf16x8*)(pr + 64);
    }
    #pragma unroll
    for (int mi = 0; mi < 4; ++mi)
      #pragma unroll
      for (int ni = 0; ni < 4; ++ni) {
        acc[mi][ni] = __builtin_amdgcn_mfma_f32_16x16x32_bf16(ah[mi], bh[ni], acc[mi][ni], 0, 0, 0);
        acc[mi][ni] = __builtin_amdgcn_mfma_f32_16x16x32_bf16(ah[mi], bl[ni], acc[mi][ni], 0, 0, 0);
        acc[mi][ni] = __builtin_amdgcn_mfma_f32_16x16x32_bf16(al[mi], bh[ni], acc[mi][ni], 0, 0, 0);
        acc[mi][ni] = __builtin_amdgcn_mfma_f32_16x16x32_bf16(al[mi], bl[ni], acc[mi][ni], 0, 0, 0);
      }
  }

  const float* xxb = xx + (size_t)b * NN;
  float* Dg = D + (size_t)blockIdx.z * NN * NN;
  #pragma unroll
  for (int ni = 0; ni < 4; ++ni) {
    float xj = xxb[j0 + ni * 16 + r16];
    #pragma unroll
    for (int mi = 0; mi < 4; ++mi) {
      int rowb = i0 + mi * 16 + kg * 4;
      #pragma unroll
      for (int r = 0; r < 4; ++r)
        Dg[(size_t)(rowb + r) * NN + j0 + ni * 16 + r16] = 2.f * acc[mi][ni][r] - xj;
    }
  }
}

// ---------------- wave-per-row top-20 (f64 keys, sorted pop) ----------------
__global__ __launch_bounds__(256) void topk_kernel(
    const float* __restrict__ D, int* __restrict__ oidx, int b0) {
  int wid = (blockIdx.x << 2) + (threadIdx.x >> 6);
  int lane = threadIdx.x & 63;
  int row = wid & (NN - 1);
  int bg = wid >> 10;

  const float4* dp = (const float4*)(D + ((size_t)bg * NN + row) * NN);
  double k[16];
  double based = (double)(1023 - lane * 4);
  #pragma unroll
  for (int q = 0; q < 4; ++q) {
    float4 v = dp[q * 64 + lane];
    double qb = based - (double)(q * 256);
    k[q * 4 + 0] = mkkeyd(v.x, qb - 0.0);
    k[q * 4 + 1] = mkkeyd(v.y, qb - 1.0);
    k[q * 4 + 2] = mkkeyd(v.z, qb - 2.0);
    k[q * 4 + 3] = mkkeyd(v.w, qb - 3.0);
  }
  tourney_out(k, lane, oidx + ((size_t)(b0 + bg) * NN + row) * KK);
}

// ---------------- layer-1: fused C=3 distance + top-20 ----------------
__global__ __launch_bounds__(256) void topk3_kernel(
    const float* __restrict__ x,   // (B,N,3)
    const float* __restrict__ xT,  // (B,3,N)
    const float* __restrict__ xx,  // (B,N)
    int* __restrict__ oidx) {
  int wid = (blockIdx.x << 2) + (threadIdx.x >> 6);
  int lane = threadIdx.x & 63;
  int row = wid & (NN - 1);
  int b = wid >> 10;

  const float* xr = x + ((size_t)b * NN + row) * 3;
  float x0 = xr[0], x1 = xr[1], x2 = xr[2];
  const float* xTb = xT + (size_t)b * 3 * NN;
  const float* xxb = xx + (size_t)b * NN;

  double k[16];
  double based = (double)(1023 - lane * 4);
  #pragma unroll
  for (int q = 0; q < 4; ++q) {
    int f4i = q * 64 + lane;
    float4 a  = ((const float4*)xTb)[f4i];
    float4 bv = ((const float4*)(xTb + NN))[f4i];
    float4 c  = ((const float4*)(xTb + 2 * NN))[f4i];
    float4 xj = ((const float4*)xxb)[f4i];
    float d0 = 0.f; d0 += x0 * a.x; d0 += x1 * bv.x; d0 += x2 * c.x;
    float d1 = 0.f; d1 += x0 * a.y; d1 += x1 * bv.y; d1 += x2 * c.y;
    float d2 = 0.f; d2 += x0 * a.z; d2 += x1 * bv.z; d2 += x2 * c.z;
    float d3 = 0.f; d3 += x0 * a.w; d3 += x1 * bv.w; d3 += x2 * c.w;
    double qb = based - (double)(q * 256);
    k[q * 4 + 0] = mkkeyd(2.f * d0 - xj.x, qb - 0.0);
    k[q * 4 + 1] = mkkeyd(2.f * d1 - xj.y, qb - 1.0);
    k[q * 4 + 2] = mkkeyd(2.f * d2 - xj.z, qb - 2.0);
    k[q * 4 + 3] = mkkeyd(2.f * d3 - xj.w, qb - 3.0);
  }
  tourney_out(k, lane, oidx + ((size_t)b * NN + row) * KK);
}

// ---------------- uc part GEMM (both parts via blockIdx.y) ----------------
#define CC 64
template<int O>
__global__ __launch_bounds__(256) void ucpart_kernel(
    const float* __restrict__ x,   // (B,N,64)
    const float* __restrict__ w,   // (O,128)
    float* __restrict__ uc) {      // (B,N,2O)
  constexpr int PPT = 32 * O / 256;
  __shared__ float4 Ws[O * 16];
  __shared__ float4 As[32 * 16];

  int part = blockIdx.y;
  int tile = blockIdx.x;
  int b = tile >> 5;
  int i0 = (tile & 31) * 32;

  const float4* w4 = (const float4*)w;
  for (int r = threadIdx.x; r < O * 16; r += 256) {
    int rowc = r >> 4, c4 = r & 15;
    float4 v;
    if (part == 0) {
      v = w4[(size_t)rowc * 32 + c4];
    } else {
      float4 lo = w4[(size_t)rowc * 32 + c4];
      float4 hi = w4[(size_t)rowc * 32 + 16 + c4];
      v = make_float4(hi.x - lo.x, hi.y - lo.y, hi.z - lo.z, hi.w - lo.w);
    }
    Ws[(rowc << 4) + (c4 ^ (rowc & 7))] = v;
  }
  const float4* xa = (const float4*)(x + ((size_t)b * NN + i0) * CC);
  for (int r = threadIdx.x; r < 32 * 16; r += 256) As[r] = xa[r];
  __syncthreads();

  int col = threadIdx.x % O;
  int pg = threadIdx.x / O;
  float4 wc[16];
  #pragma unroll
  for (int c4 = 0; c4 < 16; ++c4) wc[c4] = Ws[(col << 4) + (c4 ^ (col & 7))];

  #pragma unroll
  for (int pp = 0; pp < PPT; ++pp) {
    int p = pg * PPT + pp;
    float acc = 0.f;
    #pragma unroll
    for (int c4 = 0; c4 < 16; ++c4) {
      float4 a = As[(p << 4) + c4];
      acc += a.x * wc[c4].x; acc += a.y * wc[c4].y;
      acc += a.z * wc[c4].z; acc += a.w * wc[c4].w;
    }
    uc[((size_t)b * NN + i0 + p) * (2 * O) + part * O + col] = acc;
  }
}

// ---------------- layer-1 uc (C=3) ----------------
__global__ __launch_bounds__(256) void uc3_kernel(
    const float* __restrict__ x, const float* __restrict__ w, float* __restrict__ uc) {
  int t = blockIdx.x * 256 + threadIdx.x;   // B*N*128
  int col = t & 127;
  int i = (t >> 7) & (NN - 1);
  int b = t >> 17;
  const float* xr = x + ((size_t)b * NN + i) * 3;
  float x0 = xr[0], x1 = xr[1], x2 = xr[2];
  float r;
  if (col < 64) {
    const float* wr = w + col * 6;
    r = wr[0] * x0 + wr[1] * x1 + wr[2] * x2;
  } else {
    const float* wr = w + (col - 64) * 6;
    r = (wr[3] - wr[0]) * x0 + (wr[4] - wr[1]) * x1 + (wr[5] - wr[2]) * x2;
  }
  uc[(size_t)t] = r;
}

// ---------------- gather-max + BN/ReLU + fused global-pool (atomicMax) ----------------
template<int O>
__global__ __launch_bounds__(256) void gmp_kernel(
    const float* __restrict__ uc,   // (B,N,2O)
    const int*   __restrict__ idx,  // (B,N,K)
    const float* __restrict__ g,
    const float* __restrict__ bb,
    float* __restrict__ y,          // (B,N,O)
    u32* __restrict__ pooled,       // (B,320) u32 bit patterns (all >= 0)
    int ooff) {
  constexpr int O4 = O / 4;
  constexpr int IPB = 256 / O4;
  int t = blockIdx.x * 256 + threadIdx.x;
  int o4 = t & (O4 - 1);
  int rest = t / O4;
  int i = rest & (NN - 1);
  int b = rest >> 10;

  const int* irow = idx + ((size_t)b * NN + i) * KK;
  int jj[KK];
  #pragma unroll
  for (int k = 0; k < KK; ++k) jj[k] = irow[k];

  const float* ucb = uc + (size_t)b * NN * (2 * O);
  float4 vm = make_float4(-INFINITY, -INFINITY, -INFINITY, -INFINITY);
  #pragma unroll
  for (int k = 0; k < KK; ++k) {
    float4 v = *(const float4*)(ucb + (size_t)jj[k] * (2 * O) + o4 * 4);
    vm.x = fmaxf(vm.x, v.x); vm.y = fmaxf(vm.y, v.y);
    vm.z = fmaxf(vm.z, v.z); vm.w = fmaxf(vm.w, v.w);
  }
  float4 c0 = *(const float4*)(ucb + (size_t)i * (2 * O) + O + o4 * 4);
  float4 gv = ((const float4*)g)[o4];
  float4 bv = ((const float4*)bb)[o4];
  const float inv = 1.0f / sqrtf(1.0f + EPSF);
  float4 o;
  o.x = fmaxf((gv.x * inv) * (vm.x + c0.x) + bv.x, 0.f);
  o.y = fmaxf((gv.y * inv) * (vm.y + c0.y) + bv.y, 0.f);
  o.z = fmaxf((gv.z * inv) * (vm.z + c0.z) + bv.z, 0.f);
  o.w = fmaxf((gv.w * inv) * (vm.w + c0.w) + bv.w, 0.f);
  *(float4*)(y + ((size_t)b * NN + i) * O + o4 * 4) = o;

  __shared__ float4 sm[256];
  sm[threadIdx.x] = o;
  __syncthreads();
  if (threadIdx.x < O4) {
    float4 m = sm[threadIdx.x];
    #pragma unroll
    for (int r = 1; r < IPB; ++r) {
      float4 v = sm[threadIdx.x + r * O4];
      m.x = fmaxf(m.x, v.x); m.y = fmaxf(m.y, v.y);
      m.z = fmaxf(m.z, v.z); m.w = fmaxf(m.w, v.w);
    }
    u32* dst = pooled + (size_t)b * 320 + ooff + threadIdx.x * 4;
    atomicMax(dst + 0, __float_as_uint(m.x));
    atomicMax(dst + 1, __float_as_uint(m.y));
    atomicMax(dst + 2, __float_as_uint(m.z));
    atomicMax(dst + 3, __float_as_uint(m.w));
  }
}

// ---------------- fc ----------------
template<int IN, int OUT, bool BNRELU>
__global__ void fc_kernel(const float* __restrict__ in, const float* __restrict__ W,
                          const float* __restrict__ lb, const float* __restrict__ g,
                          const float* __restrict__ bbias, float* __restrict__ out) {
  int t = blockIdx.x * blockDim.x + threadIdx.x;
  if (t >= BB * OUT) return;
  int b = t / OUT, o = t % OUT;
  const float4* iv = (const float4*)(in + (size_t)b * IN);
  const float4* wv = (const float4*)(W + (size_t)o * IN);
  float acc = 0.f;
  for (int c4 = 0; c4 < IN / 4; ++c4) {
    float4 a = iv[c4], ww = wv[c4];
    acc += a.x * ww.x + a.y * ww.y + a.z * ww.z + a.w * ww.w;
  }
  acc += lb[o];
  if (BNRELU) {
    float s = g[o] / sqrtf(1.0f + EPSF);
    acc = fmaxf(acc * s + bbias[o], 0.0f);
  }
  out[t] = acc;
}

extern "C" void kernel_launch(void* const* d_in, const int* in_sizes, int n_in,
                              void* d_out, int out_size, void* d_ws, size_t ws_size,
                              hipStream_t stream) {
  const float* x   = (const float*)d_in[0];
  const float* w1  = (const float*)d_in[1];
  const float* g1  = (const float*)d_in[2];
  const float* b1  = (const float*)d_in[3];
  const float* w2  = (const float*)d_in[4];
  const float* g2  = (const float*)d_in[5];
  const float* b2  = (const float*)d_in[6];
  const float* w3  = (const float*)d_in[7];
  const float* g3  = (const float*)d_in[8];
  const float* b3  = (const float*)d_in[9];
  const float* w4  = (const float*)d_in[10];
  const float* g4  = (const float*)d_in[11];
  const float* b4  = (const float*)d_in[12];
  const float* lw1 = (const float*)d_in[13];
  const float* lb1 = (const float*)d_in[14];
  const float* g5  = (const float*)d_in[15];
  const float* b5  = (const float*)d_in[16];
  const float* lw2 = (const float*)d_in[17];
  const float* lb2 = (const float*)d_in[18];
  const float* g6  = (const float*)d_in[19];
  const float* b6  = (const float*)d_in[20];
  const float* lw3 = (const float*)d_in[21];
  const float* lb3 = (const float*)d_in[22];
  float* out = (float*)d_out;

  char* ws = (char*)d_ws;
  size_t off = 0;
  auto alloc = [&](size_t bytes) -> char* {
    char* p = ws + off;
    off += (bytes + 255) & ~255ULL;
    return p;
  };
  int*   idx    = (int*)  alloc((size_t)BB * NN * KK * 4);
  float* xx     = (float*)alloc((size_t)BB * NN * 4);
  float* xT0    = (float*)alloc((size_t)BB * 3 * NN * 4);
  float* bufA   = (float*)alloc((size_t)BB * NN * 64 * 4);
  float* bufB   = (float*)alloc((size_t)BB * NN * 64 * 4);
  float* bufC   = (float*)alloc((size_t)BB * NN * 128 * 4);
  float* pooled = (float*)alloc((size_t)BB * 320 * 4);
  float* h1     = (float*)alloc((size_t)BB * 1024 * 4);
  float* h2     = (float*)alloc((size_t)BB * 512 * 4);
  float* uc     = (float*)alloc((size_t)BB * NN * 256 * 4);
  ushort* xhl   = (ushort*)alloc((size_t)BB * NN * 128 * 2);

  size_t dbytes_per_b = (size_t)NN * NN * 4;
  size_t rem = (ws_size > off) ? (ws_size - off) : 0;
  int gmax = (int)(rem / dbytes_per_b);
  if (gmax > 32) gmax = 32;
  if (gmax < 1) gmax = 1;
  float* D = (float*)alloc((size_t)gmax * dbytes_per_b);

  dim3 blk(256);
  int bn_blocks = (BB * NN + 255) / 256;

  auto knn64 = [&](const float* feat) {
    xx64_kernel<<<bn_blocks, blk, 0, stream>>>(feat, xx);
    cvt_kernel<<<(BB * NN * 16) / 256, blk, 0, stream>>>(feat, xhl);
    for (int b0 = 0; b0 < BB; b0 += gmax) {
      int gg = (BB - b0 < gmax) ? (BB - b0) : gmax;
      distm_kernel<<<dim3(NN / 128, NN / 128, gg), blk, 0, stream>>>(xhl, xx, D, b0);
      topk_kernel<<<(gg * NN) / 4, blk, 0, stream>>>(D, idx, b0);
    }
  };

  zero_kernel<<<(BB * 320 + 255) / 256, blk, 0, stream>>>(pooled, BB * 320);

  // ---- layer 1 (C=3 -> 64) ----
  t3xx_kernel<<<bn_blocks, blk, 0, stream>>>(x, xT0, xx);
  topk3_kernel<<<(BB * NN) / 4, blk, 0, stream>>>(x, xT0, xx, idx);
  uc3_kernel<<<(BB * NN * 128) / 256, blk, 0, stream>>>(x, w1, uc);
  gmp_kernel<64><<<(BB * NN * 16) / 256, blk, 0, stream>>>(uc, idx, g1, b1, bufA, (u32*)pooled, 0);

  // ---- layer 2 (64 -> 64) ----
  knn64(bufA);
  ucpart_kernel<64><<<dim3((BB * NN) / 32, 2), blk, 0, stream>>>(bufA, w2, uc);
  gmp_kernel<64><<<(BB * NN * 16) / 256, blk, 0, stream>>>(uc, idx, g2, b2, bufB, (u32*)pooled, 64);

  // ---- layer 3 (64 -> 64) ----
  knn64(bufB);
  ucpart_kernel<64><<<dim3((BB * NN) / 32, 2), blk, 0, stream>>>(bufB, w3, uc);
  gmp_kernel<64><<<(BB * NN * 16) / 256, blk, 0, stream>>>(uc, idx, g3, b3, bufA, (u32*)pooled, 128);

  // ---- layer 4 (64 -> 128) ----
  knn64(bufA);
  ucpart_kernel<128><<<dim3((BB * NN) / 32, 2), blk, 0, stream>>>(bufA, w4, uc);
  gmp_kernel<128><<<(BB * NN * 32) / 256, blk, 0, stream>>>(uc, idx, g4, b4, bufC, (u32*)pooled, 192);

  // ---- classifier ----
  fc_kernel<320, 1024, true><<<(BB * 1024 + 255) / 256, blk, 0, stream>>>(pooled, lw1, lb1, g5, b5, h1);
  fc_kernel<1024, 512, true><<<(BB * 512 + 255) / 256, blk, 0, stream>>>(h1, lw2, lb2, g6, b6, h2);
  fc_kernel<512, 40, false><<<(BB * 40 + 255) / 256, blk, 0, stream>>>(h2, lw3, lb3, nullptr, nullptr, out);
}

// Round 7
// 734.835 us; speedup vs baseline: 5.4266x; 1.0937x over previous
//
#include <hip/hip_runtime.h>
#include <math.h>

#define BB 32
#define NN 1024
#define KK 20
typedef unsigned long long u64;
typedef unsigned int u32;
typedef unsigned short ushort;
static constexpr float EPSF = 1e-5f;

typedef __attribute__((ext_vector_type(8))) short bf16x8;
typedef __attribute__((ext_vector_type(4))) float f32x4;

// ---------------- fused transpose (B,N,3)->(B,3,N) + xx + pooled zero ----------------
__global__ void t3xx_kernel(const float* __restrict__ x, float* __restrict__ xT,
                            float* __restrict__ xx, float* __restrict__ pooled) {
  int t = blockIdx.x * blockDim.x + threadIdx.x;
  if (t >= BB * NN) return;
  if (t < BB * 320) pooled[t] = 0.0f;
  int b = t >> 10, i = t & (NN - 1);
  float v0 = x[(size_t)t * 3 + 0], v1 = x[(size_t)t * 3 + 1], v2 = x[(size_t)t * 3 + 2];
  xT[((size_t)b * 3 + 0) * NN + i] = v0;
  xT[((size_t)b * 3 + 1) * NN + i] = v1;
  xT[((size_t)b * 3 + 2) * NN + i] = v2;
  float s = 0.f;
  s += v0 * v0; s += v1 * v1; s += v2 * v2;
  xx[t] = s;
}

// ---------------- exact-integer f64 key: m(d)*1024 + (1023-j) ----------------
__device__ __forceinline__ double mkkeyd(float d, double idxd) {
  u32 bits = __float_as_uint(d);
  u32 m = (bits & 0x80000000u) ? ~bits : (bits | 0x80000000u);
  return fma((double)m, 1024.0, idxd);
}

// Batcher odd-even merge sort, 16 doubles descending
__device__ __forceinline__ void sort16(double (&k)[16]) {
  #pragma unroll
  for (int p = 1; p < 16; p <<= 1)
    #pragma unroll
    for (int kq = p; kq >= 1; kq >>= 1)
      #pragma unroll
      for (int j = kq & (p - 1); j + kq < 16; j += 2 * kq)
        #pragma unroll
        for (int i = 0; i < kq; ++i)
          if (i + j + kq < 16)
            if (((i + j) / (2 * p)) == ((i + j + kq) / (2 * p))) {
              double a = k[i + j], c = k[i + j + kq];
              k[i + j] = fmax(a, c);
              k[i + j + kq] = fmin(a, c);
            }
}

// tournament: hot-8 pop + lazy cold catch-up on repeat wins (exact)
__device__ __forceinline__ void tourney_out(double (&k)[16], int lane, int* __restrict__ orow) {
  sort16(k);
  double lm = k[0];
  double res = 0.0;
  int c = 0;
  #pragma unroll
  for (int t = 0; t < KK; ++t) {
    double w = lm;
    #pragma unroll
    for (int m = 1; m < 64; m <<= 1)
      w = fmax(w, __shfl_xor(w, m));
    if (lane == t) res = w;
    bool win = (lm == w);
    bool rep = win && (c > 0);
    if (__any(rep)) {
      // repeat winner advances its cold half by the one pending slot
      #pragma unroll
      for (int e = 8; e < 15; ++e) k[e] = rep ? k[e + 1] : k[e];
      k[15] = rep ? 0.0 : k[15];
    }
    #pragma unroll
    for (int e = 0; e < 8; ++e) k[e] = win ? k[e + 1] : k[e];
    c += win;
    lm = k[0];
  }
  if (lane < KK) {
    double md = trunc(res * (1.0 / 1024.0));
    double rd = fma(md, -1024.0, res);
    int r = (int)rd;
    orow[lane] = 1023 - r;
  }
}

// ---------------- MFMA split-bf16 dist: D[bg][i][j] = 2*dot(x_i,x_j) - xx_j ----------------
__global__ __launch_bounds__(256) void distm_kernel(
    const ushort* __restrict__ xhl,  // (B,N,128) [hi|lo]
    const float* __restrict__ xx,    // (B,N)
    float* __restrict__ D,           // (g,N,N)
    int b0) {
  int b = b0 + blockIdx.z;
  int w = threadIdx.x >> 6;
  int lane = threadIdx.x & 63;
  int wm = w >> 1, wn = w & 1;
  int i0 = blockIdx.y * 128 + wm * 64;
  int j0 = blockIdx.x * 128 + wn * 64;
  int r16 = lane & 15;
  int kg = lane >> 4;

  const ushort* base = xhl + (size_t)b * NN * 128;
  f32x4 acc[4][4];
  #pragma unroll
  for (int mi = 0; mi < 4; ++mi)
    #pragma unroll
    for (int ni = 0; ni < 4; ++ni) acc[mi][ni] = (f32x4){0.f, 0.f, 0.f, 0.f};

  #pragma unroll
  for (int ks = 0; ks < 2; ++ks) {
    int k0 = ks * 32 + kg * 8;
    bf16x8 ah[4], al[4], bh[4], bl[4];
    #pragma unroll
    for (int mi = 0; mi < 4; ++mi) {
      const ushort* pr = base + (size_t)(i0 + mi * 16 + r16) * 128 + k0;
      ah[mi] = *(const bf16x8*)pr;
      al[mi] = *(const bf16x8*)(pr + 64);
    }
    #pragma unroll
    for (int ni = 0; ni < 4; ++ni) {
      const ushort* pr = base + (size_t)(j0 + ni * 16 + r16) * 128 + k0;
      bh[ni] = *(const bf16x8*)pr;
      bl[ni] = *(const bf16x8*)(pr + 64);
    }
    #pragma unroll
    for (int mi = 0; mi < 4; ++mi)
      #pragma unroll
      for (int ni = 0; ni < 4; ++ni) {
        acc[mi][ni] = __builtin_amdgcn_mfma_f32_16x16x32_bf16(ah[mi], bh[ni], acc[mi][ni], 0, 0, 0);
        acc[mi][ni] = __builtin_amdgcn_mfma_f32_16x16x32_bf16(ah[mi], bl[ni], acc[mi][ni], 0, 0, 0);
        acc[mi][ni] = __builtin_amdgcn_mfma_f32_16x16x32_bf16(al[mi], bh[ni], acc[mi][ni], 0, 0, 0);
        acc[mi][ni] = __builtin_amdgcn_mfma_f32_16x16x32_bf16(al[mi], bl[ni], acc[mi][ni], 0, 0, 0);
      }
  }

  const float* xxb = xx + (size_t)b * NN;
  float* Dg = D + (size_t)blockIdx.z * NN * NN;
  #pragma unroll
  for (int ni = 0; ni < 4; ++ni) {
    float xj = xxb[j0 + ni * 16 + r16];
    #pragma unroll
    for (int mi = 0; mi < 4; ++mi) {
      int rowb = i0 + mi * 16 + kg * 4;
      #pragma unroll
      for (int r = 0; r < 4; ++r)
        Dg[(size_t)(rowb + r) * NN + j0 + ni * 16 + r16] = 2.f * acc[mi][ni][r] - xj;
    }
  }
}

// ---------------- wave-per-row top-20 ----------------
__global__ __launch_bounds__(256) void topk_kernel(
    const float* __restrict__ D, int* __restrict__ oidx, int b0) {
  int wid = (blockIdx.x << 2) + (threadIdx.x >> 6);
  int lane = threadIdx.x & 63;
  int row = wid & (NN - 1);
  int bg = wid >> 10;

  const float4* dp = (const float4*)(D + ((size_t)bg * NN + row) * NN);
  double k[16];
  double based = (double)(1023 - lane * 4);
  #pragma unroll
  for (int q = 0; q < 4; ++q) {
    float4 v = dp[q * 64 + lane];
    double qb = based - (double)(q * 256);
    k[q * 4 + 0] = mkkeyd(v.x, qb - 0.0);
    k[q * 4 + 1] = mkkeyd(v.y, qb - 1.0);
    k[q * 4 + 2] = mkkeyd(v.z, qb - 2.0);
    k[q * 4 + 3] = mkkeyd(v.w, qb - 3.0);
  }
  tourney_out(k, lane, oidx + ((size_t)(b0 + bg) * NN + row) * KK);
}

// ---------------- layer-1: fused C=3 distance + top-20 ----------------
__global__ __launch_bounds__(256) void topk3_kernel(
    const float* __restrict__ x,   // (B,N,3)
    const float* __restrict__ xT,  // (B,3,N)
    const float* __restrict__ xx,  // (B,N)
    int* __restrict__ oidx) {
  int wid = (blockIdx.x << 2) + (threadIdx.x >> 6);
  int lane = threadIdx.x & 63;
  int row = wid & (NN - 1);
  int b = wid >> 10;

  const float* xr = x + ((size_t)b * NN + row) * 3;
  float x0 = xr[0], x1 = xr[1], x2 = xr[2];
  const float* xTb = xT + (size_t)b * 3 * NN;
  const float* xxb = xx + (size_t)b * NN;

  double k[16];
  double based = (double)(1023 - lane * 4);
  #pragma unroll
  for (int q = 0; q < 4; ++q) {
    int f4i = q * 64 + lane;
    float4 a  = ((const float4*)xTb)[f4i];
    float4 bv = ((const float4*)(xTb + NN))[f4i];
    float4 c  = ((const float4*)(xTb + 2 * NN))[f4i];
    float4 xj = ((const float4*)xxb)[f4i];
    float d0 = 0.f; d0 += x0 * a.x; d0 += x1 * bv.x; d0 += x2 * c.x;
    float d1 = 0.f; d1 += x0 * a.y; d1 += x1 * bv.y; d1 += x2 * c.y;
    float d2 = 0.f; d2 += x0 * a.z; d2 += x1 * bv.z; d2 += x2 * c.z;
    float d3 = 0.f; d3 += x0 * a.w; d3 += x1 * bv.w; d3 += x2 * c.w;
    double qb = based - (double)(q * 256);
    k[q * 4 + 0] = mkkeyd(2.f * d0 - xj.x, qb - 0.0);
    k[q * 4 + 1] = mkkeyd(2.f * d1 - xj.y, qb - 1.0);
    k[q * 4 + 2] = mkkeyd(2.f * d2 - xj.z, qb - 2.0);
    k[q * 4 + 3] = mkkeyd(2.f * d3 - xj.w, qb - 3.0);
  }
  tourney_out(k, lane, oidx + ((size_t)b * NN + row) * KK);
}

// ---------------- uc part GEMM (both parts via blockIdx.y) ----------------
#define CC 64
template<int O>
__global__ __launch_bounds__(256) void ucpart_kernel(
    const float* __restrict__ x,   // (B,N,64)
    const float* __restrict__ w,   // (O,128)
    float* __restrict__ uc) {      // (B,N,2O)
  constexpr int PPT = 32 * O / 256;
  __shared__ float4 Ws[O * 16];
  __shared__ float4 As[32 * 16];

  int part = blockIdx.y;
  int tile = blockIdx.x;
  int b = tile >> 5;
  int i0 = (tile & 31) * 32;

  const float4* w4 = (const float4*)w;
  for (int r = threadIdx.x; r < O * 16; r += 256) {
    int rowc = r >> 4, c4 = r & 15;
    float4 v;
    if (part == 0) {
      v = w4[(size_t)rowc * 32 + c4];
    } else {
      float4 lo = w4[(size_t)rowc * 32 + c4];
      float4 hi = w4[(size_t)rowc * 32 + 16 + c4];
      v = make_float4(hi.x - lo.x, hi.y - lo.y, hi.z - lo.z, hi.w - lo.w);
    }
    Ws[(rowc << 4) + (c4 ^ (rowc & 7))] = v;
  }
  const float4* xa = (const float4*)(x + ((size_t)b * NN + i0) * CC);
  for (int r = threadIdx.x; r < 32 * 16; r += 256) As[r] = xa[r];
  __syncthreads();

  int col = threadIdx.x % O;
  int pg = threadIdx.x / O;
  float4 wc[16];
  #pragma unroll
  for (int c4 = 0; c4 < 16; ++c4) wc[c4] = Ws[(col << 4) + (c4 ^ (col & 7))];

  #pragma unroll
  for (int pp = 0; pp < PPT; ++pp) {
    int p = pg * PPT + pp;
    float acc = 0.f;
    #pragma unroll
    for (int c4 = 0; c4 < 16; ++c4) {
      float4 a = As[(p << 4) + c4];
      acc += a.x * wc[c4].x; acc += a.y * wc[c4].y;
      acc += a.z * wc[c4].z; acc += a.w * wc[c4].w;
    }
    uc[((size_t)b * NN + i0 + p) * (2 * O) + part * O + col] = acc;
  }
}

// ---------------- layer-1 uc (C=3) ----------------
__global__ __launch_bounds__(256) void uc3_kernel(
    const float* __restrict__ x, const float* __restrict__ w, float* __restrict__ uc) {
  int t = blockIdx.x * 256 + threadIdx.x;   // B*N*128
  int col = t & 127;
  int i = (t >> 7) & (NN - 1);
  int b = t >> 17;
  const float* xr = x + ((size_t)b * NN + i) * 3;
  float x0 = xr[0], x1 = xr[1], x2 = xr[2];
  float r;
  if (col < 64) {
    const float* wr = w + col * 6;
    r = wr[0] * x0 + wr[1] * x1 + wr[2] * x2;
  } else {
    const float* wr = w + (col - 64) * 6;
    r = (wr[3] - wr[0]) * x0 + (wr[4] - wr[1]) * x1 + (wr[5] - wr[2]) * x2;
  }
  uc[(size_t)t] = r;
}

// ---- gather-max + BN/ReLU + global-pool (atomicMax) + (if NEXT) y write + xx/xhl prep ----
template<int O, bool NEXT>
__global__ __launch_bounds__(256) void gmp_kernel(
    const float* __restrict__ uc,   // (B,N,2O)
    const int*   __restrict__ idx,  // (B,N,K)
    const float* __restrict__ g,
    const float* __restrict__ bb,
    float* __restrict__ y,          // (B,N,O)
    u32* __restrict__ pooled,       // (B,320) u32 bit patterns (all >= 0)
    int ooff,
    ushort* __restrict__ xhl,       // (B,N,128) [hi|lo]   (NEXT only)
    float* __restrict__ xx) {       // (B,N)               (NEXT only)
  constexpr int O4 = O / 4;
  constexpr int IPB = 256 / O4;
  int t = blockIdx.x * 256 + threadIdx.x;
  int o4 = t & (O4 - 1);
  int rest = t / O4;
  int i = rest & (NN - 1);
  int b = rest >> 10;

  const int* irow = idx + ((size_t)b * NN + i) * KK;
  int jj[KK];
  #pragma unroll
  for (int k = 0; k < KK; ++k) jj[k] = irow[k];

  const float* ucb = uc + (size_t)b * NN * (2 * O);
  float4 vm = make_float4(-INFINITY, -INFINITY, -INFINITY, -INFINITY);
  #pragma unroll
  for (int k = 0; k < KK; ++k) {
    float4 v = *(const float4*)(ucb + (size_t)jj[k] * (2 * O) + o4 * 4);
    vm.x = fmaxf(vm.x, v.x); vm.y = fmaxf(vm.y, v.y);
    vm.z = fmaxf(vm.z, v.z); vm.w = fmaxf(vm.w, v.w);
  }
  float4 c0 = *(const float4*)(ucb + (size_t)i * (2 * O) + O + o4 * 4);
  float4 gv = ((const float4*)g)[o4];
  float4 bv = ((const float4*)bb)[o4];
  const float inv = 1.0f / sqrtf(1.0f + EPSF);
  float4 o;
  o.x = fmaxf((gv.x * inv) * (vm.x + c0.x) + bv.x, 0.f);
  o.y = fmaxf((gv.y * inv) * (vm.y + c0.y) + bv.y, 0.f);
  o.z = fmaxf((gv.z * inv) * (vm.z + c0.z) + bv.z, 0.f);
  o.w = fmaxf((gv.w * inv) * (vm.w + c0.w) + bv.w, 0.f);

  if constexpr (NEXT) {
    *(float4*)(y + ((size_t)b * NN + i) * O + o4 * 4) = o;
    // split to bf16 hi/lo for next layer's MFMA distance
    ushort4 hi, lo;
    u32 q0 = __float_as_uint(o.x); hi.x = q0 >> 16;
    u32 q1 = __float_as_uint(o.y); hi.y = q1 >> 16;
    u32 q2 = __float_as_uint(o.z); hi.z = q2 >> 16;
    u32 q3 = __float_as_uint(o.w); hi.w = q3 >> 16;
    lo.x = __float_as_uint(o.x - __uint_as_float(q0 & 0xFFFF0000u)) >> 16;
    lo.y = __float_as_uint(o.y - __uint_as_float(q1 & 0xFFFF0000u)) >> 16;
    lo.z = __float_as_uint(o.z - __uint_as_float(q2 & 0xFFFF0000u)) >> 16;
    lo.w = __float_as_uint(o.w - __uint_as_float(q3 & 0xFFFF0000u)) >> 16;
    ushort* xr = xhl + ((size_t)b * NN + i) * 128;
    *(ushort4*)(xr + o4 * 4) = hi;
    *(ushort4*)(xr + 64 + o4 * 4) = lo;
    // xx reduce over the 16 threads sharing point i (lanes aligned in groups of 16)
    float px = o.x * o.x + o.y * o.y + o.z * o.z + o.w * o.w;
    px += __shfl_xor(px, 1);
    px += __shfl_xor(px, 2);
    px += __shfl_xor(px, 4);
    px += __shfl_xor(px, 8);
    if (o4 == 0) xx[(size_t)b * NN + i] = px;
  }

  __shared__ float4 sm[256];
  sm[threadIdx.x] = o;
  __syncthreads();
  if (threadIdx.x < O4) {
    float4 m = sm[threadIdx.x];
    #pragma unroll
    for (int r = 1; r < IPB; ++r) {
      float4 v = sm[threadIdx.x + r * O4];
      m.x = fmaxf(m.x, v.x); m.y = fmaxf(m.y, v.y);
      m.z = fmaxf(m.z, v.z); m.w = fmaxf(m.w, v.w);
    }
    u32* dst = pooled + (size_t)b * 320 + ooff + threadIdx.x * 4;
    atomicMax(dst + 0, __float_as_uint(m.x));
    atomicMax(dst + 1, __float_as_uint(m.y));
    atomicMax(dst + 2, __float_as_uint(m.z));
    atomicMax(dst + 3, __float_as_uint(m.w));
  }
}

// ---------------- coalesced fc: wave-per-output, LDS-staged input ----------------
template<int IN, int OUT, int OPW, bool BNRELU>
__global__ __launch_bounds__(256) void fcw_kernel(
    const float* __restrict__ in, const float* __restrict__ W,
    const float* __restrict__ lb, const float* __restrict__ g,
    const float* __restrict__ bbias, float* __restrict__ out) {
  int b = blockIdx.x;
  int oc = blockIdx.y;
  __shared__ float sIn[IN];
  for (int r = threadIdx.x; r < IN; r += 256) sIn[r] = in[(size_t)b * IN + r];
  __syncthreads();
  int w = threadIdx.x >> 6, lane = threadIdx.x & 63;
  constexpr int RPL = IN / 64;
  for (int ii = 0; ii < OPW; ++ii) {
    int o = (oc * 4 + w) * OPW + ii;
    const float* wr = W + (size_t)o * IN;
    float acc = 0.f;
    #pragma unroll
    for (int r = 0; r < RPL; ++r) acc += wr[r * 64 + lane] * sIn[r * 64 + lane];
    #pragma unroll
    for (int m = 32; m >= 1; m >>= 1) acc += __shfl_xor(acc, m);
    if (lane == 0) {
      acc += lb[o];
      if (BNRELU) {
        float s = g[o] * (1.0f / sqrtf(1.0f + EPSF));
        acc = fmaxf(acc * s + bbias[o], 0.0f);
      }
      out[(size_t)b * OUT + o] = acc;
    }
  }
}

extern "C" void kernel_launch(void* const* d_in, const int* in_sizes, int n_in,
                              void* d_out, int out_size, void* d_ws, size_t ws_size,
                              hipStream_t stream) {
  const float* x   = (const float*)d_in[0];
  const float* w1  = (const float*)d_in[1];
  const float* g1  = (const float*)d_in[2];
  const float* b1  = (const float*)d_in[3];
  const float* w2  = (const float*)d_in[4];
  const float* g2  = (const float*)d_in[5];
  const float* b2  = (const float*)d_in[6];
  const float* w3  = (const float*)d_in[7];
  const float* g3  = (const float*)d_in[8];
  const float* b3  = (const float*)d_in[9];
  const float* w4  = (const float*)d_in[10];
  const float* g4  = (const float*)d_in[11];
  const float* b4  = (const float*)d_in[12];
  const float* lw1 = (const float*)d_in[13];
  const float* lb1 = (const float*)d_in[14];
  const float* g5  = (const float*)d_in[15];
  const float* b5  = (const float*)d_in[16];
  const float* lw2 = (const float*)d_in[17];
  const float* lb2 = (const float*)d_in[18];
  const float* g6  = (const float*)d_in[19];
  const float* b6  = (const float*)d_in[20];
  const float* lw3 = (const float*)d_in[21];
  const float* lb3 = (const float*)d_in[22];
  float* out = (float*)d_out;

  char* ws = (char*)d_ws;
  size_t off = 0;
  auto alloc = [&](size_t bytes) -> char* {
    char* p = ws + off;
    off += (bytes + 255) & ~255ULL;
    return p;
  };
  int*   idx    = (int*)  alloc((size_t)BB * NN * KK * 4);
  float* xx     = (float*)alloc((size_t)BB * NN * 4);
  float* xT0    = (float*)alloc((size_t)BB * 3 * NN * 4);
  float* bufA   = (float*)alloc((size_t)BB * NN * 64 * 4);
  float* bufB   = (float*)alloc((size_t)BB * NN * 64 * 4);
  float* pooled = (float*)alloc((size_t)BB * 320 * 4);
  float* h1     = (float*)alloc((size_t)BB * 1024 * 4);
  float* h2     = (float*)alloc((size_t)BB * 512 * 4);
  float* uc     = (float*)alloc((size_t)BB * NN * 256 * 4);
  ushort* xhl   = (ushort*)alloc((size_t)BB * NN * 128 * 2);

  size_t dbytes_per_b = (size_t)NN * NN * 4;
  size_t rem = (ws_size > off) ? (ws_size - off) : 0;
  int gmax = (int)(rem / dbytes_per_b);
  if (gmax > 32) gmax = 32;
  if (gmax < 1) gmax = 1;
  float* D = (float*)alloc((size_t)gmax * dbytes_per_b);

  dim3 blk(256);
  int bn_blocks = (BB * NN + 255) / 256;

  auto knn64 = [&]() {
    for (int b0 = 0; b0 < BB; b0 += gmax) {
      int gg = (BB - b0 < gmax) ? (BB - b0) : gmax;
      distm_kernel<<<dim3(NN / 128, NN / 128, gg), blk, 0, stream>>>(xhl, xx, D, b0);
      topk_kernel<<<(gg * NN) / 4, blk, 0, stream>>>(D, idx, b0);
    }
  };

  // ---- layer 1 (C=3 -> 64) ----
  t3xx_kernel<<<bn_blocks, blk, 0, stream>>>(x, xT0, xx, pooled);
  topk3_kernel<<<(BB * NN) / 4, blk, 0, stream>>>(x, xT0, xx, idx);
  uc3_kernel<<<(BB * NN * 128) / 256, blk, 0, stream>>>(x, w1, uc);
  gmp_kernel<64, true><<<(BB * NN * 16) / 256, blk, 0, stream>>>(
      uc, idx, g1, b1, bufA, (u32*)pooled, 0, xhl, xx);

  // ---- layer 2 (64 -> 64) ----
  knn64();
  ucpart_kernel<64><<<dim3((BB * NN) / 32, 2), blk, 0, stream>>>(bufA, w2, uc);
  gmp_kernel<64, true><<<(BB * NN * 16) / 256, blk, 0, stream>>>(
      uc, idx, g2, b2, bufB, (u32*)pooled, 64, xhl, xx);

  // ---- layer 3 (64 -> 64) ----
  knn64();
  ucpart_kernel<64><<<dim3((BB * NN) / 32, 2), blk, 0, stream>>>(bufB, w3, uc);
  gmp_kernel<64, true><<<(BB * NN * 16) / 256, blk, 0, stream>>>(
      uc, idx, g3, b3, bufA, (u32*)pooled, 128, xhl, xx);

  // ---- layer 4 (64 -> 128) ----
  knn64();
  ucpart_kernel<128><<<dim3((BB * NN) / 32, 2), blk, 0, stream>>>(bufA, w4, uc);
  gmp_kernel<128, false><<<(BB * NN * 32) / 256, blk, 0, stream>>>(
      uc, idx, g4, b4, bufB, (u32*)pooled, 192, nullptr, nullptr);

  // ---- classifier ----
  fcw_kernel<320, 1024, 32, true><<<dim3(BB, 8), blk, 0, stream>>>(pooled, lw1, lb1, g5, b5, h1);
  fcw_kernel<1024, 512, 16, true><<<dim3(BB, 8), blk, 0, stream>>>(h1, lw2, lb2, g6, b6, h2);
  fcw_kernel<512, 40, 10, false><<<dim3(BB, 1), blk, 0, stream>>>(h2, lw3, lb3, nullptr, nullptr, out);
}

// Round 8
// 563.900 us; speedup vs baseline: 7.0716x; 1.3031x over previous
//
#include <hip/hip_runtime.h>
#include <math.h>

#define BB 32
#define NN 1024
#define KK 20
typedef unsigned long long u64;
typedef unsigned int u32;
typedef unsigned short ushort;
static constexpr float EPSF = 1e-5f;

typedef __attribute__((ext_vector_type(8))) short bf16x8;
typedef __attribute__((ext_vector_type(4))) float f32x4;

// ---------------- fused transpose (B,N,3)->(B,3,N) + xx + pooled zero ----------------
__global__ void t3xx_kernel(const float* __restrict__ x, float* __restrict__ xT,
                            float* __restrict__ xx, float* __restrict__ pooled) {
  int t = blockIdx.x * blockDim.x + threadIdx.x;
  if (t >= BB * NN) return;
  if (t < BB * 320) pooled[t] = 0.0f;
  int b = t >> 10, i = t & (NN - 1);
  float v0 = x[(size_t)t * 3 + 0], v1 = x[(size_t)t * 3 + 1], v2 = x[(size_t)t * 3 + 2];
  xT[((size_t)b * 3 + 0) * NN + i] = v0;
  xT[((size_t)b * 3 + 1) * NN + i] = v1;
  xT[((size_t)b * 3 + 2) * NN + i] = v2;
  float s = 0.f;
  s += v0 * v0; s += v1 * v1; s += v2 * v2;
  xx[t] = s;
}

// ---------------- exact-integer f64 key: m(d)*1024 + (1023-j) ----------------
__device__ __forceinline__ double mkkeyd(float d, double idxd) {
  u32 bits = __float_as_uint(d);
  u32 m = (bits & 0x80000000u) ? ~bits : (bits | 0x80000000u);
  return fma((double)m, 1024.0, idxd);
}

__device__ __forceinline__ double shflxd(double v, int m) {
  long long u = __double_as_longlong(v);
  int lo = (int)(u & 0xFFFFFFFFll);
  int hi = (int)(((u64)u) >> 32);
  lo = __shfl_xor(lo, m);
  hi = __shfl_xor(hi, m);
  return __longlong_as_double(((long long)hi << 32) | (u32)lo);
}

__device__ __forceinline__ double shfld(double v, int src) {
  long long u = __double_as_longlong(v);
  int lo = (int)(u & 0xFFFFFFFFll);
  int hi = (int)(((u64)u) >> 32);
  lo = __shfl(lo, src);
  hi = __shfl(hi, src);
  return __longlong_as_double(((long long)hi << 32) | (u32)lo);
}

// descending bitonic sort of 64 doubles across lanes
__device__ __forceinline__ double lane_sort64(double v, int lane) {
  #pragma unroll
  for (int kk = 2; kk <= 64; kk <<= 1) {
    #pragma unroll
    for (int j = kk >> 1; j > 0; j >>= 1) {
      double pv = shflxd(v, j);
      bool keepMax = (((lane & j) == 0) == ((lane & kk) == 0));
      v = keepMax ? fmax(v, pv) : fmin(v, pv);
    }
  }
  return v;
}

__device__ __forceinline__ void key_decode_write(double res, int lane, int* __restrict__ orow) {
  if (lane < KK) {
    double md = trunc(res * (1.0 / 1024.0));
    double rd = fma(md, -1024.0, res);
    orow[lane] = 1023 - (int)rd;
  }
}

// filter-sort exact top-20: T = 20th-largest lane-head; survivors >= T; sort survivors.
__device__ __forceinline__ void topk_select(double (&k)[16], int lane,
                                            volatile double* __restrict__ sb,
                                            int* __restrict__ orow) {
  // per-lane head (tree max)
  double m0 = fmax(k[0], k[1]), m1 = fmax(k[2], k[3]), m2 = fmax(k[4], k[5]), m3 = fmax(k[6], k[7]);
  double m4 = fmax(k[8], k[9]), m5 = fmax(k[10], k[11]), m6 = fmax(k[12], k[13]), m7 = fmax(k[14], k[15]);
  m0 = fmax(m0, m1); m2 = fmax(m2, m3); m4 = fmax(m4, m5); m6 = fmax(m6, m7);
  m0 = fmax(m0, m2); m4 = fmax(m4, m6);
  double h = fmax(m0, m4);

  // sort heads desc, take 20th as threshold
  double sh = lane_sort64(h, lane);
  double T = shfld(sh, KK - 1);

  // count survivors per lane + wave scan
  int cnt = 0;
  #pragma unroll
  for (int e = 0; e < 16; ++e) cnt += (k[e] >= T) ? 1 : 0;
  int scan = cnt;
  #pragma unroll
  for (int d = 1; d < 64; d <<= 1) {
    int nv = __shfl_up(scan, d);
    if (lane >= d) scan += nv;
  }
  int total = __shfl(scan, 63);
  int ofs = scan - cnt;

  if (total <= 64) {
    sb[lane] = 0.0;
    #pragma unroll
    for (int e = 0; e < 16; ++e)
      if (k[e] >= T) { sb[ofs] = k[e]; ++ofs; }
    double v = sb[lane];
    v = lane_sort64(v, lane);
    key_decode_write(v, lane, orow);
  } else {
    // exact fallback: scan-removal tournament (rare; only near-degenerate data)
    double lm = h;
    double res = 0.0;
    for (int t = 0; t < KK; ++t) {
      double w = lm;
      #pragma unroll
      for (int m = 1; m < 64; m <<= 1) w = fmax(w, shflxd(w, m));
      if (lane == t) res = w;
      bool win = (lm == w);
      #pragma unroll
      for (int e = 0; e < 16; ++e) k[e] = (k[e] == w) ? 0.0 : k[e];
      if (win) {
        double n0 = fmax(k[0], k[1]);
        #pragma unroll
        for (int e = 2; e < 16; ++e) n0 = fmax(n0, k[e]);
        lm = n0;
      }
    }
    key_decode_write(res, lane, orow);
  }
}

// ---------------- MFMA split-bf16 dist: D[bg][i][j] = 2*dot(x_i,x_j) - xx_j ----------------
__global__ __launch_bounds__(256) void distm_kernel(
    const ushort* __restrict__ xhl,  // (B,N,128) [hi|lo]
    const float* __restrict__ xx,    // (B,N)
    float* __restrict__ D,           // (g,N,N)
    int b0) {
  int b = b0 + blockIdx.z;
  int w = threadIdx.x >> 6;
  int lane = threadIdx.x & 63;
  int wm = w >> 1, wn = w & 1;
  int i0 = blockIdx.y * 128 + wm * 64;
  int j0 = blockIdx.x * 128 + wn * 64;
  int r16 = lane & 15;
  int kg = lane >> 4;

  const ushort* base = xhl + (size_t)b * NN * 128;
  f32x4 acc[4][4];
  #pragma unroll
  for (int mi = 0; mi < 4; ++mi)
    #pragma unroll
    for (int ni = 0; ni < 4; ++ni) acc[mi][ni] = (f32x4){0.f, 0.f, 0.f, 0.f};

  #pragma unroll
  for (int ks = 0; ks < 2; ++ks) {
    int k0 = ks * 32 + kg * 8;
    bf16x8 ah[4], al[4], bh[4], bl[4];
    #pragma unroll
    for (int mi = 0; mi < 4; ++mi) {
      const ushort* pr = base + (size_t)(i0 + mi * 16 + r16) * 128 + k0;
      ah[mi] = *(const bf16x8*)pr;
      al[mi] = *(const bf16x8*)(pr + 64);
    }
    #pragma unroll
    for (int ni = 0; ni < 4; ++ni) {
      const ushort* pr = base + (size_t)(j0 + ni * 16 + r16) * 128 + k0;
      bh[ni] = *(const bf16x8*)pr;
      bl[ni] = *(const bf16x8*)(pr + 64);
    }
    #pragma unroll
    for (int mi = 0; mi < 4; ++mi)
      #pragma unroll
      for (int ni = 0; ni < 4; ++ni) {
        acc[mi][ni] = __builtin_amdgcn_mfma_f32_16x16x32_bf16(ah[mi], bh[ni], acc[mi][ni], 0, 0, 0);
        acc[mi][ni] = __builtin_amdgcn_mfma_f32_16x16x32_bf16(ah[mi], bl[ni], acc[mi][ni], 0, 0, 0);
        acc[mi][ni] = __builtin_amdgcn_mfma_f32_16x16x32_bf16(al[mi], bh[ni], acc[mi][ni], 0, 0, 0);
        acc[mi][ni] = __builtin_amdgcn_mfma_f32_16x16x32_bf16(al[mi], bl[ni], acc[mi][ni], 0, 0, 0);
      }
  }

  const float* xxb = xx + (size_t)b * NN;
  float* Dg = D + (size_t)blockIdx.z * NN * NN;
  #pragma unroll
  for (int ni = 0; ni < 4; ++ni) {
    float xj = xxb[j0 + ni * 16 + r16];
    #pragma unroll
    for (int mi = 0; mi < 4; ++mi) {
      int rowb = i0 + mi * 16 + kg * 4;
      #pragma unroll
      for (int r = 0; r < 4; ++r)
        Dg[(size_t)(rowb + r) * NN + j0 + ni * 16 + r16] = 2.f * acc[mi][ni][r] - xj;
    }
  }
}

// ---------------- wave-per-row top-20 ----------------
__global__ __launch_bounds__(256) void topk_kernel(
    const float* __restrict__ D, int* __restrict__ oidx, int b0) {
  __shared__ double sb[4][64];
  int wslot = threadIdx.x >> 6;
  int wid = (blockIdx.x << 2) + wslot;
  int lane = threadIdx.x & 63;
  int row = wid & (NN - 1);
  int bg = wid >> 10;

  const float4* dp = (const float4*)(D + ((size_t)bg * NN + row) * NN);
  double k[16];
  double based = (double)(1023 - lane * 4);
  #pragma unroll
  for (int q = 0; q < 4; ++q) {
    float4 v = dp[q * 64 + lane];
    double qb = based - (double)(q * 256);
    k[q * 4 + 0] = mkkeyd(v.x, qb - 0.0);
    k[q * 4 + 1] = mkkeyd(v.y, qb - 1.0);
    k[q * 4 + 2] = mkkeyd(v.z, qb - 2.0);
    k[q * 4 + 3] = mkkeyd(v.w, qb - 3.0);
  }
  topk_select(k, lane, &sb[wslot][0], oidx + ((size_t)(b0 + bg) * NN + row) * KK);
}

// ---------------- layer-1: fused C=3 distance + top-20 ----------------
__global__ __launch_bounds__(256) void topk3_kernel(
    const float* __restrict__ x,   // (B,N,3)
    const float* __restrict__ xT,  // (B,3,N)
    const float* __restrict__ xx,  // (B,N)
    int* __restrict__ oidx) {
  __shared__ double sb[4][64];
  int wslot = threadIdx.x >> 6;
  int wid = (blockIdx.x << 2) + wslot;
  int lane = threadIdx.x & 63;
  int row = wid & (NN - 1);
  int b = wid >> 10;

  const float* xr = x + ((size_t)b * NN + row) * 3;
  float x0 = xr[0], x1 = xr[1], x2 = xr[2];
  const float* xTb = xT + (size_t)b * 3 * NN;
  const float* xxb = xx + (size_t)b * NN;

  double k[16];
  double based = (double)(1023 - lane * 4);
  #pragma unroll
  for (int q = 0; q < 4; ++q) {
    int f4i = q * 64 + lane;
    float4 a  = ((const float4*)xTb)[f4i];
    float4 bv = ((const float4*)(xTb + NN))[f4i];
    float4 c  = ((const float4*)(xTb + 2 * NN))[f4i];
    float4 xj = ((const float4*)xxb)[f4i];
    float d0 = 0.f; d0 += x0 * a.x; d0 += x1 * bv.x; d0 += x2 * c.x;
    float d1 = 0.f; d1 += x0 * a.y; d1 += x1 * bv.y; d1 += x2 * c.y;
    float d2 = 0.f; d2 += x0 * a.z; d2 += x1 * bv.z; d2 += x2 * c.z;
    float d3 = 0.f; d3 += x0 * a.w; d3 += x1 * bv.w; d3 += x2 * c.w;
    double qb = based - (double)(q * 256);
    k[q * 4 + 0] = mkkeyd(2.f * d0 - xj.x, qb - 0.0);
    k[q * 4 + 1] = mkkeyd(2.f * d1 - xj.y, qb - 1.0);
    k[q * 4 + 2] = mkkeyd(2.f * d2 - xj.z, qb - 2.0);
    k[q * 4 + 3] = mkkeyd(2.f * d3 - xj.w, qb - 3.0);
  }
  topk_select(k, lane, &sb[wslot][0], oidx + ((size_t)b * NN + row) * KK);
}

// ---------------- uc part GEMM (both parts via blockIdx.y) ----------------
#define CC 64
template<int O>
__global__ __launch_bounds__(256) void ucpart_kernel(
    const float* __restrict__ x,   // (B,N,64)
    const float* __restrict__ w,   // (O,128)
    float* __restrict__ uc) {      // (B,N,2O)
  constexpr int PPT = 32 * O / 256;
  __shared__ float4 Ws[O * 16];
  __shared__ float4 As[32 * 16];

  int part = blockIdx.y;
  int tile = blockIdx.x;
  int b = tile >> 5;
  int i0 = (tile & 31) * 32;

  const float4* w4 = (const float4*)w;
  for (int r = threadIdx.x; r < O * 16; r += 256) {
    int rowc = r >> 4, c4 = r & 15;
    float4 v;
    if (part == 0) {
      v = w4[(size_t)rowc * 32 + c4];
    } else {
      float4 lo = w4[(size_t)rowc * 32 + c4];
      float4 hi = w4[(size_t)rowc * 32 + 16 + c4];
      v = make_float4(hi.x - lo.x, hi.y - lo.y, hi.z - lo.z, hi.w - lo.w);
    }
    Ws[(rowc << 4) + (c4 ^ (rowc & 7))] = v;
  }
  const float4* xa = (const float4*)(x + ((size_t)b * NN + i0) * CC);
  for (int r = threadIdx.x; r < 32 * 16; r += 256) As[r] = xa[r];
  __syncthreads();

  int col = threadIdx.x % O;
  int pg = threadIdx.x / O;
  float4 wc[16];
  #pragma unroll
  for (int c4 = 0; c4 < 16; ++c4) wc[c4] = Ws[(col << 4) + (c4 ^ (col & 7))];

  #pragma unroll
  for (int pp = 0; pp < PPT; ++pp) {
    int p = pg * PPT + pp;
    float acc = 0.f;
    #pragma unroll
    for (int c4 = 0; c4 < 16; ++c4) {
      float4 a = As[(p << 4) + c4];
      acc += a.x * wc[c4].x; acc += a.y * wc[c4].y;
      acc += a.z * wc[c4].z; acc += a.w * wc[c4].w;
    }
    uc[((size_t)b * NN + i0 + p) * (2 * O) + part * O + col] = acc;
  }
}

// ---------------- layer-1 uc (C=3) ----------------
__global__ __launch_bounds__(256) void uc3_kernel(
    const float* __restrict__ x, const float* __restrict__ w, float* __restrict__ uc) {
  int t = blockIdx.x * 256 + threadIdx.x;   // B*N*128
  int col = t & 127;
  int i = (t >> 7) & (NN - 1);
  int b = t >> 17;
  const float* xr = x + ((size_t)b * NN + i) * 3;
  float x0 = xr[0], x1 = xr[1], x2 = xr[2];
  float r;
  if (col < 64) {
    const float* wr = w + col * 6;
    r = wr[0] * x0 + wr[1] * x1 + wr[2] * x2;
  } else {
    const float* wr = w + (col - 64) * 6;
    r = (wr[3] - wr[0]) * x0 + (wr[4] - wr[1]) * x1 + (wr[5] - wr[2]) * x2;
  }
  uc[(size_t)t] = r;
}

// ---- gather-max + BN/ReLU + global-pool (atomicMax) + (if NEXT) y write + xx/xhl prep ----
template<int O, bool NEXT>
__global__ __launch_bounds__(256) void gmp_kernel(
    const float* __restrict__ uc,   // (B,N,2O)
    const int*   __restrict__ idx,  // (B,N,K)
    const float* __restrict__ g,
    const float* __restrict__ bb,
    float* __restrict__ y,          // (B,N,O)
    u32* __restrict__ pooled,       // (B,320) u32 bit patterns (all >= 0)
    int ooff,
    ushort* __restrict__ xhl,       // (B,N,128) [hi|lo]   (NEXT only)
    float* __restrict__ xx) {       // (B,N)               (NEXT only)
  constexpr int O4 = O / 4;
  constexpr int IPB = 256 / O4;
  int t = blockIdx.x * 256 + threadIdx.x;
  int o4 = t & (O4 - 1);
  int rest = t / O4;
  int i = rest & (NN - 1);
  int b = rest >> 10;

  const int* irow = idx + ((size_t)b * NN + i) * KK;
  int jj[KK];
  #pragma unroll
  for (int k = 0; k < KK; ++k) jj[k] = irow[k];

  const float* ucb = uc + (size_t)b * NN * (2 * O);
  float4 vm = make_float4(-INFINITY, -INFINITY, -INFINITY, -INFINITY);
  #pragma unroll
  for (int k = 0; k < KK; ++k) {
    float4 v = *(const float4*)(ucb + (size_t)jj[k] * (2 * O) + o4 * 4);
    vm.x = fmaxf(vm.x, v.x); vm.y = fmaxf(vm.y, v.y);
    vm.z = fmaxf(vm.z, v.z); vm.w = fmaxf(vm.w, v.w);
  }
  float4 c0 = *(const float4*)(ucb + (size_t)i * (2 * O) + O + o4 * 4);
  float4 gv = ((const float4*)g)[o4];
  float4 bv = ((const float4*)bb)[o4];
  const float inv = 1.0f / sqrtf(1.0f + EPSF);
  float4 o;
  o.x = fmaxf((gv.x * inv) * (vm.x + c0.x) + bv.x, 0.f);
  o.y = fmaxf((gv.y * inv) * (vm.y + c0.y) + bv.y, 0.f);
  o.z = fmaxf((gv.z * inv) * (vm.z + c0.z) + bv.z, 0.f);
  o.w = fmaxf((gv.w * inv) * (vm.w + c0.w) + bv.w, 0.f);

  if constexpr (NEXT) {
    *(float4*)(y + ((size_t)b * NN + i) * O + o4 * 4) = o;
    ushort4 hi, lo;
    u32 q0 = __float_as_uint(o.x); hi.x = q0 >> 16;
    u32 q1 = __float_as_uint(o.y); hi.y = q1 >> 16;
    u32 q2 = __float_as_uint(o.z); hi.z = q2 >> 16;
    u32 q3 = __float_as_uint(o.w); hi.w = q3 >> 16;
    lo.x = __float_as_uint(o.x - __uint_as_float(q0 & 0xFFFF0000u)) >> 16;
    lo.y = __float_as_uint(o.y - __uint_as_float(q1 & 0xFFFF0000u)) >> 16;
    lo.z = __float_as_uint(o.z - __uint_as_float(q2 & 0xFFFF0000u)) >> 16;
    lo.w = __float_as_uint(o.w - __uint_as_float(q3 & 0xFFFF0000u)) >> 16;
    ushort* xr = xhl + ((size_t)b * NN + i) * 128;
    *(ushort4*)(xr + o4 * 4) = hi;
    *(ushort4*)(xr + 64 + o4 * 4) = lo;
    float px = o.x * o.x + o.y * o.y + o.z * o.z + o.w * o.w;
    px += __shfl_xor(px, 1);
    px += __shfl_xor(px, 2);
    px += __shfl_xor(px, 4);
    px += __shfl_xor(px, 8);
    if (o4 == 0) xx[(size_t)b * NN + i] = px;
  }

  __shared__ float4 sm[256];
  sm[threadIdx.x] = o;
  __syncthreads();
  if (threadIdx.x < O4) {
    float4 m = sm[threadIdx.x];
    #pragma unroll
    for (int r = 1; r < IPB; ++r) {
      float4 v = sm[threadIdx.x + r * O4];
      m.x = fmaxf(m.x, v.x); m.y = fmaxf(m.y, v.y);
      m.z = fmaxf(m.z, v.z); m.w = fmaxf(m.w, v.w);
    }
    u32* dst = pooled + (size_t)b * 320 + ooff + threadIdx.x * 4;
    atomicMax(dst + 0, __float_as_uint(m.x));
    atomicMax(dst + 1, __float_as_uint(m.y));
    atomicMax(dst + 2, __float_as_uint(m.z));
    atomicMax(dst + 3, __float_as_uint(m.w));
  }
}

// ---------------- coalesced fc: wave-per-output, LDS-staged input ----------------
template<int IN, int OUT, int OPW, bool BNRELU>
__global__ __launch_bounds__(256) void fcw_kernel(
    const float* __restrict__ in, const float* __restrict__ W,
    const float* __restrict__ lb, const float* __restrict__ g,
    const float* __restrict__ bbias, float* __restrict__ out) {
  int b = blockIdx.x;
  int oc = blockIdx.y;
  __shared__ float sIn[IN];
  for (int r = threadIdx.x; r < IN; r += 256) sIn[r] = in[(size_t)b * IN + r];
  __syncthreads();
  int w = threadIdx.x >> 6, lane = threadIdx.x & 63;
  constexpr int RPL = IN / 64;
  for (int ii = 0; ii < OPW; ++ii) {
    int o = (oc * 4 + w) * OPW + ii;
    const float* wr = W + (size_t)o * IN;
    float acc = 0.f;
    #pragma unroll
    for (int r = 0; r < RPL; ++r) acc += wr[r * 64 + lane] * sIn[r * 64 + lane];
    #pragma unroll
    for (int m = 32; m >= 1; m >>= 1) acc += __shfl_xor(acc, m);
    if (lane == 0) {
      acc += lb[o];
      if (BNRELU) {
        float s = g[o] * (1.0f / sqrtf(1.0f + EPSF));
        acc = fmaxf(acc * s + bbias[o], 0.0f);
      }
      out[(size_t)b * OUT + o] = acc;
    }
  }
}

extern "C" void kernel_launch(void* const* d_in, const int* in_sizes, int n_in,
                              void* d_out, int out_size, void* d_ws, size_t ws_size,
                              hipStream_t stream) {
  const float* x   = (const float*)d_in[0];
  const float* w1  = (const float*)d_in[1];
  const float* g1  = (const float*)d_in[2];
  const float* b1  = (const float*)d_in[3];
  const float* w2  = (const float*)d_in[4];
  const float* g2  = (const float*)d_in[5];
  const float* b2  = (const float*)d_in[6];
  const float* w3  = (const float*)d_in[7];
  const float* g3  = (const float*)d_in[8];
  const float* b3  = (const float*)d_in[9];
  const float* w4  = (const float*)d_in[10];
  const float* g4  = (const float*)d_in[11];
  const float* b4  = (const float*)d_in[12];
  const float* lw1 = (const float*)d_in[13];
  const float* lb1 = (const float*)d_in[14];
  const float* g5  = (const float*)d_in[15];
  const float* b5  = (const float*)d_in[16];
  const float* lw2 = (const float*)d_in[17];
  const float* lb2 = (const float*)d_in[18];
  const float* g6  = (const float*)d_in[19];
  const float* b6  = (const float*)d_in[20];
  const float* lw3 = (const float*)d_in[21];
  const float* lb3 = (const float*)d_in[22];
  float* out = (float*)d_out;

  char* ws = (char*)d_ws;
  size_t off = 0;
  auto alloc = [&](size_t bytes) -> char* {
    char* p = ws + off;
    off += (bytes + 255) & ~255ULL;
    return p;
  };
  int*   idx    = (int*)  alloc((size_t)BB * NN * KK * 4);
  float* xx     = (float*)alloc((size_t)BB * NN * 4);
  float* xT0    = (float*)alloc((size_t)BB * 3 * NN * 4);
  float* bufA   = (float*)alloc((size_t)BB * NN * 64 * 4);
  float* bufB   = (float*)alloc((size_t)BB * NN * 64 * 4);
  float* pooled = (float*)alloc((size_t)BB * 320 * 4);
  float* h1     = (float*)alloc((size_t)BB * 1024 * 4);
  float* h2     = (float*)alloc((size_t)BB * 512 * 4);
  float* uc     = (float*)alloc((size_t)BB * NN * 256 * 4);
  ushort* xhl   = (ushort*)alloc((size_t)BB * NN * 128 * 2);

  size_t dbytes_per_b = (size_t)NN * NN * 4;
  size_t rem = (ws_size > off) ? (ws_size - off) : 0;
  int gmax = (int)(rem / dbytes_per_b);
  if (gmax > 32) gmax = 32;
  if (gmax < 1) gmax = 1;
  float* D = (float*)alloc((size_t)gmax * dbytes_per_b);

  dim3 blk(256);
  int bn_blocks = (BB * NN + 255) / 256;

  auto knn64 = [&]() {
    for (int b0 = 0; b0 < BB; b0 += gmax) {
      int gg = (BB - b0 < gmax) ? (BB - b0) : gmax;
      distm_kernel<<<dim3(NN / 128, NN / 128, gg), blk, 0, stream>>>(xhl, xx, D, b0);
      topk_kernel<<<(gg * NN) / 4, blk, 0, stream>>>(D, idx, b0);
    }
  };

  // ---- layer 1 (C=3 -> 64) ----
  t3xx_kernel<<<bn_blocks, blk, 0, stream>>>(x, xT0, xx, pooled);
  topk3_kernel<<<(BB * NN) / 4, blk, 0, stream>>>(x, xT0, xx, idx);
  uc3_kernel<<<(BB * NN * 128) / 256, blk, 0, stream>>>(x, w1, uc);
  gmp_kernel<64, true><<<(BB * NN * 16) / 256, blk, 0, stream>>>(
      uc, idx, g1, b1, bufA, (u32*)pooled, 0, xhl, xx);

  // ---- layer 2 (64 -> 64) ----
  knn64();
  ucpart_kernel<64><<<dim3((BB * NN) / 32, 2), blk, 0, stream>>>(bufA, w2, uc);
  gmp_kernel<64, true><<<(BB * NN * 16) / 256, blk, 0, stream>>>(
      uc, idx, g2, b2, bufB, (u32*)pooled, 64, xhl, xx);

  // ---- layer 3 (64 -> 64) ----
  knn64();
  ucpart_kernel<64><<<dim3((BB * NN) / 32, 2), blk, 0, stream>>>(bufB, w3, uc);
  gmp_kernel<64, true><<<(BB * NN * 16) / 256, blk, 0, stream>>>(
      uc, idx, g3, b3, bufA, (u32*)pooled, 128, xhl, xx);

  // ---- layer 4 (64 -> 128) ----
  knn64();
  ucpart_kernel<128><<<dim3((BB * NN) / 32, 2), blk, 0, stream>>>(bufA, w4, uc);
  gmp_kernel<128, false><<<(BB * NN * 32) / 256, blk, 0, stream>>>(
      uc, idx, g4, b4, bufB, (u32*)pooled, 192, nullptr, nullptr);

  // ---- classifier ----
  fcw_kernel<320, 1024, 32, true><<<dim3(BB, 8), blk, 0, stream>>>(pooled, lw1, lb1, g5, b5, h1);
  fcw_kernel<1024, 512, 16, true><<<dim3(BB, 8), blk, 0, stream>>>(h1, lw2, lb2, g6, b6, h2);
  fcw_kernel<512, 40, 10, false><<<dim3(BB, 1), blk, 0, stream>>>(h2, lw3, lb3, nullptr, nullptr, out);
}

// Round 9
// 484.556 us; speedup vs baseline: 8.2295x; 1.1637x over previous
//
#include <hip/hip_runtime.h>
#include <math.h>

#define BB 32
#define NN 1024
#define KK 20
typedef unsigned long long u64;
typedef unsigned int u32;
typedef unsigned short ushort;
static constexpr float EPSF = 1e-5f;

typedef __attribute__((ext_vector_type(8))) short bf16x8;
typedef __attribute__((ext_vector_type(4))) float f32x4;

// ---------------- fused transpose (B,N,3)->(B,3,N) + xx + pooled zero ----------------
__global__ void t3xx_kernel(const float* __restrict__ x, float* __restrict__ xT,
                            float* __restrict__ xx, float* __restrict__ pooled) {
  int t = blockIdx.x * blockDim.x + threadIdx.x;
  if (t >= BB * NN) return;
  if (t < BB * 320) pooled[t] = 0.0f;
  int b = t >> 10, i = t & (NN - 1);
  float v0 = x[(size_t)t * 3 + 0], v1 = x[(size_t)t * 3 + 1], v2 = x[(size_t)t * 3 + 2];
  xT[((size_t)b * 3 + 0) * NN + i] = v0;
  xT[((size_t)b * 3 + 1) * NN + i] = v1;
  xT[((size_t)b * 3 + 2) * NN + i] = v2;
  float s = 0.f;
  s += v0 * v0; s += v1 * v1; s += v2 * v2;
  xx[t] = s;
}

// ---------------- exact-integer f64 key: m(d)*1024 + (1023-j) ----------------
__device__ __forceinline__ double mkkeyd(float d, double idxd) {
  u32 bits = __float_as_uint(d);
  u32 m = (bits & 0x80000000u) ? ~bits : (bits | 0x80000000u);
  return fma((double)m, 1024.0, idxd);
}

__device__ __forceinline__ double shflxd(double v, int m) {
  long long u = __double_as_longlong(v);
  int lo = (int)(u & 0xFFFFFFFFll);
  int hi = (int)(((u64)u) >> 32);
  lo = __shfl_xor(lo, m);
  hi = __shfl_xor(hi, m);
  return __longlong_as_double(((long long)hi << 32) | (u32)lo);
}

__device__ __forceinline__ double shfld(double v, int src) {
  long long u = __double_as_longlong(v);
  int lo = (int)(u & 0xFFFFFFFFll);
  int hi = (int)(((u64)u) >> 32);
  lo = __shfl(lo, src);
  hi = __shfl(hi, src);
  return __longlong_as_double(((long long)hi << 32) | (u32)lo);
}

// descending bitonic sort of 64 doubles across lanes
__device__ __forceinline__ double lane_sort64(double v, int lane) {
  #pragma unroll
  for (int kk = 2; kk <= 64; kk <<= 1) {
    #pragma unroll
    for (int j = kk >> 1; j > 0; j >>= 1) {
      double pv = shflxd(v, j);
      bool keepMax = (((lane & j) == 0) == ((lane & kk) == 0));
      v = keepMax ? fmax(v, pv) : fmin(v, pv);
    }
  }
  return v;
}

__device__ __forceinline__ void key_decode_write(double res, int lane, int* __restrict__ orow) {
  if (lane < KK) {
    double md = trunc(res * (1.0 / 1024.0));
    double rd = fma(md, -1024.0, res);
    orow[lane] = 1023 - (int)rd;
  }
}

// filter-sort exact top-20
__device__ __forceinline__ void topk_select(double (&k)[16], int lane,
                                            volatile double* __restrict__ sb,
                                            int* __restrict__ orow) {
  double m0 = fmax(k[0], k[1]), m1 = fmax(k[2], k[3]), m2 = fmax(k[4], k[5]), m3 = fmax(k[6], k[7]);
  double m4 = fmax(k[8], k[9]), m5 = fmax(k[10], k[11]), m6 = fmax(k[12], k[13]), m7 = fmax(k[14], k[15]);
  m0 = fmax(m0, m1); m2 = fmax(m2, m3); m4 = fmax(m4, m5); m6 = fmax(m6, m7);
  m0 = fmax(m0, m2); m4 = fmax(m4, m6);
  double h = fmax(m0, m4);

  double sh = lane_sort64(h, lane);
  double T = shfld(sh, KK - 1);

  int cnt = 0;
  #pragma unroll
  for (int e = 0; e < 16; ++e) cnt += (k[e] >= T) ? 1 : 0;
  int scan = cnt;
  #pragma unroll
  for (int d = 1; d < 64; d <<= 1) {
    int nv = __shfl_up(scan, d);
    if (lane >= d) scan += nv;
  }
  int total = __shfl(scan, 63);
  int ofs = scan - cnt;

  if (total <= 64) {
    sb[lane] = 0.0;
    #pragma unroll
    for (int e = 0; e < 16; ++e)
      if (k[e] >= T) { sb[ofs] = k[e]; ++ofs; }
    double v = sb[lane];
    v = lane_sort64(v, lane);
    key_decode_write(v, lane, orow);
  } else {
    double lm = h;
    double res = 0.0;
    for (int t = 0; t < KK; ++t) {
      double w = lm;
      #pragma unroll
      for (int m = 1; m < 64; m <<= 1) w = fmax(w, shflxd(w, m));
      if (lane == t) res = w;
      bool win = (lm == w);
      #pragma unroll
      for (int e = 0; e < 16; ++e) k[e] = (k[e] == w) ? 0.0 : k[e];
      if (win) {
        double n0 = fmax(k[0], k[1]);
        #pragma unroll
        for (int e = 2; e < 16; ++e) n0 = fmax(n0, k[e]);
        lm = n0;
      }
    }
    key_decode_write(res, lane, orow);
  }
}

// ---------------- MFMA split-bf16 dist (XCD-swizzled blocks) ----------------
// gshift >= 0: gg >= 8, batch b = b0 + (bid&7) + 8*(rest & (2^gshift-1)); else plain.
__global__ __launch_bounds__(256) void distm_kernel(
    const ushort* __restrict__ xhl,  // (B,N,128) [hi|lo]
    const float* __restrict__ xx,    // (B,N)
    float* __restrict__ D,           // (g,N,N)
    int b0, int gshift) {
  int bid = blockIdx.x;
  int b, tile;
  if (gshift >= 0) {
    int xcd = bid & 7;
    int rest = bid >> 3;
    int bl = rest & ((1 << gshift) - 1);
    tile = rest >> gshift;
    b = b0 + xcd + (bl << 3);
  } else {
    b = b0 + (bid >> 6);
    tile = bid & 63;
  }
  int dloc = b - b0;
  int w = threadIdx.x >> 6;
  int lane = threadIdx.x & 63;
  int wm = w >> 1, wn = w & 1;
  int i0 = (tile >> 3) * 128 + wm * 64;
  int j0 = (tile & 7) * 128 + wn * 64;
  int r16 = lane & 15;
  int kg = lane >> 4;

  const ushort* base = xhl + (size_t)b * NN * 128;
  f32x4 acc[4][4];
  #pragma unroll
  for (int mi = 0; mi < 4; ++mi)
    #pragma unroll
    for (int ni = 0; ni < 4; ++ni) acc[mi][ni] = (f32x4){0.f, 0.f, 0.f, 0.f};

  #pragma unroll
  for (int ks = 0; ks < 2; ++ks) {
    int k0 = ks * 32 + kg * 8;
    bf16x8 ah[4], al[4], bh[4], bl[4];
    #pragma unroll
    for (int mi = 0; mi < 4; ++mi) {
      const ushort* pr = base + (size_t)(i0 + mi * 16 + r16) * 128 + k0;
      ah[mi] = *(const bf16x8*)pr;
      al[mi] = *(const bf16x8*)(pr + 64);
    }
    #pragma unroll
    for (int ni = 0; ni < 4; ++ni) {
      const ushort* pr = base + (size_t)(j0 + ni * 16 + r16) * 128 + k0;
      bh[ni] = *(const bf16x8*)pr;
      bl[ni] = *(const bf16x8*)(pr + 64);
    }
    #pragma unroll
    for (int mi = 0; mi < 4; ++mi)
      #pragma unroll
      for (int ni = 0; ni < 4; ++ni) {
        acc[mi][ni] = __builtin_amdgcn_mfma_f32_16x16x32_bf16(ah[mi], bh[ni], acc[mi][ni], 0, 0, 0);
        acc[mi][ni] = __builtin_amdgcn_mfma_f32_16x16x32_bf16(ah[mi], bl[ni], acc[mi][ni], 0, 0, 0);
        acc[mi][ni] = __builtin_amdgcn_mfma_f32_16x16x32_bf16(al[mi], bh[ni], acc[mi][ni], 0, 0, 0);
        acc[mi][ni] = __builtin_amdgcn_mfma_f32_16x16x32_bf16(al[mi], bl[ni], acc[mi][ni], 0, 0, 0);
      }
  }

  const float* xxb = xx + (size_t)b * NN;
  float* Dg = D + (size_t)dloc * NN * NN;
  #pragma unroll
  for (int ni = 0; ni < 4; ++ni) {
    float xj = xxb[j0 + ni * 16 + r16];
    #pragma unroll
    for (int mi = 0; mi < 4; ++mi) {
      int rowb = i0 + mi * 16 + kg * 4;
      #pragma unroll
      for (int r = 0; r < 4; ++r)
        Dg[(size_t)(rowb + r) * NN + j0 + ni * 16 + r16] = 2.f * acc[mi][ni][r] - xj;
    }
  }
}

// ---------------- wave-per-row top-20 ----------------
__global__ __launch_bounds__(256) void topk_kernel(
    const float* __restrict__ D, int* __restrict__ oidx, int b0) {
  __shared__ double sb[4][64];
  int wslot = threadIdx.x >> 6;
  int wid = (blockIdx.x << 2) + wslot;
  int lane = threadIdx.x & 63;
  int row = wid & (NN - 1);
  int bg = wid >> 10;

  const float4* dp = (const float4*)(D + ((size_t)bg * NN + row) * NN);
  double k[16];
  double based = (double)(1023 - lane * 4);
  #pragma unroll
  for (int q = 0; q < 4; ++q) {
    float4 v = dp[q * 64 + lane];
    double qb = based - (double)(q * 256);
    k[q * 4 + 0] = mkkeyd(v.x, qb - 0.0);
    k[q * 4 + 1] = mkkeyd(v.y, qb - 1.0);
    k[q * 4 + 2] = mkkeyd(v.z, qb - 2.0);
    k[q * 4 + 3] = mkkeyd(v.w, qb - 3.0);
  }
  topk_select(k, lane, &sb[wslot][0], oidx + ((size_t)(b0 + bg) * NN + row) * KK);
}

// ---------------- layer-1: fused C=3 distance + top-20 ----------------
__global__ __launch_bounds__(256) void topk3_kernel(
    const float* __restrict__ x,   // (B,N,3)
    const float* __restrict__ xT,  // (B,3,N)
    const float* __restrict__ xx,  // (B,N)
    int* __restrict__ oidx) {
  __shared__ double sb[4][64];
  int wslot = threadIdx.x >> 6;
  int wid = (blockIdx.x << 2) + wslot;
  int lane = threadIdx.x & 63;
  int row = wid & (NN - 1);
  int b = wid >> 10;

  const float* xr = x + ((size_t)b * NN + row) * 3;
  float x0 = xr[0], x1 = xr[1], x2 = xr[2];
  const float* xTb = xT + (size_t)b * 3 * NN;
  const float* xxb = xx + (size_t)b * NN;

  double k[16];
  double based = (double)(1023 - lane * 4);
  #pragma unroll
  for (int q = 0; q < 4; ++q) {
    int f4i = q * 64 + lane;
    float4 a  = ((const float4*)xTb)[f4i];
    float4 bv = ((const float4*)(xTb + NN))[f4i];
    float4 c  = ((const float4*)(xTb + 2 * NN))[f4i];
    float4 xj = ((const float4*)xxb)[f4i];
    float d0 = 0.f; d0 += x0 * a.x; d0 += x1 * bv.x; d0 += x2 * c.x;
    float d1 = 0.f; d1 += x0 * a.y; d1 += x1 * bv.y; d1 += x2 * c.y;
    float d2 = 0.f; d2 += x0 * a.z; d2 += x1 * bv.z; d2 += x2 * c.z;
    float d3 = 0.f; d3 += x0 * a.w; d3 += x1 * bv.w; d3 += x2 * c.w;
    double qb = based - (double)(q * 256);
    k[q * 4 + 0] = mkkeyd(2.f * d0 - xj.x, qb - 0.0);
    k[q * 4 + 1] = mkkeyd(2.f * d1 - xj.y, qb - 1.0);
    k[q * 4 + 2] = mkkeyd(2.f * d2 - xj.z, qb - 2.0);
    k[q * 4 + 3] = mkkeyd(2.f * d3 - xj.w, qb - 3.0);
  }
  topk_select(k, lane, &sb[wslot][0], oidx + ((size_t)b * NN + row) * KK);
}

// ---------------- uc part GEMM (both parts via blockIdx.y) ----------------
#define CC 64
template<int O>
__global__ __launch_bounds__(256) void ucpart_kernel(
    const float* __restrict__ x,   // (B,N,64)
    const float* __restrict__ w,   // (O,128)
    float* __restrict__ uc) {      // (B,N,2O)
  constexpr int PPT = 32 * O / 256;
  __shared__ float4 Ws[O * 16];
  __shared__ float4 As[32 * 16];

  int part = blockIdx.y;
  int tile = blockIdx.x;
  int b = tile >> 5;
  int i0 = (tile & 31) * 32;

  const float4* w4 = (const float4*)w;
  for (int r = threadIdx.x; r < O * 16; r += 256) {
    int rowc = r >> 4, c4 = r & 15;
    float4 v;
    if (part == 0) {
      v = w4[(size_t)rowc * 32 + c4];
    } else {
      float4 lo = w4[(size_t)rowc * 32 + c4];
      float4 hi = w4[(size_t)rowc * 32 + 16 + c4];
      v = make_float4(hi.x - lo.x, hi.y - lo.y, hi.z - lo.z, hi.w - lo.w);
    }
    Ws[(rowc << 4) + (c4 ^ (rowc & 7))] = v;
  }
  const float4* xa = (const float4*)(x + ((size_t)b * NN + i0) * CC);
  for (int r = threadIdx.x; r < 32 * 16; r += 256) As[r] = xa[r];
  __syncthreads();

  int col = threadIdx.x % O;
  int pg = threadIdx.x / O;
  float4 wc[16];
  #pragma unroll
  for (int c4 = 0; c4 < 16; ++c4) wc[c4] = Ws[(col << 4) + (c4 ^ (col & 7))];

  #pragma unroll
  for (int pp = 0; pp < PPT; ++pp) {
    int p = pg * PPT + pp;
    float acc = 0.f;
    #pragma unroll
    for (int c4 = 0; c4 < 16; ++c4) {
      float4 a = As[(p << 4) + c4];
      acc += a.x * wc[c4].x; acc += a.y * wc[c4].y;
      acc += a.z * wc[c4].z; acc += a.w * wc[c4].w;
    }
    uc[((size_t)b * NN + i0 + p) * (2 * O) + part * O + col] = acc;
  }
}

// ---------------- layer-1 uc (C=3) ----------------
__global__ void uc3_kernel(
    const float* __restrict__ x, const float* __restrict__ w, float* __restrict__ uc) {
  int t = blockIdx.x * 256 + threadIdx.x;   // B*N*128
  int col = t & 127;
  int i = (t >> 7) & (NN - 1);
  int b = t >> 17;
  const float* xr = x + ((size_t)b * NN + i) * 3;
  float x0 = xr[0], x1 = xr[1], x2 = xr[2];
  float r;
  if (col < 64) {
    const float* wr = w + col * 6;
    r = wr[0] * x0 + wr[1] * x1 + wr[2] * x2;
  } else {
    const float* wr = w + (col - 64) * 6;
    r = (wr[3] - wr[0]) * x0 + (wr[4] - wr[1]) * x1 + (wr[5] - wr[2]) * x2;
  }
  uc[(size_t)t] = r;
}

// ---- gather-max + BN/ReLU + global-pool + (NEXT) y/xhl/xx prep. XCD-swizzled blocks. ----
template<int O, bool NEXT>
__global__ __launch_bounds__(256) void gmp_kernel(
    const float* __restrict__ uc,   // (B,N,2O)
    const int*   __restrict__ idx,  // (B,N,K)
    const float* __restrict__ g,
    const float* __restrict__ bb,
    float* __restrict__ y,          // (B,N,O)
    u32* __restrict__ pooled,       // (B,320) u32 bit patterns (all >= 0)
    int ooff,
    ushort* __restrict__ xhl,       // (B,N,128) [hi|lo]   (NEXT only)
    float* __restrict__ xx) {       // (B,N)               (NEXT only)
  constexpr int O4 = O / 4;
  constexpr int PPB = 256 / O4;
  // swizzle: all blocks of batch b land on XCD b%8 (4 batches per XCD -> L2-local gather)
  int bid = blockIdx.x;
  int xcd = bid & 7;
  int rest = bid >> 3;
  int bgrp = rest & 3;
  int jblk = rest >> 2;
  int b = xcd + (bgrp << 3);
  int o4 = threadIdx.x & (O4 - 1);
  int i = jblk * PPB + (threadIdx.x >> (O == 64 ? 4 : 5));

  const int* irow = idx + ((size_t)b * NN + i) * KK;
  int jj[KK];
  #pragma unroll
  for (int k = 0; k < KK; ++k) jj[k] = irow[k];

  const float* ucb = uc + (size_t)b * NN * (2 * O);
  float4 vm = make_float4(-INFINITY, -INFINITY, -INFINITY, -INFINITY);
  #pragma unroll
  for (int k = 0; k < KK; ++k) {
    float4 v = *(const float4*)(ucb + (size_t)jj[k] * (2 * O) + o4 * 4);
    vm.x = fmaxf(vm.x, v.x); vm.y = fmaxf(vm.y, v.y);
    vm.z = fmaxf(vm.z, v.z); vm.w = fmaxf(vm.w, v.w);
  }
  float4 c0 = *(const float4*)(ucb + (size_t)i * (2 * O) + O + o4 * 4);
  float4 gv = ((const float4*)g)[o4];
  float4 bv = ((const float4*)bb)[o4];
  const float inv = 1.0f / sqrtf(1.0f + EPSF);
  float4 o;
  o.x = fmaxf((gv.x * inv) * (vm.x + c0.x) + bv.x, 0.f);
  o.y = fmaxf((gv.y * inv) * (vm.y + c0.y) + bv.y, 0.f);
  o.z = fmaxf((gv.z * inv) * (vm.z + c0.z) + bv.z, 0.f);
  o.w = fmaxf((gv.w * inv) * (vm.w + c0.w) + bv.w, 0.f);

  if constexpr (NEXT) {
    *(float4*)(y + ((size_t)b * NN + i) * O + o4 * 4) = o;
    ushort4 hi, lo;
    u32 q0 = __float_as_uint(o.x); hi.x = q0 >> 16;
    u32 q1 = __float_as_uint(o.y); hi.y = q1 >> 16;
    u32 q2 = __float_as_uint(o.z); hi.z = q2 >> 16;
    u32 q3 = __float_as_uint(o.w); hi.w = q3 >> 16;
    lo.x = __float_as_uint(o.x - __uint_as_float(q0 & 0xFFFF0000u)) >> 16;
    lo.y = __float_as_uint(o.y - __uint_as_float(q1 & 0xFFFF0000u)) >> 16;
    lo.z = __float_as_uint(o.z - __uint_as_float(q2 & 0xFFFF0000u)) >> 16;
    lo.w = __float_as_uint(o.w - __uint_as_float(q3 & 0xFFFF0000u)) >> 16;
    ushort* xr = xhl + ((size_t)b * NN + i) * 128;
    *(ushort4*)(xr + o4 * 4) = hi;
    *(ushort4*)(xr + 64 + o4 * 4) = lo;
    float px = o.x * o.x + o.y * o.y + o.z * o.z + o.w * o.w;
    px += __shfl_xor(px, 1);
    px += __shfl_xor(px, 2);
    px += __shfl_xor(px, 4);
    px += __shfl_xor(px, 8);
    if (o4 == 0) xx[(size_t)b * NN + i] = px;
  }

  __shared__ float4 sm[256];
  sm[threadIdx.x] = o;
  __syncthreads();
  if (threadIdx.x < O4) {
    float4 m = sm[threadIdx.x];
    #pragma unroll
    for (int r = 1; r < PPB; ++r) {
      float4 v = sm[threadIdx.x + r * O4];
      m.x = fmaxf(m.x, v.x); m.y = fmaxf(m.y, v.y);
      m.z = fmaxf(m.z, v.z); m.w = fmaxf(m.w, v.w);
    }
    u32* dst = pooled + (size_t)b * 320 + ooff + threadIdx.x * 4;
    atomicMax(dst + 0, __float_as_uint(m.x));
    atomicMax(dst + 1, __float_as_uint(m.y));
    atomicMax(dst + 2, __float_as_uint(m.z));
    atomicMax(dst + 3, __float_as_uint(m.w));
  }
}

// ---------------- coalesced fc: wave-per-output, LDS-staged input ----------------
template<int IN, int OUT, int OPW, bool BNRELU>
__global__ __launch_bounds__(256) void fcw_kernel(
    const float* __restrict__ in, const float* __restrict__ W,
    const float* __restrict__ lb, const float* __restrict__ g,
    const float* __restrict__ bbias, float* __restrict__ out) {
  int b = blockIdx.x;
  int oc = blockIdx.y;
  __shared__ float sIn[IN];
  for (int r = threadIdx.x; r < IN; r += 256) sIn[r] = in[(size_t)b * IN + r];
  __syncthreads();
  int w = threadIdx.x >> 6, lane = threadIdx.x & 63;
  constexpr int RPL = IN / 64;
  for (int ii = 0; ii < OPW; ++ii) {
    int o = (oc * 4 + w) * OPW + ii;
    const float* wr = W + (size_t)o * IN;
    float acc = 0.f;
    #pragma unroll
    for (int r = 0; r < RPL; ++r) acc += wr[r * 64 + lane] * sIn[r * 64 + lane];
    #pragma unroll
    for (int m = 32; m >= 1; m >>= 1) acc += __shfl_xor(acc, m);
    if (lane == 0) {
      acc += lb[o];
      if (BNRELU) {
        float s = g[o] * (1.0f / sqrtf(1.0f + EPSF));
        acc = fmaxf(acc * s + bbias[o], 0.0f);
      }
      out[(size_t)b * OUT + o] = acc;
    }
  }
}

extern "C" void kernel_launch(void* const* d_in, const int* in_sizes, int n_in,
                              void* d_out, int out_size, void* d_ws, size_t ws_size,
                              hipStream_t stream) {
  const float* x   = (const float*)d_in[0];
  const float* w1  = (const float*)d_in[1];
  const float* g1  = (const float*)d_in[2];
  const float* b1  = (const float*)d_in[3];
  const float* w2  = (const float*)d_in[4];
  const float* g2  = (const float*)d_in[5];
  const float* b2  = (const float*)d_in[6];
  const float* w3  = (const float*)d_in[7];
  const float* g3  = (const float*)d_in[8];
  const float* b3  = (const float*)d_in[9];
  const float* w4  = (const float*)d_in[10];
  const float* g4  = (const float*)d_in[11];
  const float* b4  = (const float*)d_in[12];
  const float* lw1 = (const float*)d_in[13];
  const float* lb1 = (const float*)d_in[14];
  const float* g5  = (const float*)d_in[15];
  const float* b5  = (const float*)d_in[16];
  const float* lw2 = (const float*)d_in[17];
  const float* lb2 = (const float*)d_in[18];
  const float* g6  = (const float*)d_in[19];
  const float* b6  = (const float*)d_in[20];
  const float* lw3 = (const float*)d_in[21];
  const float* lb3 = (const float*)d_in[22];
  float* out = (float*)d_out;

  char* ws = (char*)d_ws;
  size_t off = 0;
  auto alloc = [&](size_t bytes) -> char* {
    char* p = ws + off;
    off += (bytes + 255) & ~255ULL;
    return p;
  };
  int*   idx    = (int*)  alloc((size_t)BB * NN * KK * 4);
  float* xx     = (float*)alloc((size_t)BB * NN * 4);
  float* xT0    = (float*)alloc((size_t)BB * 3 * NN * 4);
  float* bufA   = (float*)alloc((size_t)BB * NN * 64 * 4);
  float* bufB   = (float*)alloc((size_t)BB * NN * 64 * 4);
  float* pooled = (float*)alloc((size_t)BB * 320 * 4);
  float* h1     = (float*)alloc((size_t)BB * 1024 * 4);
  float* h2     = (float*)alloc((size_t)BB * 512 * 4);
  float* uc     = (float*)alloc((size_t)BB * NN * 256 * 4);
  ushort* xhl   = (ushort*)alloc((size_t)BB * NN * 128 * 2);

  size_t dbytes_per_b = (size_t)NN * NN * 4;
  size_t rem = (ws_size > off) ? (ws_size - off) : 0;
  int gmax = (int)(rem / dbytes_per_b);
  if (gmax > 32) gmax = 32;
  int gp2 = 1;
  while (gp2 * 2 <= gmax) gp2 <<= 1;   // power of two so BB%gmax==0 and swizzle decode is shifts
  gmax = gp2 < 1 ? 1 : gp2;
  float* D = (float*)alloc((size_t)gmax * dbytes_per_b);

  int gshift = -1;                      // -1 -> no swizzle (gg < 8)
  if (gmax >= 8) {
    int gper = gmax >> 3;
    gshift = 0;
    while ((1 << gshift) < gper) ++gshift;
  }

  dim3 blk(256);
  int bn_blocks = (BB * NN + 255) / 256;

  auto knn64 = [&]() {
    for (int b0 = 0; b0 < BB; b0 += gmax) {
      distm_kernel<<<gmax * 64, blk, 0, stream>>>(xhl, xx, D, b0, gshift);
      topk_kernel<<<(gmax * NN) / 4, blk, 0, stream>>>(D, idx, b0);
    }
  };

  // ---- layer 1 (C=3 -> 64) ----
  t3xx_kernel<<<bn_blocks, blk, 0, stream>>>(x, xT0, xx, pooled);
  topk3_kernel<<<(BB * NN) / 4, blk, 0, stream>>>(x, xT0, xx, idx);
  uc3_kernel<<<(BB * NN * 128) / 256, blk, 0, stream>>>(x, w1, uc);
  gmp_kernel<64, true><<<(BB * NN * 16) / 256, blk, 0, stream>>>(
      uc, idx, g1, b1, bufA, (u32*)pooled, 0, xhl, xx);

  // ---- layer 2 (64 -> 64) ----
  knn64();
  ucpart_kernel<64><<<dim3((BB * NN) / 32, 2), blk, 0, stream>>>(bufA, w2, uc);
  gmp_kernel<64, true><<<(BB * NN * 16) / 256, blk, 0, stream>>>(
      uc, idx, g2, b2, bufB, (u32*)pooled, 64, xhl, xx);

  // ---- layer 3 (64 -> 64) ----
  knn64();
  ucpart_kernel<64><<<dim3((BB * NN) / 32, 2), blk, 0, stream>>>(bufB, w3, uc);
  gmp_kernel<64, true><<<(BB * NN * 16) / 256, blk, 0, stream>>>(
      uc, idx, g3, b3, bufA, (u32*)pooled, 128, xhl, xx);

  // ---- layer 4 (64 -> 128) ----
  knn64();
  ucpart_kernel<128><<<dim3((BB * NN) / 32, 2), blk, 0, stream>>>(bufA, w4, uc);
  gmp_kernel<128, false><<<(BB * NN * 32) / 256, blk, 0, stream>>>(
      uc, idx, g4, b4, bufB, (u32*)pooled, 192, nullptr, nullptr);

  // ---- classifier ----
  fcw_kernel<320, 1024, 32, true><<<dim3(BB, 8), blk, 0, stream>>>(pooled, lw1, lb1, g5, b5, h1);
  fcw_kernel<1024, 512, 16, true><<<dim3(BB, 8), blk, 0, stream>>>(h1, lw2, lb2, g6, b6, h2);
  fcw_kernel<512, 40, 10, false><<<dim3(BB, 1), blk, 0, stream>>>(h2, lw3, lb3, nullptr, nullptr, out);
}

// Round 10
// 425.016 us; speedup vs baseline: 9.3824x; 1.1401x over previous
//
#include <hip/hip_runtime.h>
#include <math.h>

#define BB 32
#define NN 1024
#define KK 20
typedef unsigned long long u64;
typedef unsigned int u32;
typedef unsigned short ushort;
static constexpr float EPSF = 1e-5f;

typedef __attribute__((ext_vector_type(8))) short bf16x8;
typedef __attribute__((ext_vector_type(4))) float f32x4;

// ---------------- fused transpose (B,N,3)->(B,3,N) + xx + pooled zero ----------------
__global__ void t3xx_kernel(const float* __restrict__ x, float* __restrict__ xT,
                            float* __restrict__ xx, float* __restrict__ pooled) {
  int t = blockIdx.x * blockDim.x + threadIdx.x;
  if (t >= BB * NN) return;
  if (t < BB * 320) pooled[t] = 0.0f;
  int b = t >> 10, i = t & (NN - 1);
  float v0 = x[(size_t)t * 3 + 0], v1 = x[(size_t)t * 3 + 1], v2 = x[(size_t)t * 3 + 2];
  xT[((size_t)b * 3 + 0) * NN + i] = v0;
  xT[((size_t)b * 3 + 1) * NN + i] = v1;
  xT[((size_t)b * 3 + 2) * NN + i] = v2;
  float s = 0.f;
  s += v0 * v0; s += v1 * v1; s += v2 * v2;
  xx[t] = s;
}

// ---------------- monotone f32 -> u32 order map ----------------
__device__ __forceinline__ u32 map_m(float d) {
  u32 bits = __float_as_uint(d);
  return bits ^ (u32)(((int)bits >> 31) | 0x80000000);
}

__device__ __forceinline__ double shflxd(double v, int m) {
  long long u = __double_as_longlong(v);
  int lo = (int)(u & 0xFFFFFFFFll);
  int hi = (int)(((u64)u) >> 32);
  lo = __shfl_xor(lo, m);
  hi = __shfl_xor(hi, m);
  return __longlong_as_double(((long long)hi << 32) | (u32)lo);
}

// descending bitonic sorts
__device__ __forceinline__ u32 lane_sort64_u32(u32 v, int lane) {
  #pragma unroll
  for (int kk = 2; kk <= 64; kk <<= 1)
    #pragma unroll
    for (int j = kk >> 1; j > 0; j >>= 1) {
      u32 pv = (u32)__shfl_xor((int)v, j);
      bool keepMax = (((lane & j) == 0) == ((lane & kk) == 0));
      u32 mx = v > pv ? v : pv, mn = v > pv ? pv : v;
      v = keepMax ? mx : mn;
    }
  return v;
}

__device__ __forceinline__ double lane_sort64(double v, int lane) {
  #pragma unroll
  for (int kk = 2; kk <= 64; kk <<= 1)
    #pragma unroll
    for (int j = kk >> 1; j > 0; j >>= 1) {
      double pv = shflxd(v, j);
      bool keepMax = (((lane & j) == 0) == ((lane & kk) == 0));
      v = keepMax ? fmax(v, pv) : fmin(v, pv);
    }
  return v;
}

__device__ __forceinline__ double lane_sort32(double v, int lane) {
  #pragma unroll
  for (int kk = 2; kk <= 32; kk <<= 1)
    #pragma unroll
    for (int j = kk >> 1; j > 0; j >>= 1) {
      double pv = shflxd(v, j);
      bool keepMax = (((lane & j) == 0) == ((lane & kk) == 0));
      v = keepMax ? fmax(v, pv) : fmin(v, pv);
    }
  return v;
}

__device__ __forceinline__ void key_decode_write(double res, int lane, int* __restrict__ orow) {
  if (lane < KK) {
    double md = trunc(res * (1.0 / 1024.0));
    double rd = fma(md, -1024.0, res);
    orow[lane] = 1023 - (int)rd;
  }
}

// u32 first-stage filter + f64 survivor sort. m[e] is candidate (q=e>>2,c=e&3):
// j = q*256 + lane*4 + c ; f64 key = m*1024 + (1023-j)  (exact integers in f64)
__device__ __forceinline__ void topk_sel(u32 (&m)[16], int lane,
                                         volatile double* __restrict__ sb,
                                         int* __restrict__ orow) {
  u32 h = m[0];
  #pragma unroll
  for (int e = 1; e < 16; ++e) h = m[e] > h ? m[e] : h;
  u32 sh = lane_sort64_u32(h, lane);
  u32 T = (u32)__shfl((int)sh, KK - 1);

  int cnt = 0;
  #pragma unroll
  for (int e = 0; e < 16; ++e) cnt += (m[e] >= T) ? 1 : 0;
  int scan = cnt;
  #pragma unroll
  for (int d = 1; d < 64; d <<= 1) {
    int nv = __shfl_up(scan, d);
    if (lane >= d) scan += nv;
  }
  int total = __shfl(scan, 63);
  double based = (double)(1023 - lane * 4);

  if (total <= 64) {
    int ofs = scan - cnt;
    sb[lane] = 0.0;
    #pragma unroll
    for (int e = 0; e < 16; ++e)
      if (m[e] >= T) {
        double kd = fma((double)m[e], 1024.0, based - (double)((e >> 2) * 256 + (e & 3)));
        sb[ofs++] = kd;
      }
    double v = sb[lane];
    v = (total <= 32) ? lane_sort32(v, lane) : lane_sort64(v, lane);
    key_decode_write(v, lane, orow);
  } else {
    // exact fallback (near-degenerate data): tournament over full f64 keys
    double k[16];
    #pragma unroll
    for (int e = 0; e < 16; ++e)
      k[e] = fma((double)m[e], 1024.0, based - (double)((e >> 2) * 256 + (e & 3)));
    double lm = k[0];
    #pragma unroll
    for (int e = 1; e < 16; ++e) lm = fmax(lm, k[e]);
    double res = 0.0;
    for (int t = 0; t < KK; ++t) {
      double w = lm;
      #pragma unroll
      for (int mm = 1; mm < 64; mm <<= 1) w = fmax(w, shflxd(w, mm));
      if (lane == t) res = w;
      bool win = (lm == w);
      #pragma unroll
      for (int e = 0; e < 16; ++e) k[e] = (k[e] == w) ? 0.0 : k[e];
      if (win) {
        double n0 = fmax(k[0], k[1]);
        #pragma unroll
        for (int e = 2; e < 16; ++e) n0 = fmax(n0, k[e]);
        lm = n0;
      }
    }
    key_decode_write(res, lane, orow);
  }
}

// ---------------- merged: MFMA dist (u32-m output, XCD-swizzled) + uc GEMM ----------------
#define CC 64
template<int O>
__global__ __launch_bounds__(256) void ducp_kernel(
    const ushort* __restrict__ xhl,  // (B,N,128) [hi|lo]
    const float* __restrict__ xx,    // (B,N)
    u32* __restrict__ Dm,            // (g,N,N) mapped u32
    int b0, int gshift, int distBlocks,
    const float* __restrict__ xfeat, // (B,N,64)
    const float* __restrict__ w,     // (O,128)
    float* __restrict__ uc) {        // (B,N,2O)
  __shared__ float4 Ws[O * 16];
  __shared__ float4 As[32 * 16];

  if ((int)blockIdx.x < distBlocks) {
    // ----- distance part -----
    int bid = blockIdx.x;
    int b, tile;
    if (gshift >= 0) {
      int xcd = bid & 7;
      int rest = bid >> 3;
      int bl = rest & ((1 << gshift) - 1);
      tile = rest >> gshift;
      b = b0 + xcd + (bl << 3);
    } else {
      b = b0 + (bid >> 6);
      tile = bid & 63;
    }
    int dloc = b - b0;
    int wv = threadIdx.x >> 6;
    int lane = threadIdx.x & 63;
    int wm = wv >> 1, wn = wv & 1;
    int i0 = (tile >> 3) * 128 + wm * 64;
    int j0 = (tile & 7) * 128 + wn * 64;
    int r16 = lane & 15;
    int kg = lane >> 4;

    const ushort* base = xhl + (size_t)b * NN * 128;
    f32x4 acc[4][4];
    #pragma unroll
    for (int mi = 0; mi < 4; ++mi)
      #pragma unroll
      for (int ni = 0; ni < 4; ++ni) acc[mi][ni] = (f32x4){0.f, 0.f, 0.f, 0.f};

    #pragma unroll
    for (int ks = 0; ks < 2; ++ks) {
      int k0 = ks * 32 + kg * 8;
      bf16x8 ah[4], al[4], bh[4], bl[4];
      #pragma unroll
      for (int mi = 0; mi < 4; ++mi) {
        const ushort* pr = base + (size_t)(i0 + mi * 16 + r16) * 128 + k0;
        ah[mi] = *(const bf16x8*)pr;
        al[mi] = *(const bf16x8*)(pr + 64);
      }
      #pragma unroll
      for (int ni = 0; ni < 4; ++ni) {
        const ushort* pr = base + (size_t)(j0 + ni * 16 + r16) * 128 + k0;
        bh[ni] = *(const bf16x8*)pr;
        bl[ni] = *(const bf16x8*)(pr + 64);
      }
      #pragma unroll
      for (int mi = 0; mi < 4; ++mi)
        #pragma unroll
        for (int ni = 0; ni < 4; ++ni) {
          acc[mi][ni] = __builtin_amdgcn_mfma_f32_16x16x32_bf16(ah[mi], bh[ni], acc[mi][ni], 0, 0, 0);
          acc[mi][ni] = __builtin_amdgcn_mfma_f32_16x16x32_bf16(ah[mi], bl[ni], acc[mi][ni], 0, 0, 0);
          acc[mi][ni] = __builtin_amdgcn_mfma_f32_16x16x32_bf16(al[mi], bh[ni], acc[mi][ni], 0, 0, 0);
          acc[mi][ni] = __builtin_amdgcn_mfma_f32_16x16x32_bf16(al[mi], bl[ni], acc[mi][ni], 0, 0, 0);
        }
    }

    const float* xxb = xx + (size_t)b * NN;
    u32* Dg = Dm + (size_t)dloc * NN * NN;
    #pragma unroll
    for (int ni = 0; ni < 4; ++ni) {
      float xj = xxb[j0 + ni * 16 + r16];
      #pragma unroll
      for (int mi = 0; mi < 4; ++mi) {
        int rowb = i0 + mi * 16 + kg * 4;
        #pragma unroll
        for (int r = 0; r < 4; ++r)
          Dg[(size_t)(rowb + r) * NN + j0 + ni * 16 + r16] = map_m(2.f * acc[mi][ni][r] - xj);
      }
    }
  } else {
    // ----- uc GEMM part -----
    int id = blockIdx.x - distBlocks;
    int part = id >> 10;
    int tile = id & 1023;
    int b = tile >> 5;
    int i0 = (tile & 31) * 32;

    const float4* w4 = (const float4*)w;
    for (int r = threadIdx.x; r < O * 16; r += 256) {
      int rowc = r >> 4, c4 = r & 15;
      float4 v;
      if (part == 0) {
        v = w4[(size_t)rowc * 32 + c4];
      } else {
        float4 lo = w4[(size_t)rowc * 32 + c4];
        float4 hi = w4[(size_t)rowc * 32 + 16 + c4];
        v = make_float4(hi.x - lo.x, hi.y - lo.y, hi.z - lo.z, hi.w - lo.w);
      }
      Ws[(rowc << 4) + (c4 ^ (rowc & 7))] = v;
    }
    const float4* xa = (const float4*)(xfeat + ((size_t)b * NN + i0) * CC);
    for (int r = threadIdx.x; r < 32 * 16; r += 256) As[r] = xa[r];
    __syncthreads();

    int col = threadIdx.x % O;
    int pg = threadIdx.x / O;
    constexpr int PPT = 32 * O / 256;
    float4 wc[16];
    #pragma unroll
    for (int c4 = 0; c4 < 16; ++c4) wc[c4] = Ws[(col << 4) + (c4 ^ (col & 7))];

    #pragma unroll
    for (int pp = 0; pp < PPT; ++pp) {
      int p = pg * PPT + pp;
      float acc = 0.f;
      #pragma unroll
      for (int c4 = 0; c4 < 16; ++c4) {
        float4 a = As[(p << 4) + c4];
        acc += a.x * wc[c4].x; acc += a.y * wc[c4].y;
        acc += a.z * wc[c4].z; acc += a.w * wc[c4].w;
      }
      uc[((size_t)b * NN + i0 + p) * (2 * O) + part * O + col] = acc;
    }
  }
}

// ---------------- wave-per-row top-20 over u32 m ----------------
__global__ __launch_bounds__(256) void topk_kernel(
    const u32* __restrict__ Dm, int* __restrict__ oidx, int b0) {
  __shared__ double sb[4][64];
  int wslot = threadIdx.x >> 6;
  int wid = (blockIdx.x << 2) + wslot;
  int lane = threadIdx.x & 63;
  int row = wid & (NN - 1);
  int bg = wid >> 10;

  const uint4* dp = (const uint4*)(Dm + ((size_t)bg * NN + row) * NN);
  u32 m[16];
  #pragma unroll
  for (int q = 0; q < 4; ++q) {
    uint4 v = dp[q * 64 + lane];
    m[q * 4 + 0] = v.x; m[q * 4 + 1] = v.y; m[q * 4 + 2] = v.z; m[q * 4 + 3] = v.w;
  }
  topk_sel(m, lane, &sb[wslot][0], oidx + ((size_t)(b0 + bg) * NN + row) * KK);
}

// ---------------- merged layer-1: fused C=3 dist+top-20 (blocks < 8192) + uc3 ----------------
__global__ __launch_bounds__(256) void tu3_kernel(
    const float* __restrict__ x,   // (B,N,3)
    const float* __restrict__ xT,  // (B,3,N)
    const float* __restrict__ xx,  // (B,N)
    int* __restrict__ oidx,
    const float* __restrict__ w1,
    float* __restrict__ uc) {
  __shared__ double sb[4][64];
  if ((int)blockIdx.x < 8192) {
    int wslot = threadIdx.x >> 6;
    int wid = ((int)blockIdx.x << 2) + wslot;
    int lane = threadIdx.x & 63;
    int row = wid & (NN - 1);
    int b = wid >> 10;

    const float* xr = x + ((size_t)b * NN + row) * 3;
    float x0 = xr[0], x1 = xr[1], x2 = xr[2];
    const float* xTb = xT + (size_t)b * 3 * NN;
    const float* xxb = xx + (size_t)b * NN;

    u32 m[16];
    #pragma unroll
    for (int q = 0; q < 4; ++q) {
      int f4i = q * 64 + lane;
      float4 a  = ((const float4*)xTb)[f4i];
      float4 bv = ((const float4*)(xTb + NN))[f4i];
      float4 c  = ((const float4*)(xTb + 2 * NN))[f4i];
      float4 xj = ((const float4*)xxb)[f4i];
      float d0 = 0.f; d0 += x0 * a.x; d0 += x1 * bv.x; d0 += x2 * c.x;
      float d1 = 0.f; d1 += x0 * a.y; d1 += x1 * bv.y; d1 += x2 * c.y;
      float d2 = 0.f; d2 += x0 * a.z; d2 += x1 * bv.z; d2 += x2 * c.z;
      float d3 = 0.f; d3 += x0 * a.w; d3 += x1 * bv.w; d3 += x2 * c.w;
      m[q * 4 + 0] = map_m(2.f * d0 - xj.x);
      m[q * 4 + 1] = map_m(2.f * d1 - xj.y);
      m[q * 4 + 2] = map_m(2.f * d2 - xj.z);
      m[q * 4 + 3] = map_m(2.f * d3 - xj.w);
    }
    topk_sel(m, lane, &sb[wslot][0], oidx + ((size_t)b * NN + row) * KK);
  } else {
    int t = ((int)blockIdx.x - 8192) * 256 + threadIdx.x;   // B*N*128
    int col = t & 127;
    int i = (t >> 7) & (NN - 1);
    int b = t >> 17;
    const float* xr = x + ((size_t)b * NN + i) * 3;
    float x0 = xr[0], x1 = xr[1], x2 = xr[2];
    float r;
    if (col < 64) {
      const float* wr = w1 + col * 6;
      r = wr[0] * x0 + wr[1] * x1 + wr[2] * x2;
    } else {
      const float* wr = w1 + (col - 64) * 6;
      r = (wr[3] - wr[0]) * x0 + (wr[4] - wr[1]) * x1 + (wr[5] - wr[2]) * x2;
    }
    uc[(size_t)t] = r;
  }
}

// ---- gather-max + BN/ReLU + global-pool + (NEXT) y/xhl/xx prep. XCD-swizzled blocks. ----
template<int O, bool NEXT>
__global__ __launch_bounds__(256) void gmp_kernel(
    const float* __restrict__ uc,   // (B,N,2O)
    const int*   __restrict__ idx,  // (B,N,K)
    const float* __restrict__ g,
    const float* __restrict__ bb,
    float* __restrict__ y,          // (B,N,O)
    u32* __restrict__ pooled,       // (B,320) u32 bit patterns (all >= 0)
    int ooff,
    ushort* __restrict__ xhl,       // (B,N,128) [hi|lo]   (NEXT only)
    float* __restrict__ xx) {       // (B,N)               (NEXT only)
  constexpr int O4 = O / 4;
  constexpr int PPB = 256 / O4;
  int bid = blockIdx.x;
  int xcd = bid & 7;
  int rest = bid >> 3;
  int bgrp = rest & 3;
  int jblk = rest >> 2;
  int b = xcd + (bgrp << 3);
  int o4 = threadIdx.x & (O4 - 1);
  int i = jblk * PPB + (threadIdx.x >> (O == 64 ? 4 : 5));

  const int* irow = idx + ((size_t)b * NN + i) * KK;
  int jj[KK];
  #pragma unroll
  for (int k = 0; k < KK; ++k) jj[k] = irow[k];

  const float* ucb = uc + (size_t)b * NN * (2 * O);
  float4 vm = make_float4(-INFINITY, -INFINITY, -INFINITY, -INFINITY);
  #pragma unroll
  for (int k = 0; k < KK; ++k) {
    float4 v = *(const float4*)(ucb + (size_t)jj[k] * (2 * O) + o4 * 4);
    vm.x = fmaxf(vm.x, v.x); vm.y = fmaxf(vm.y, v.y);
    vm.z = fmaxf(vm.z, v.z); vm.w = fmaxf(vm.w, v.w);
  }
  float4 c0 = *(const float4*)(ucb + (size_t)i * (2 * O) + O + o4 * 4);
  float4 gv = ((const float4*)g)[o4];
  float4 bv = ((const float4*)bb)[o4];
  const float inv = 1.0f / sqrtf(1.0f + EPSF);
  float4 o;
  o.x = fmaxf((gv.x * inv) * (vm.x + c0.x) + bv.x, 0.f);
  o.y = fmaxf((gv.y * inv) * (vm.y + c0.y) + bv.y, 0.f);
  o.z = fmaxf((gv.z * inv) * (vm.z + c0.z) + bv.z, 0.f);
  o.w = fmaxf((gv.w * inv) * (vm.w + c0.w) + bv.w, 0.f);

  if constexpr (NEXT) {
    *(float4*)(y + ((size_t)b * NN + i) * O + o4 * 4) = o;
    ushort4 hi, lo;
    u32 q0 = __float_as_uint(o.x); hi.x = q0 >> 16;
    u32 q1 = __float_as_uint(o.y); hi.y = q1 >> 16;
    u32 q2 = __float_as_uint(o.z); hi.z = q2 >> 16;
    u32 q3 = __float_as_uint(o.w); hi.w = q3 >> 16;
    lo.x = __float_as_uint(o.x - __uint_as_float(q0 & 0xFFFF0000u)) >> 16;
    lo.y = __float_as_uint(o.y - __uint_as_float(q1 & 0xFFFF0000u)) >> 16;
    lo.z = __float_as_uint(o.z - __uint_as_float(q2 & 0xFFFF0000u)) >> 16;
    lo.w = __float_as_uint(o.w - __uint_as_float(q3 & 0xFFFF0000u)) >> 16;
    ushort* xr = xhl + ((size_t)b * NN + i) * 128;
    *(ushort4*)(xr + o4 * 4) = hi;
    *(ushort4*)(xr + 64 + o4 * 4) = lo;
    float px = o.x * o.x + o.y * o.y + o.z * o.z + o.w * o.w;
    px += __shfl_xor(px, 1);
    px += __shfl_xor(px, 2);
    px += __shfl_xor(px, 4);
    px += __shfl_xor(px, 8);
    if (o4 == 0) xx[(size_t)b * NN + i] = px;
  }

  __shared__ float4 sm[256];
  sm[threadIdx.x] = o;
  __syncthreads();
  if (threadIdx.x < O4) {
    float4 m = sm[threadIdx.x];
    #pragma unroll
    for (int r = 1; r < PPB; ++r) {
      float4 v = sm[threadIdx.x + r * O4];
      m.x = fmaxf(m.x, v.x); m.y = fmaxf(m.y, v.y);
      m.z = fmaxf(m.z, v.z); m.w = fmaxf(m.w, v.w);
    }
    u32* dst = pooled + (size_t)b * 320 + ooff + threadIdx.x * 4;
    atomicMax(dst + 0, __float_as_uint(m.x));
    atomicMax(dst + 1, __float_as_uint(m.y));
    atomicMax(dst + 2, __float_as_uint(m.z));
    atomicMax(dst + 3, __float_as_uint(m.w));
  }
}

// ---------------- coalesced fc: wave-per-output, LDS-staged input ----------------
template<int IN, int OUT, int OPW, bool BNRELU>
__global__ __launch_bounds__(256) void fcw_kernel(
    const float* __restrict__ in, const float* __restrict__ W,
    const float* __restrict__ lb, const float* __restrict__ g,
    const float* __restrict__ bbias, float* __restrict__ out) {
  int b = blockIdx.x;
  int oc = blockIdx.y;
  __shared__ float sIn[IN];
  for (int r = threadIdx.x; r < IN; r += 256) sIn[r] = in[(size_t)b * IN + r];
  __syncthreads();
  int w = threadIdx.x >> 6, lane = threadIdx.x & 63;
  constexpr int RPL = IN / 64;
  for (int ii = 0; ii < OPW; ++ii) {
    int o = (oc * 4 + w) * OPW + ii;
    const float* wr = W + (size_t)o * IN;
    float acc = 0.f;
    #pragma unroll
    for (int r = 0; r < RPL; ++r) acc += wr[r * 64 + lane] * sIn[r * 64 + lane];
    #pragma unroll
    for (int m = 32; m >= 1; m >>= 1) acc += __shfl_xor(acc, m);
    if (lane == 0) {
      acc += lb[o];
      if (BNRELU) {
        float s = g[o] * (1.0f / sqrtf(1.0f + EPSF));
        acc = fmaxf(acc * s + bbias[o], 0.0f);
      }
      out[(size_t)b * OUT + o] = acc;
    }
  }
}

extern "C" void kernel_launch(void* const* d_in, const int* in_sizes, int n_in,
                              void* d_out, int out_size, void* d_ws, size_t ws_size,
                              hipStream_t stream) {
  const float* x   = (const float*)d_in[0];
  const float* w1  = (const float*)d_in[1];
  const float* g1  = (const float*)d_in[2];
  const float* b1  = (const float*)d_in[3];
  const float* w2  = (const float*)d_in[4];
  const float* g2  = (const float*)d_in[5];
  const float* b2  = (const float*)d_in[6];
  const float* w3  = (const float*)d_in[7];
  const float* g3  = (const float*)d_in[8];
  const float* b3  = (const float*)d_in[9];
  const float* w4  = (const float*)d_in[10];
  const float* g4  = (const float*)d_in[11];
  const float* b4  = (const float*)d_in[12];
  const float* lw1 = (const float*)d_in[13];
  const float* lb1 = (const float*)d_in[14];
  const float* g5  = (const float*)d_in[15];
  const float* b5  = (const float*)d_in[16];
  const float* lw2 = (const float*)d_in[17];
  const float* lb2 = (const float*)d_in[18];
  const float* g6  = (const float*)d_in[19];
  const float* b6  = (const float*)d_in[20];
  const float* lw3 = (const float*)d_in[21];
  const float* lb3 = (const float*)d_in[22];
  float* out = (float*)d_out;

  char* ws = (char*)d_ws;
  size_t off = 0;
  auto alloc = [&](size_t bytes) -> char* {
    char* p = ws + off;
    off += (bytes + 255) & ~255ULL;
    return p;
  };
  int*   idx    = (int*)  alloc((size_t)BB * NN * KK * 4);
  float* xx     = (float*)alloc((size_t)BB * NN * 4);
  float* xT0    = (float*)alloc((size_t)BB * 3 * NN * 4);
  float* bufA   = (float*)alloc((size_t)BB * NN * 64 * 4);
  float* bufB   = (float*)alloc((size_t)BB * NN * 64 * 4);
  float* pooled = (float*)alloc((size_t)BB * 320 * 4);
  float* h1     = (float*)alloc((size_t)BB * 1024 * 4);
  float* h2     = (float*)alloc((size_t)BB * 512 * 4);
  float* uc     = (float*)alloc((size_t)BB * NN * 256 * 4);
  ushort* xhl   = (ushort*)alloc((size_t)BB * NN * 128 * 2);

  size_t dbytes_per_b = (size_t)NN * NN * 4;
  size_t rem = (ws_size > off) ? (ws_size - off) : 0;
  int gmax = (int)(rem / dbytes_per_b);
  if (gmax > 32) gmax = 32;
  int gp2 = 1;
  while (gp2 * 2 <= gmax) gp2 <<= 1;
  gmax = gp2 < 1 ? 1 : gp2;
  u32* Dm = (u32*)alloc((size_t)gmax * dbytes_per_b);

  int gshift = -1;
  if (gmax >= 8) {
    int gper = gmax >> 3;
    gshift = 0;
    while ((1 << gshift) < gper) ++gshift;
  }

  dim3 blk(256);
  int bn_blocks = (BB * NN + 255) / 256;

  // per layer: [dist + ucGEMM merged] -> topk -> gmp
  auto layer64 = [&](const float* feat, const float* w, const float* gg, const float* bbv,
                     float* yout, int ooff, bool next, float* ybuf) {
    for (int b0 = 0; b0 < BB; b0 += gmax) {
      int distBlocks = gmax * 64;
      int ucBlocks = (b0 == 0) ? 2048 : 0;   // uc GEMM once (covers all batches)
      ducp_kernel<64><<<distBlocks + ucBlocks, blk, 0, stream>>>(
          xhl, xx, Dm, b0, gshift, distBlocks, feat, w, uc);
      topk_kernel<<<(gmax * NN) / 4, blk, 0, stream>>>(Dm, idx, b0);
    }
    if (next)
      gmp_kernel<64, true><<<(BB * NN * 16) / 256, blk, 0, stream>>>(
          uc, idx, gg, bbv, yout, (u32*)pooled, ooff, xhl, xx);
    else
      gmp_kernel<64, false><<<(BB * NN * 16) / 256, blk, 0, stream>>>(
          uc, idx, gg, bbv, yout, (u32*)pooled, ooff, nullptr, nullptr);
    (void)ybuf;
  };

  // ---- layer 1 (C=3 -> 64) ----
  t3xx_kernel<<<bn_blocks, blk, 0, stream>>>(x, xT0, xx, pooled);
  tu3_kernel<<<8192 + 16384, blk, 0, stream>>>(x, xT0, xx, idx, w1, uc);
  gmp_kernel<64, true><<<(BB * NN * 16) / 256, blk, 0, stream>>>(
      uc, idx, g1, b1, bufA, (u32*)pooled, 0, xhl, xx);

  // ---- layer 2 (64 -> 64) ----
  layer64(bufA, w2, g2, b2, bufB, 64, true, bufB);

  // ---- layer 3 (64 -> 64) ----
  layer64(bufB, w3, g3, b3, bufA, 128, true, bufA);

  // ---- layer 4 (64 -> 128) ----
  for (int b0 = 0; b0 < BB; b0 += gmax) {
    int distBlocks = gmax * 64;
    int ucBlocks = (b0 == 0) ? 2048 : 0;
    ducp_kernel<128><<<distBlocks + ucBlocks, blk, 0, stream>>>(
        xhl, xx, Dm, b0, gshift, distBlocks, bufA, w4, uc);
    topk_kernel<<<(gmax * NN) / 4, blk, 0, stream>>>(Dm, idx, b0);
  }
  gmp_kernel<128, false><<<(BB * NN * 32) / 256, blk, 0, stream>>>(
      uc, idx, g4, b4, bufB, (u32*)pooled, 192, nullptr, nullptr);

  // ---- classifier ----
  fcw_kernel<320, 1024, 32, true><<<dim3(BB, 8), blk, 0, stream>>>(pooled, lw1, lb1, g5, b5, h1);
  fcw_kernel<1024, 512, 16, true><<<dim3(BB, 8), blk, 0, stream>>>(h1, lw2, lb2, g6, b6, h2);
  fcw_kernel<512, 40, 10, false><<<dim3(BB, 1), blk, 0, stream>>>(h2, lw3, lb3, nullptr, nullptr, out);
}